// Round 26
// baseline (1892.270 us; speedup 1.0000x reference)
//
#include <hip/hip_runtime.h>
#include <cstdint>

#define Bb 8
#define Ll 512
#define Cc 512
#define Hh 8
#define HD 64
#define Ff 2048
#define Ss 50
#define NROWS 4096   // B*L
#define QKVS 1536

typedef __attribute__((ext_vector_type(8))) short short8v;  // 8 bf16 (4 VGPR)
typedef __attribute__((ext_vector_type(4))) float f32x4;

__device__ __forceinline__ float wave_sum(float v){
  #pragma unroll
  for (int o=32;o>=1;o>>=1) v += __shfl_xor(v,o);
  return v;
}
__device__ __forceinline__ float bf2f(unsigned short u){
  return __uint_as_float(((unsigned)u) << 16);
}

// cheap split: hi = trunc-bf16(a); lo = trunc-bf16(a - hi). err ~ 2^-16 |a|
__device__ __forceinline__ void splitc(float a, unsigned short& hi, unsigned short& lo){
  unsigned u = __float_as_uint(a);
  hi = (unsigned short)(u >> 16);
  float l = a - __uint_as_float(u & 0xFFFF0000u);
  lo = (unsigned short)(__float_as_uint(l) >> 16);
}
__device__ __forceinline__ unsigned short f2bf_rne(float a){
  unsigned u = __float_as_uint(a);
  unsigned r = u + 0x7FFFu + ((u >> 16) & 1u);
  return (unsigned short)(r >> 16);
}
__device__ __forceinline__ void split4(float4 v, unsigned short* hi, unsigned short* lo){
  unsigned short h0,h1,h2,h3,l0,l1,l2,l3;
  splitc(v.x,h0,l0); splitc(v.y,h1,l1); splitc(v.z,h2,l2); splitc(v.w,h3,l3);
  *(ushort4*)hi = make_ushort4(h0,h1,h2,h3);
  *(ushort4*)lo = make_ushort4(l0,l1,l2,l3);
}

// ---------------- merged weight split: 8 segments in one launch --------------
__global__ __launch_bounds__(256) void split_all(
    const float* __restrict__ pw1w, const float* __restrict__ pw2w,
    const float* __restrict__ aow,  const float* __restrict__ f1w,
    const float* __restrict__ f2w,  const float* __restrict__ sqw,
    const float* __restrict__ sow,
    const float* __restrict__ aqw, const float* __restrict__ akw,
    const float* __restrict__ avw,
    unsigned short* __restrict__ pw1h, unsigned short* __restrict__ pw1l,
    unsigned short* __restrict__ pw2h, unsigned short* __restrict__ pw2l,
    unsigned short* __restrict__ aoh,  unsigned short* __restrict__ aol,
    unsigned short* __restrict__ f1h,  unsigned short* __restrict__ f1l,
    unsigned short* __restrict__ f2h,  unsigned short* __restrict__ f2l,
    unsigned short* __restrict__ sqh,  unsigned short* __restrict__ sql,
    unsigned short* __restrict__ soh,  unsigned short* __restrict__ sol,
    unsigned short* __restrict__ qkvh, unsigned short* __restrict__ qkvl)
{
  int seg = blockIdx.y;
  if (seg == 7){
    const int n4 = 6*QKVS*512/4;
    for (int i = blockIdx.x*256 + threadIdx.x; i < n4; i += gridDim.x*256){
      int e = i << 2;
      int layer = e / 786432;
      int r = e - layer*786432;
      int which = r >> 18;
      int off = r & 262143;
      const float* s = (which==0) ? aqw : (which==1) ? akw : avw;
      float4 vv = *(const float4*)(s + (size_t)layer*262144 + off);
      split4(vv, (unsigned short*)((ushort4*)qkvh + i),
                 (unsigned short*)((ushort4*)qkvl + i));
    }
    return;
  }
  const float* src; unsigned short* hi; unsigned short* lo; int n4;
  switch(seg){
    case 0: src=pw1w; hi=pw1h; lo=pw1l; n4=1048576; break;
    case 1: src=pw2w; hi=pw2h; lo=pw2l; n4=1048576; break;
    case 2: src=aow;  hi=aoh;  lo=aol;  n4=393216;  break;
    case 3: src=f1w;  hi=f1h;  lo=f1l;  n4=1572864; break;
    case 4: src=f2w;  hi=f2h;  lo=f2l;  n4=1572864; break;
    case 5: src=sqw;  hi=sqh;  lo=sql;  n4=131072;  break;
    default: src=sow; hi=soh;  lo=sol;  n4=131072;  break;
  }
  for (int i = blockIdx.x*256 + threadIdx.x; i < n4; i += gridDim.x*256){
    float4 v = ((const float4*)src)[i];
    split4(v, (unsigned short*)((ushort4*)hi + i), (unsigned short*)((ushort4*)lo + i));
  }
}

// ---------------- embed gather (mask fused) ----------------
__global__ __launch_bounds__(128) void embed_k(const int* __restrict__ tok,
    const float* __restrict__ emb, const float* __restrict__ mask,
    float* __restrict__ x){
  int n = blockIdx.x;
  int t = tok[n];
  float m = mask[n];
  float4 v = ((const float4*)(emb + ((size_t)t<<9)))[threadIdx.x];
  v.x*=m; v.y*=m; v.z*=m; v.w*=m;
  ((float4*)(x + ((size_t)n<<9)))[threadIdx.x] = v;
}

// ---------------- FUSED depthwise conv K=5 + bias + mask + LayerNorm + split --
__global__ __launch_bounds__(128) void dwln_k(const float* __restrict__ x,
    const float* __restrict__ w, const float* __restrict__ bias,
    const float* __restrict__ mask, const float* __restrict__ g,
    const float* __restrict__ bt, unsigned short* __restrict__ yh,
    unsigned short* __restrict__ yl){
  __shared__ float ws1[2], ws2[2];
  int n = blockIdx.x; int b_ = n >> 9, l = n & 511;
  int c0 = threadIdx.x * 4;
  float a0=bias[c0], a1=bias[c0+1], a2=bias[c0+2], a3=bias[c0+3];
  #pragma unroll
  for (int k=0;k<5;k++){
    int ls = l + k - 2; ls = ls < 0 ? 0 : (ls > 511 ? 511 : ls);
    const float4 xv = *(const float4*)&x[((size_t)(b_*512 + ls) << 9) + c0];
    a0 += w[(c0+0)*5+k]*xv.x;
    a1 += w[(c0+1)*5+k]*xv.y;
    a2 += w[(c0+2)*5+k]*xv.z;
    a3 += w[(c0+3)*5+k]*xv.w;
  }
  float mm = mask[n];
  a0*=mm; a1*=mm; a2*=mm; a3*=mm;
  int wv = threadIdx.x >> 6, ln_ = threadIdx.x & 63;
  float s = wave_sum(a0+a1+a2+a3);
  if (ln_ == 0) ws1[wv] = s;
  __syncthreads();
  float mean = (ws1[0] + ws1[1]) * (1.f/512.f);
  float d0=a0-mean, d1=a1-mean, d2=a2-mean, d3=a3-mean;
  float sq = wave_sum(d0*d0+d1*d1+d2*d2+d3*d3);
  if (ln_ == 0) ws2[wv] = sq;
  __syncthreads();
  float var = (ws2[0] + ws2[1]) * (1.f/512.f);
  float inv = 1.f/sqrtf(var + 1e-6f);
  float4 gv = *(const float4*)&g[c0];
  float4 bv = *(const float4*)&bt[c0];
  float4 o;
  o.x = d0*inv*gv.x + bv.x;
  o.y = d1*inv*gv.y + bv.y;
  o.z = d2*inv*gv.z + bv.z;
  o.w = d3*inv*gv.w + bv.w;
  size_t base = ((size_t)n << 9) + c0;
  split4(o, yh+base, yl+base);
}

// ---------------- rowwise LayerNorm over C=512 (optional split / mask) -------
template<bool SPLIT, bool MASK>
__global__ __launch_bounds__(256) void ln_rows(const float* __restrict__ x,
    const float* __restrict__ g, const float* __restrict__ bt,
    const float* __restrict__ rowmask,
    float* __restrict__ y, unsigned short* __restrict__ yh,
    unsigned short* __restrict__ yl, int nrows){
  int wid = threadIdx.x >> 6, lane = threadIdx.x & 63;
  int row = blockIdx.x*4 + wid;
  if (row >= nrows) return;
  const float4* xr = (const float4*)(x + ((size_t)row<<9));
  float4 a = xr[lane*2], b = xr[lane*2+1];
  float s = a.x+a.y+a.z+a.w+b.x+b.y+b.z+b.w;
  s = wave_sum(s);
  float m = s * (1.f/512.f);
  float d0=a.x-m,d1=a.y-m,d2=a.z-m,d3=a.w-m,d4=b.x-m,d5=b.y-m,d6=b.z-m,d7=b.w-m;
  float sq = d0*d0+d1*d1+d2*d2+d3*d3+d4*d4+d5*d5+d6*d6+d7*d7;
  sq = wave_sum(sq);
  float var = sq * (1.f/512.f);
  float inv = 1.f/sqrtf(var + 1e-6f);
  const float4* gr = (const float4*)g; const float4* br = (const float4*)bt;
  float4 g0=gr[lane*2], g1=gr[lane*2+1], b0=br[lane*2], b1=br[lane*2+1];
  float4 o0, o1;
  o0.x=d0*inv*g0.x+b0.x; o0.y=d1*inv*g0.y+b0.y; o0.z=d2*inv*g0.z+b0.z; o0.w=d3*inv*g0.w+b0.w;
  o1.x=d4*inv*g1.x+b1.x; o1.y=d5*inv*g1.y+b1.y; o1.z=d6*inv*g1.z+b1.z; o1.w=d7*inv*g1.w+b1.w;
  if constexpr (MASK){
    float mf = rowmask[row];
    o0.x*=mf; o0.y*=mf; o0.z*=mf; o0.w*=mf;
    o1.x*=mf; o1.y*=mf; o1.z*=mf; o1.w*=mf;
  }
  float4* yr = (float4*)(y + ((size_t)row<<9));
  yr[lane*2]=o0; yr[lane*2+1]=o1;
  if constexpr (SPLIT){
    size_t base = ((size_t)row<<9) + lane*8;
    split4(o0, yh+base,   yl+base);
    split4(o1, yh+base+4, yl+base+4);
  }
}

#define EPI_BIAS 0
#define EPI_SCALE 1
#define EPI_GELU 2
#define EPI_RES 3
#define EPI_RELU_MASK 4
#define EPI_RES_MASK 5
#define EPI_RES_GAMMA_MASK 6
#define EPI_TANH 7
#define EPI_QKV 8

// ---------------- style K/V prep -> bf16 planes (zero-padded to 64 keys) -----
__global__ __launch_bounds__(256) void style_prep(
    const float* __restrict__ style_key, const float* __restrict__ style_v,
    const float* __restrict__ sk_w, const float* __restrict__ sk_b,
    const float* __restrict__ sv_w, const float* __restrict__ sv_b,
    unsigned short* __restrict__ KKh, unsigned short* __restrict__ KKl,
    unsigned short* __restrict__ VTh_s, unsigned short* __restrict__ VTl_s)
{
  __shared__ float As[16][68];
  __shared__ float Bs[16][68];
  int sel = blockIdx.y;
  bool is_k = (sel < 2);
  int layer = sel & 1;
  const float* A = is_k ? style_key : style_v;
  const float* W = (sel==0) ? sk_w : (sel==1) ? sk_w+262144 :
                   (sel==2) ? sv_w : sv_w+262144;
  const float* bias = (sel==0) ? sk_b : (sel==1) ? sk_b+512 :
                      (sel==2) ? sv_b : sv_b+512;
  const int N = 50, K = 512;
  int t = threadIdx.x;
  int tx = t & 15, ty = t >> 4;
  int col0 = blockIdx.x << 6;
  int lr = t >> 2, lk = (t & 3) << 2;
  float acc[4][4] = {};
  bool arok = lr < N;
  const float* Ap = A + (size_t)(arok ? lr : 0) * K + lk;
  const float* Wp = W + (size_t)(col0 + lr) * K + lk;
  for (int k0 = 0; k0 < K; k0 += 16) {
    float4 av;
    if (arok) av = *(const float4*)(Ap + k0);
    else { av.x=0;av.y=0;av.z=0;av.w=0; }
    float4 bv = *(const float4*)(Wp + k0);
    As[lk+0][lr]=av.x; As[lk+1][lr]=av.y; As[lk+2][lr]=av.z; As[lk+3][lr]=av.w;
    Bs[lk+0][lr]=bv.x; Bs[lk+1][lr]=bv.y; Bs[lk+2][lr]=bv.z; Bs[lk+3][lr]=bv.w;
    __syncthreads();
    #pragma unroll
    for (int k=0;k<16;k++){
      float4 af = *(const float4*)&As[k][ty<<2];
      float4 bf = *(const float4*)&Bs[k][tx<<2];
      float a4[4]={af.x,af.y,af.z,af.w};
      float b4[4]={bf.x,bf.y,bf.z,bf.w};
      #pragma unroll
      for (int i=0;i<4;i++)
        #pragma unroll
        for (int j=0;j<4;j++)
          acc[i][j] += a4[i]*b4[j];
    }
    __syncthreads();
  }
  #pragma unroll
  for (int i=0;i<4;i++){
    int row = (ty<<2) + i;                 // 0..63 (padded keys zeroed)
    #pragma unroll
    for (int j=0;j<4;j++){
      int col = col0 + (tx<<2) + j;
      int head = col >> 8, d = col & 255;
      float v = 0.f;
      if (row < N){
        v = acc[i][j] + bias[col];
        if (is_k) v = tanhf(v);
      }
      unsigned short hh, ll_;
      splitc(v, hh, ll_);
      if (is_k){
        size_t o = (((size_t)layer*2 + head)<<14) + row*256 + d;
        KKh[o]=hh; KKl[o]=ll_;
      } else {
        size_t o = (((size_t)layer*2 + head)<<14) + d*64 + row;
        VTh_s[o]=hh; VTl_s[o]=ll_;
      }
    }
  }
}

// ---------------- MFMA style attention: block = 16 rows x 2 heads ------------
__global__ __launch_bounds__(256) void style_mf(
    const unsigned short* __restrict__ Qh_g, const unsigned short* __restrict__ Ql_g,
    const unsigned short* __restrict__ KKh, const unsigned short* __restrict__ KKl,
    const unsigned short* __restrict__ VTh_s, const unsigned short* __restrict__ VTl_s,
    const float* __restrict__ mask,
    unsigned short* __restrict__ Oh, unsigned short* __restrict__ Ol)
{
  __shared__ float Sc[2][16][68];
  __shared__ unsigned short Pph[2][16][72], Ppl[2][16][72];
  int t = threadIdx.x, lane = t & 63, w = t >> 6;
  int head = w >> 1, nh = w & 1;
  int rowbase = blockIdx.x * 16;
  int fr = lane & 15, fc = (lane >> 4) << 3, qbase = (lane >> 4) << 2;

  // ---- QK: S = Q_h . KK_h^T ----
  f32x4 s2[2] = {};
  #pragma unroll
  for (int ks = 0; ks < 8; ++ks){
    size_t qoff = (size_t)(rowbase + fr)*512 + head*256 + ks*32 + fc;
    short8v ah = *(const short8v*)(Qh_g + qoff);
    short8v al = *(const short8v*)(Ql_g + qoff);
    #pragma unroll
    for (int nt = 0; nt < 2; ++nt){
      int key = nh*32 + nt*16 + fr;
      size_t ko = (((size_t)head)<<14) + key*256 + ks*32 + fc;
      short8v bh = *(const short8v*)(KKh + ko);
      short8v bl = *(const short8v*)(KKl + ko);
      f32x4 c = s2[nt];
      c = __builtin_amdgcn_mfma_f32_16x16x32_bf16(ah,bh,c,0,0,0);
      c = __builtin_amdgcn_mfma_f32_16x16x32_bf16(ah,bl,c,0,0,0);
      c = __builtin_amdgcn_mfma_f32_16x16x32_bf16(al,bh,c,0,0,0);
      s2[nt] = c;
    }
  }
  #pragma unroll
  for (int nt = 0; nt < 2; ++nt)
    #pragma unroll
    for (int j = 0; j < 4; ++j)
      Sc[head][qbase+j][nh*32 + nt*16 + fr] = s2[nt][j] * 0.044194173824159216f;
  __syncthreads();

  // ---- softmax over 50 keys (32 threads: head x row); keep/sum folded in ----
  if (t < 32){
    int h2 = t >> 4, r = t & 15;
    float mx = -3.4e38f;
    for (int ss = 0; ss < 50; ++ss) mx = fmaxf(mx, Sc[h2][r][ss]);
    float sum = 0.f;
    for (int ss = 0; ss < 50; ++ss) sum += expf(Sc[h2][r][ss] - mx);
    float keep = (mask[rowbase + r] == 0.f) ? 0.f : 1.f;
    float inv = keep / sum;
    for (int ss = 0; ss < 64; ++ss){
      float p = (ss < 50) ? expf(Sc[h2][r][ss] - mx) * inv : 0.f;
      unsigned short hh, ll_;
      splitc(p, hh, ll_);
      Pph[h2][r][ss] = hh; Ppl[h2][r][ss] = ll_;
    }
  }
  __syncthreads();

  // ---- AV: O = P . V ----
  f32x4 av[8] = {};
  #pragma unroll
  for (int ks = 0; ks < 2; ++ks){
    short8v ah = *(const short8v*)&Pph[head][fr][ks*32 + fc];
    short8v al = *(const short8v*)&Ppl[head][fr][ks*32 + fc];
    #pragma unroll
    for (int nt = 0; nt < 8; ++nt){
      int d = nh*128 + nt*16 + fr;
      size_t vo = (((size_t)head)<<14) + d*64 + ks*32 + fc;
      short8v bh = *(const short8v*)(VTh_s + vo);
      short8v bl = *(const short8v*)(VTl_s + vo);
      f32x4 c = av[nt];
      c = __builtin_amdgcn_mfma_f32_16x16x32_bf16(ah,bh,c,0,0,0);
      c = __builtin_amdgcn_mfma_f32_16x16x32_bf16(ah,bl,c,0,0,0);
      c = __builtin_amdgcn_mfma_f32_16x16x32_bf16(al,bh,c,0,0,0);
      av[nt] = c;
    }
  }
  #pragma unroll
  for (int nt = 0; nt < 8; ++nt)
    #pragma unroll
    for (int j = 0; j < 4; ++j){
      int row = rowbase + qbase + j;
      int d = nh*128 + nt*16 + fr;
      unsigned short hh, ll_;
      splitc(av[nt][j], hh, ll_);
      size_t o = (size_t)row*512 + head*256 + d;
      Oh[o] = hh; Ol[o] = ll_;
    }
}

// ---------------- pre-split MFMA GEMM, double-buffered LDS (64-row tiles) ----
// OUT: 0 = fp32 Y, 1 = planes, 2 = QKV mode, 3 = fp32 Y + planes.
template<int EPI, bool AMASK, int OUT, int NF>
__global__ __launch_bounds__(256) void gemm_ps(
    const unsigned short* __restrict__ Ah, const unsigned short* __restrict__ Al,
    const unsigned short* __restrict__ Wh, const unsigned short* __restrict__ Wl,
    const float* __restrict__ bias, const float* __restrict__ res,
    const float* __restrict__ gamma, const float* __restrict__ rowmask,
    float* __restrict__ Y, unsigned short* __restrict__ Yh,
    unsigned short* __restrict__ Yl, unsigned short* __restrict__ VTh,
    unsigned short* __restrict__ VTl, int K, int O, float scale)
{
  __shared__ unsigned short AhS[2][64][40], AlS[2][64][40];
  __shared__ unsigned short BhS[2][NF*32][40], BlS[2][NF*32][40];
  int t = threadIdx.x;
  int row0 = blockIdx.y << 6;
  int col0 = blockIdx.x << (NF==4 ? 7 : 6);
  int lane = t & 63, wid = t >> 6;
  int wr = wid >> 1, wc = wid & 1;

  int sr = t >> 2, sc = (t & 3) << 3;
  const unsigned short* Ahg = Ah + (size_t)(row0 + sr)*K + sc;
  const unsigned short* Alg = Al + (size_t)(row0 + sr)*K + sc;
  const unsigned short* Bhg = Wh + (size_t)(col0 + sr)*K + sc;
  const unsigned short* Blg = Wl + (size_t)(col0 + sr)*K + sc;
  float am = 1.f;
  if (AMASK) am = rowmask[row0 + sr];

  f32x4 acc[2][NF] = {};
  int nsteps = K >> 5;
  short8v ah_, al_, bh0_, bl0_, bh1_, bl1_;
  ah_ = *(const short8v*)(Ahg);
  al_ = *(const short8v*)(Alg);
  bh0_ = *(const short8v*)(Bhg);
  bl0_ = *(const short8v*)(Blg);
  if constexpr (NF==4){
    bh1_ = *(const short8v*)(Bhg + (size_t)64*K);
    bl1_ = *(const short8v*)(Blg + (size_t)64*K);
  }
  if (AMASK && am == 0.f){ ah_ ^= ah_; al_ ^= al_; }
  *(short8v*)&AhS[0][sr][sc] = ah_;
  *(short8v*)&AlS[0][sr][sc] = al_;
  *(short8v*)&BhS[0][sr][sc] = bh0_;
  *(short8v*)&BlS[0][sr][sc] = bl0_;
  if constexpr (NF==4){
    *(short8v*)&BhS[0][sr+64][sc] = bh1_;
    *(short8v*)&BlS[0][sr+64][sc] = bl1_;
  }

  int st = 0;
  for (int s = 0; s < nsteps; ++s){
    if (s+1 < nsteps){
      int ko = (s+1) << 5;
      ah_ = *(const short8v*)(Ahg + ko);
      al_ = *(const short8v*)(Alg + ko);
      bh0_ = *(const short8v*)(Bhg + ko);
      bl0_ = *(const short8v*)(Blg + ko);
      if constexpr (NF==4){
        bh1_ = *(const short8v*)(Bhg + (size_t)64*K + ko);
        bl1_ = *(const short8v*)(Blg + (size_t)64*K + ko);
      }
      if (AMASK && am == 0.f){ ah_ ^= ah_; al_ ^= al_; }
    }
    __syncthreads();
    int fr = lane & 15, fc = (lane >> 4) << 3;
    short8v ahf[2], alf[2], bhf[NF], blf[NF];
    #pragma unroll
    for (int mt=0; mt<2; ++mt){
      int r = (wr<<5) + (mt<<4) + fr;
      ahf[mt] = *(const short8v*)&AhS[st][r][fc];
      alf[mt] = *(const short8v*)&AlS[st][r][fc];
    }
    #pragma unroll
    for (int nt=0; nt<NF; ++nt){
      int r = (NF==4 ? (wc<<6) : (wc<<5)) + (nt<<4) + fr;
      bhf[nt] = *(const short8v*)&BhS[st][r][fc];
      blf[nt] = *(const short8v*)&BlS[st][r][fc];
    }
    #pragma unroll
    for (int mt=0; mt<2; ++mt)
      #pragma unroll
      for (int nt=0; nt<NF; ++nt){
        f32x4 c = acc[mt][nt];
        c = __builtin_amdgcn_mfma_f32_16x16x32_bf16(ahf[mt], bhf[nt], c, 0,0,0);
        c = __builtin_amdgcn_mfma_f32_16x16x32_bf16(ahf[mt], blf[nt], c, 0,0,0);
        c = __builtin_amdgcn_mfma_f32_16x16x32_bf16(alf[mt], bhf[nt], c, 0,0,0);
        acc[mt][nt] = c;
      }
    if (s+1 < nsteps){
      int nb = st ^ 1;
      *(short8v*)&AhS[nb][sr][sc] = ah_;
      *(short8v*)&AlS[nb][sr][sc] = al_;
      *(short8v*)&BhS[nb][sr][sc] = bh0_;
      *(short8v*)&BlS[nb][sr][sc] = bl0_;
      if constexpr (NF==4){
        *(short8v*)&BhS[nb][sr+64][sc] = bh1_;
        *(short8v*)&BlS[nb][sr+64][sc] = bl1_;
      }
    }
    st ^= 1;
  }

  int rb = row0 + (wr<<5) + ((lane>>4)<<2);
  int cb = col0 + (NF==4 ? (wc<<6) : (wc<<5)) + (lane & 15);
  float bs[NF], gm[NF];
  int which = 0;
  if constexpr (EPI==EPI_QKV) which = blockIdx.x >> 2;
  #pragma unroll
  for (int nt=0; nt<NF; ++nt){
    int col = cb + (nt<<4);
    if constexpr (EPI==EPI_QKV){
      const float* bp = (which==0) ? bias : (which==1) ? res : gamma;
      bs[nt] = bp[col & 511];
    } else {
      bs[nt] = bias[col];
      if constexpr (EPI==EPI_RES_GAMMA_MASK) gm[nt] = gamma[col];
    }
  }
  float qscale = 1.f;
  if constexpr (EPI==EPI_QKV) qscale = (which==0) ? scale : 1.f;

  if constexpr (OUT==2){
    if (which == 2){
      #pragma unroll
      for (int mt=0; mt<2; ++mt){
        int row = rb + (mt<<4);
        int b = row >> 9, tok = row & 511;
        #pragma unroll
        for (int nt=0; nt<NF; ++nt){
          int dglob = cb + (nt<<4) - 1024;
          size_t vt = ((size_t)b*512 + dglob)*512 + tok;
          unsigned short h4[4], l4[4];
          #pragma unroll
          for (int j=0; j<4; ++j)
            splitc(acc[mt][nt][j] + bs[nt], h4[j], l4[j]);
          *(ushort4*)&VTh[vt] = make_ushort4(h4[0],h4[1],h4[2],h4[3]);
          *(ushort4*)&VTl[vt] = make_ushort4(l4[0],l4[1],l4[2],l4[3]);
        }
      }
      return;
    }
    #pragma unroll
    for (int mt=0; mt<2; ++mt)
      #pragma unroll
      for (int j=0; j<4; ++j){
        int row = rb + (mt<<4) + j;
        #pragma unroll
        for (int nt=0; nt<NF; ++nt){
          float v = (acc[mt][nt][j] + bs[nt]) * qscale;
          size_t oidx = (size_t)row*O + cb + (nt<<4);
          unsigned short h,l; splitc(v,h,l); Yh[oidx]=h; Yl[oidx]=l;
        }
      }
    return;
  }

  #pragma unroll
  for (int mt=0; mt<2; ++mt)
    #pragma unroll
    for (int j=0; j<4; ++j){
      int row = rb + (mt<<4) + j;
      float rm = 1.f;
      if constexpr (EPI==EPI_RELU_MASK || EPI==EPI_RES_MASK || EPI==EPI_RES_GAMMA_MASK)
        rm = rowmask[row];
      const float* rr = nullptr;
      if constexpr (EPI==EPI_RES || EPI==EPI_RES_MASK || EPI==EPI_RES_GAMMA_MASK)
        rr = res + (size_t)row*O + cb;
      #pragma unroll
      for (int nt=0; nt<NF; ++nt){
        float v = acc[mt][nt][j] + bs[nt];
        if constexpr (EPI==EPI_SCALE) v *= scale;
        else if constexpr (EPI==EPI_QKV) v *= qscale;
        else if constexpr (EPI==EPI_GELU) v = 0.5f*v*(1.f+erff(v*0.7071067811865475f));
        else if constexpr (EPI==EPI_RES) v = rr[nt<<4] + v;
        else if constexpr (EPI==EPI_RELU_MASK) v = fmaxf(v,0.f)*rm;
        else if constexpr (EPI==EPI_RES_MASK) v = rr[nt<<4] + v*rm;
        else if constexpr (EPI==EPI_RES_GAMMA_MASK) v = (rr[nt<<4] + gm[nt]*v)*rm;
        size_t oidx = (size_t)row*O + cb + (nt<<4);
        if constexpr (OUT==0) Y[oidx] = v;
        else if constexpr (OUT==3){
          Y[oidx] = v;
          unsigned short h,l; splitc(v,h,l); Yh[oidx]=h; Yl[oidx]=l;
        }
        else { unsigned short h,l; splitc(v,h,l); Yh[oidx]=h; Yl[oidx]=l; }
      }
    }
}

// ---------------- 128x128x32 MFMA GEMM (big-O + K=2048 O=512 GEMMs) ----------
// OUT: 0 = fp32 Y, 1 = planes, 2 = QKV mode, 3 = fp32 Y + planes.
template<int EPI, bool AMASK, int OUT>
__global__ __launch_bounds__(256) void gemm_big(
    const unsigned short* __restrict__ Ah, const unsigned short* __restrict__ Al,
    const unsigned short* __restrict__ Wh, const unsigned short* __restrict__ Wl,
    const float* __restrict__ bias, const float* __restrict__ res,
    const float* __restrict__ gamma, const float* __restrict__ rowmask,
    float* __restrict__ Y, unsigned short* __restrict__ Yh,
    unsigned short* __restrict__ Yl, unsigned short* __restrict__ VTh,
    unsigned short* __restrict__ VTl, int K, int O, float scale)
{
  __shared__ unsigned short AhS[128][40], AlS[128][40];
  __shared__ unsigned short BhS[128][40], BlS[128][40];
  int t = threadIdx.x;
  int row0 = blockIdx.y << 7, col0 = blockIdx.x << 7;
  int lane = t & 63, wid = t >> 6;
  int wr = wid >> 1, wc = wid & 1;

  int sr = t >> 2, sc = (t & 3) << 3;
  const unsigned short* Ahg = Ah + (size_t)(row0 + sr)*K + sc;
  const unsigned short* Alg = Al + (size_t)(row0 + sr)*K + sc;
  const unsigned short* Bhg = Wh + (size_t)(col0 + sr)*K + sc;
  const unsigned short* Blg = Wl + (size_t)(col0 + sr)*K + sc;
  bool az0 = false, az1 = false;
  if (AMASK){ az0 = (rowmask[row0+sr] == 0.f); az1 = (rowmask[row0+sr+64] == 0.f); }

  f32x4 acc[4][4] = {};
  int nsteps = K >> 5;
  short8v a0h,a0l,a1h,a1l,b0h,b0l,b1h,b1l;
  a0h = *(const short8v*)(Ahg);
  a0l = *(const short8v*)(Alg);
  a1h = *(const short8v*)(Ahg + (size_t)64*K);
  a1l = *(const short8v*)(Alg + (size_t)64*K);
  b0h = *(const short8v*)(Bhg);
  b0l = *(const short8v*)(Blg);
  b1h = *(const short8v*)(Bhg + (size_t)64*K);
  b1l = *(const short8v*)(Blg + (size_t)64*K);

  for (int s = 0; s < nsteps; ++s){
    if (AMASK){
      if (az0){ a0h ^= a0h; a0l ^= a0l; }
      if (az1){ a1h ^= a1h; a1l ^= a1l; }
    }
    __syncthreads();
    *(short8v*)&AhS[sr][sc] = a0h;    *(short8v*)&AlS[sr][sc] = a0l;
    *(short8v*)&AhS[sr+64][sc] = a1h; *(short8v*)&AlS[sr+64][sc] = a1l;
    *(short8v*)&BhS[sr][sc] = b0h;    *(short8v*)&BlS[sr][sc] = b0l;
    *(short8v*)&BhS[sr+64][sc] = b1h; *(short8v*)&BlS[sr+64][sc] = b1l;
    __syncthreads();
    if (s+1 < nsteps){
      int ko = (s+1) << 5;
      a0h = *(const short8v*)(Ahg + ko);
      a0l = *(const short8v*)(Alg + ko);
      a1h = *(const short8v*)(Ahg + (size_t)64*K + ko);
      a1l = *(const short8v*)(Alg + (size_t)64*K + ko);
      b0h = *(const short8v*)(Bhg + ko);
      b0l = *(const short8v*)(Blg + ko);
      b1h = *(const short8v*)(Bhg + (size_t)64*K + ko);
      b1l = *(const short8v*)(Blg + (size_t)64*K + ko);
    }
    int fr = lane & 15, fc = (lane >> 4) << 3;
    short8v ahf[4], alf[4], bhf[4], blf[4];
    #pragma unroll
    for (int mt=0; mt<4; ++mt){
      int r = (wr<<6) + (mt<<4) + fr;
      ahf[mt] = *(const short8v*)&AhS[r][fc];
      alf[mt] = *(const short8v*)&AlS[r][fc];
    }
    #pragma unroll
    for (int nt=0; nt<4; ++nt){
      int r = (wc<<6) + (nt<<4) + fr;
      bhf[nt] = *(const short8v*)&BhS[r][fc];
      blf[nt] = *(const short8v*)&BlS[r][fc];
    }
    #pragma unroll
    for (int mt=0; mt<4; ++mt)
      #pragma unroll
      for (int nt=0; nt<4; ++nt){
        f32x4 c = acc[mt][nt];
        c = __builtin_amdgcn_mfma_f32_16x16x32_bf16(ahf[mt], bhf[nt], c, 0,0,0);
        c = __builtin_amdgcn_mfma_f32_16x16x32_bf16(ahf[mt], blf[nt], c, 0,0,0);
        c = __builtin_amdgcn_mfma_f32_16x16x32_bf16(alf[mt], bhf[nt], c, 0,0,0);
        acc[mt][nt] = c;
      }
  }

  int rb = row0 + (wr<<6) + ((lane>>4)<<2);
  int cb = col0 + (wc<<6) + (lane & 15);
  float bs[4], gm[4];
  int which = 0;
  if constexpr (EPI==EPI_QKV) which = blockIdx.x >> 2;
  #pragma unroll
  for (int nt=0; nt<4; ++nt){
    int col = cb + (nt<<4);
    if constexpr (EPI==EPI_QKV){
      const float* bp = (which==0) ? bias : (which==1) ? res : gamma;
      bs[nt] = bp[col & 511];
    } else {
      bs[nt] = bias[col];
      if constexpr (EPI==EPI_RES_GAMMA_MASK) gm[nt] = gamma[col];
    }
  }
  float qscale = 1.f;
  if constexpr (EPI==EPI_QKV) qscale = (which==0) ? scale : 1.f;

  if constexpr (OUT==2){
    if (which == 2){
      #pragma unroll
      for (int mt=0; mt<4; ++mt){
        int row = rb + (mt<<4);
        int b = row >> 9, tok = row & 511;
        #pragma unroll
        for (int nt=0; nt<4; ++nt){
          int dglob = cb + (nt<<4) - 1024;
          size_t vt = ((size_t)b*512 + dglob)*512 + tok;
          unsigned short h4[4], l4[4];
          #pragma unroll
          for (int j=0; j<4; ++j)
            splitc(acc[mt][nt][j] + bs[nt], h4[j], l4[j]);
          *(ushort4*)&VTh[vt] = make_ushort4(h4[0],h4[1],h4[2],h4[3]);
          *(ushort4*)&VTl[vt] = make_ushort4(l4[0],l4[1],l4[2],l4[3]);
        }
      }
      return;
    }
    #pragma unroll
    for (int mt=0; mt<4; ++mt)
      #pragma unroll
      for (int j=0; j<4; ++j){
        int row = rb + (mt<<4) + j;
        #pragma unroll
        for (int nt=0; nt<4; ++nt){
          float v = (acc[mt][nt][j] + bs[nt]) * qscale;
          size_t oidx = (size_t)row*O + cb + (nt<<4);
          unsigned short h,l; splitc(v,h,l); Yh[oidx]=h; Yl[oidx]=l;
        }
      }
    return;
  }

  #pragma unroll
  for (int mt=0; mt<4; ++mt)
    #pragma unroll
    for (int j=0; j<4; ++j){
      int row = rb + (mt<<4) + j;
      float rm = 1.f;
      if constexpr (EPI==EPI_RELU_MASK || EPI==EPI_RES_MASK || EPI==EPI_RES_GAMMA_MASK)
        rm = rowmask[row];
      const float* rr = nullptr;
      if constexpr (EPI==EPI_RES || EPI==EPI_RES_MASK || EPI==EPI_RES_GAMMA_MASK)
        rr = res + (size_t)row*O + cb;
      #pragma unroll
      for (int nt=0; nt<4; ++nt){
        float v = acc[mt][nt][j] + bs[nt];
        if constexpr (EPI==EPI_GELU) v = 0.5f*v*(1.f+erff(v*0.7071067811865475f));
        else if constexpr (EPI==EPI_RELU_MASK) v = fmaxf(v,0.f)*rm;
        else if constexpr (EPI==EPI_RES) v = rr[nt<<4] + v;
        else if constexpr (EPI==EPI_RES_MASK) v = rr[nt<<4] + v*rm;
        else if constexpr (EPI==EPI_RES_GAMMA_MASK) v = (rr[nt<<4] + gm[nt]*v)*rm;
        size_t oidx = (size_t)row*O + cb + (nt<<4);
        if constexpr (OUT==0) Y[oidx] = v;
        else if constexpr (OUT==3){
          Y[oidx] = v;
          unsigned short h,l; splitc(v,h,l); Yh[oidx]=h; Yl[oidx]=l;
        }
        else { unsigned short h,l; splitc(v,h,l); Yh[oidx]=h; Yl[oidx]=l; }
      }
    }
}

// ---------------- MFMA windowed-rel attention v4: 2 Q-tiles per block --------
__global__ __launch_bounds__(256) void attn_mf(
    const unsigned short* __restrict__ Ph_g, const unsigned short* __restrict__ Pl_g,
    const unsigned short* __restrict__ VTh_g, const unsigned short* __restrict__ VTl_g,
    const float* __restrict__ relk, const float* __restrict__ relv,
    const float* __restrict__ mask, unsigned short* __restrict__ Oh,
    unsigned short* __restrict__ Ol)
{
  __shared__ float ms_[512];
  __shared__ float rv[9][64];
  __shared__ float qrel[32][16];
  __shared__ float red1[4][32];
  __shared__ float red2[4][32];
  __shared__ __align__(16) unsigned short Spool[32*520];
  unsigned short (*Qh)[72]  = (unsigned short(*)[72])(Spool);          // [32][72]
  unsigned short (*Ql)[72]  = (unsigned short(*)[72])(Spool + 2304);   // [32][72]
  unsigned short (*Rkh)[72] = (unsigned short(*)[72])(Spool + 4608);   // [16][72]
  unsigned short (*Rkl)[72] = (unsigned short(*)[72])(Spool + 5760);   // [16][72]
  unsigned short (*Sp)[520] = (unsigned short(*)[520])(Spool);         // [32][520]

  int id = blockIdx.x;
  int xcd = id & 7, kk = id >> 3;
  int bh_ = xcd*8 + (kk >> 4);
  int qt = kk & 15;
  int h = bh_ & 7, b_ = bh_ >> 3;
  int t = threadIdx.x;
  int l0 = qt * 32;
  const size_t rowoff = (size_t)b_ * 512;
  int lane = t & 63, w = t >> 6;

  ms_[t] = mask[rowoff + t]; ms_[t+256] = mask[rowoff + t + 256];
  for (int i = t; i < 576; i += 256) ((float*)rv)[i] = relv[i];
  {
    int r = t >> 4, c = (t & 15) << 2;
    float4 v;
    if (r < 9) v = *(const float4*)&relk[r*64 + c];
    else { v.x=0.f; v.y=0.f; v.z=0.f; v.w=0.f; }
    split4(v, &Rkh[r][c], &Rkl[r][c]);
  }
  for (int i = t; i < 512; i += 256){
    int r = (i & 255) >> 3, c = (i & 7) << 3;
    size_t g = (rowoff + l0 + r)*QKVS + h*64 + c;
    if (i < 256) *(short8v*)&Qh[r][c] = *(const short8v*)&Ph_g[g];
    else         *(short8v*)&Ql[r][c] = *(const short8v*)&Pl_g[g];
  }
  __syncthreads();

  int fr = lane & 15, fc = (lane >> 4) << 3;
  int qbase = (lane>>4) << 2;
  short8v a0h0 = *(const short8v*)&Qh[fr][fc];
  short8v a0h1 = *(const short8v*)&Qh[fr][32+fc];
  short8v a0l0 = *(const short8v*)&Ql[fr][fc];
  short8v a0l1 = *(const short8v*)&Ql[fr][32+fc];
  short8v a1h0 = *(const short8v*)&Qh[16+fr][fc];
  short8v a1h1 = *(const short8v*)&Qh[16+fr][32+fc];
  short8v a1l0 = *(const short8v*)&Ql[16+fr][fc];
  short8v a1l1 = *(const short8v*)&Ql[16+fr][32+fc];

  if (w < 2){
    short8v rh0 = *(const short8v*)&Rkh[fr][fc];
    short8v rh1 = *(const short8v*)&Rkh[fr][32+fc];
    short8v rl0 = *(const short8v*)&Rkl[fr][fc];
    short8v rl1 = *(const short8v*)&Rkl[fr][32+fc];
    short8v qa0 = (w==0) ? a0h0 : a1h0;
    short8v qa1 = (w==0) ? a0h1 : a1h1;
    short8v qb0 = (w==0) ? a0l0 : a1l0;
    short8v qb1 = (w==0) ? a0l1 : a1l1;
    f32x4 c4 = {};
    c4 = __builtin_amdgcn_mfma_f32_16x16x32_bf16(qa0,rh0,c4,0,0,0);
    c4 = __builtin_amdgcn_mfma_f32_16x16x32_bf16(qa1,rh1,c4,0,0,0);
    c4 = __builtin_amdgcn_mfma_f32_16x16x32_bf16(qa0,rl0,c4,0,0,0);
    c4 = __builtin_amdgcn_mfma_f32_16x16x32_bf16(qa1,rl1,c4,0,0,0);
    c4 = __builtin_amdgcn_mfma_f32_16x16x32_bf16(qb0,rh0,c4,0,0,0);
    c4 = __builtin_amdgcn_mfma_f32_16x16x32_bf16(qb1,rh1,c4,0,0,0);
    #pragma unroll
    for (int j = 0; j < 4; ++j) qrel[w*16 + qbase + j][fr] = c4[j];
  }
  __syncthreads();   // after this: Q/Rk LDS dead, P region live

  f32x4 sreg0[8], sreg1[8];
  #pragma unroll
  for (int tt = 0; tt < 8; ++tt){
    int br = tt*64 + w*16 + fr;
    const unsigned short* krh = Ph_g + (rowoff + br)*QKVS + 512 + h*64;
    const unsigned short* krl = Pl_g + (rowoff + br)*QKVS + 512 + h*64;
    short8v bh0 = *(const short8v*)(krh + fc);
    short8v bh1 = *(const short8v*)(krh + 32 + fc);
    short8v bl0 = *(const short8v*)(krl + fc);
    short8v bl1 = *(const short8v*)(krl + 32 + fc);
    f32x4 c0 = {}, c1 = {};
    c0 = __builtin_amdgcn_mfma_f32_16x16x32_bf16(a0h0,bh0,c0,0,0,0);
    c1 = __builtin_amdgcn_mfma_f32_16x16x32_bf16(a1h0,bh0,c1,0,0,0);
    c0 = __builtin_amdgcn_mfma_f32_16x16x32_bf16(a0h1,bh1,c0,0,0,0);
    c1 = __builtin_amdgcn_mfma_f32_16x16x32_bf16(a1h1,bh1,c1,0,0,0);
    c0 = __builtin_amdgcn_mfma_f32_16x16x32_bf16(a0h0,bl0,c0,0,0,0);
    c1 = __builtin_amdgcn_mfma_f32_16x16x32_bf16(a1h0,bl0,c1,0,0,0);
    c0 = __builtin_amdgcn_mfma_f32_16x16x32_bf16(a0h1,bl1,c0,0,0,0);
    c1 = __builtin_amdgcn_mfma_f32_16x16x32_bf16(a1h1,bl1,c1,0,0,0);
    c0 = __builtin_amdgcn_mfma_f32_16x16x32_bf16(a0l0,bh0,c0,0,0,0);
    c1 = __builtin_amdgcn_mfma_f32_16x16x32_bf16(a1l0,bh0,c1,0,0,0);
    c0 = __builtin_amdgcn_mfma_f32_16x16x32_bf16(a0l1,bh1,c0,0,0,0);
    c1 = __builtin_amdgcn_mfma_f32_16x16x32_bf16(a1l1,bh1,c1,0,0,0);
    int m = tt*64 + w*16 + fr;
    float mm_ = ms_[m];
    #pragma unroll
    for (int j = 0; j < 4; ++j){
      int q = qbase + j;
      {
        int l = l0 + q;
        float s = c0[j];
        int dlt = m - l + 4;
        if (dlt >= 0 && dlt <= 8) s += qrel[q][dlt];
        if (ms_[l] * mm_ == 0.f) s = -10000.f;
        c0[j] = s;
      }
      {
        int l = l0 + 16 + q;
        float s = c1[j];
        int dlt = m - l + 4;
        if (dlt >= 0 && dlt <= 8) s += qrel[16 + q][dlt];
        if (ms_[l] * mm_ == 0.f) s = -10000.f;
        c1[j] = s;
      }
    }
    sreg0[tt] = c0; sreg1[tt] = c1;
  }

  float mx0[4], mx1[4], sm0[4], sm1[4], inv0[4], inv1[4];
  #pragma unroll
  for (int j = 0; j < 4; ++j){
    float v0 = sreg0[0][j], v1 = sreg1[0][j];
    #pragma unroll
    for (int tt = 1; tt < 8; ++tt){
      v0 = fmaxf(v0, sreg0[tt][j]);
      v1 = fmaxf(v1, sreg1[tt][j]);
    }
    #pragma unroll
    for (int o = 8; o >= 1; o >>= 1){
      v0 = fmaxf(v0, __shfl_xor(v0, o));
      v1 = fmaxf(v1, __shfl_xor(v1, o));
    }
    mx0[j] = v0; mx1[j] = v1;
  }
  if (fr == 0){
    #pragma unroll
    for (int j = 0; j < 4; ++j){
      red1[w][qbase + j] = mx0[j];
      red1[w][16 + qbase + j] = mx1[j];
    }
  }
  __syncthreads();
  #pragma unroll
  for (int j = 0; j < 4; ++j){
    int q = qbase + j;
    mx0[j] = fmaxf(fmaxf(red1[0][q], red1[1][q]), fmaxf(red1[2][q], red1[3][q]));
    mx1[j] = fmaxf(fmaxf(red1[0][16+q], red1[1][16+q]), fmaxf(red1[2][16+q], red1[3][16+q]));
  }
  #pragma unroll
  for (int j = 0; j < 4; ++j){ sm0[j] = 0.f; sm1[j] = 0.f; }
  #pragma unroll
  for (int tt = 0; tt < 8; ++tt){
    f32x4 c0 = sreg0[tt], c1 = sreg1[tt];
    #pragma unroll
    for (int j = 0; j < 4; ++j){
      float e0 = expf(c0[j] - mx0[j]);
      float e1 = expf(c1[j] - mx1[j]);
      c0[j] = e0; c1[j] = e1;
      sm0[j] += e0; sm1[j] += e1;
    }
    sreg0[tt] = c0; sreg1[tt] = c1;
  }
  #pragma unroll
  for (int j = 0; j < 4; ++j){
    float v0 = sm0[j], v1 = sm1[j];
    #pragma unroll
    for (int o = 8; o >= 1; o >>= 1){
      v0 += __shfl_xor(v0, o);
      v1 += __shfl_xor(v1, o);
    }
    sm0[j] = v0; sm1[j] = v1;
  }
  if (fr == 0){
    #pragma unroll
    for (int j = 0; j < 4; ++j){
      red2[w][qbase + j] = sm0[j];
      red2[w][16 + qbase + j] = sm1[j];
    }
  }
  #pragma unroll
  for (int tt = 0; tt < 8; ++tt){
    int m = tt*64 + w*16 + fr;
    #pragma unroll
    for (int j = 0; j < 4; ++j){
      Sp[qbase + j][m]      = f2bf_rne(sreg0[tt][j]);
      Sp[16 + qbase + j][m] = f2bf_rne(sreg1[tt][j]);
    }
  }
  __syncthreads();
  #pragma unroll
  for (int j = 0; j < 4; ++j){
    int q = qbase + j;
    inv0[j] = 1.f / (red2[0][q] + red2[1][q] + red2[2][q] + red2[3][q]);
    inv1[j] = 1.f / (red2[0][16+q] + red2[1][16+q] + red2[2][16+q] + red2[3][16+q]);
  }

  f32x4 oacc0 = {}, oacc1 = {};
  const unsigned short* vrh = VTh_g + ((size_t)b_*512 + h*64 + w*16 + fr)*512;
  const unsigned short* vrl = VTl_g + ((size_t)b_*512 + h*64 + w*16 + fr)*512;
  #pragma unroll
  for (int tt = 0; tt < 8; ++tt){
    #pragma unroll
    for (int ks = 0; ks < 2; ++ks){
      int moff = tt*64 + ks*32 + fc;
      short8v ap0 = *(const short8v*)&Sp[fr][moff];
      short8v ap1 = *(const short8v*)&Sp[16+fr][moff];
      short8v bh = *(const short8v*)(vrh + moff);
      short8v bl = *(const short8v*)(vrl + moff);
      oacc0 = __builtin_amdgcn_mfma_f32_16x16x32_bf16(ap0,bh,oacc0,0,0,0);
      oacc1 = __builtin_amdgcn_mfma_f32_16x16x32_bf16(ap1,bh,oacc1,0,0,0);
      oacc0 = __builtin_amdgcn_mfma_f32_16x16x32_bf16(ap0,bl,oacc0,0,0,0);
      oacc1 = __builtin_amdgcn_mfma_f32_16x16x32_bf16(ap1,bl,oacc1,0,0,0);
    }
  }
  {
    int d = w*16 + fr;
    #pragma unroll
    for (int j = 0; j < 4; ++j){
      {
        int q = qbase + j;
        int l = l0 + q;
        float val = oacc0[j];
        #pragma unroll
        for (int dlt = 0; dlt < 9; ++dlt){
          int m = l + dlt - 4;
          if (m >= 0 && m < 512){
            float e = bf2f(Sp[q][m]);
            val += e * rv[dlt][d];
          }
        }
        val *= inv0[j];
        unsigned short hh, ll_; splitc(val, hh, ll_);
        size_t oidx = ((rowoff + l) << 9) + h*64 + d;
        Oh[oidx] = hh; Ol[oidx] = ll_;
      }
      {
        int q = 16 + qbase + j;
        int l = l0 + q;
        float val = oacc1[j];
        #pragma unroll
        for (int dlt = 0; dlt < 9; ++dlt){
          int m = l + dlt - 4;
          if (m >= 0 && m < 512){
            float e = bf2f(Sp[q][m]);
            val += e * rv[dlt][d];
          }
        }
        val *= inv1[j];
        unsigned short hh, ll_; splitc(val, hh, ll_);
        size_t oidx = ((rowoff + l) << 9) + h*64 + d;
        Oh[oidx] = hh; Ol[oidx] = ll_;
      }
    }
  }
}

// ---------------- final transpose ----------------
__global__ __launch_bounds__(256) void transpose_out_k(const float* __restrict__ xn,
    const float* __restrict__ mask, float* __restrict__ out){
  __shared__ float tile[32][33];
  int b_ = blockIdx.z; int c0 = blockIdx.x*32; int l0 = blockIdx.y*32;
  int tx = threadIdx.x & 31, ty = threadIdx.x >> 5;
  #pragma unroll
  for (int r=0;r<4;r++){
    int l = l0 + ty + r*8;
    tile[ty + r*8][tx] = xn[(((size_t)(b_*512 + l))<<9) + c0 + tx];
  }
  __syncthreads();
  float mm = mask[b_*512 + l0 + tx];
  #pragma unroll
  for (int r=0;r<4;r++){
    int c = c0 + ty + r*8;
    out[(((size_t)(b_*512 + c))<<9) + l0 + tx] = tile[tx][ty + r*8] * mm;
  }
}

extern "C" void kernel_launch(void* const* d_in, const int* in_sizes, int n_in,
                              void* d_out, int out_size, void* d_ws, size_t ws_size,
                              hipStream_t stream) {
  const int*   tokens   = (const int*)  d_in[0];
  const float* style_v  = (const float*)d_in[1];
  const float* mask     = (const float*)d_in[2];
  const float* embed_w  = (const float*)d_in[3];
  const float* cw_dw_w  = (const float*)d_in[4];
  const float* cw_dw_b  = (const float*)d_in[5];
  const float* cw_ln_g  = (const float*)d_in[6];
  const float* cw_ln_b  = (const float*)d_in[7];
  const float* cw_pw1_w = (const float*)d_in[8];
  const float* cw_pw1_b = (const float*)d_in[9];
  const float* cw_pw2_w = (const float*)d_in[10];
  const float* cw_pw2_b = (const float*)d_in[11];
  const float* cw_gamma = (const float*)d_in[12];
  const float* aq_w = (const float*)d_in[13];
  const float* aq_b = (const float*)d_in[14];
  const float* ak_w = (const float*)d_in[15];
  const float* ak_b = (const float*)d_in[16];
  const float* av_w = (const float*)d_in[17];
  const float* av_b = (const float*)d_in[18];
  const float* ao_w = (const float*)d_in[19];
  const float* ao_b = (const float*)d_in[20];
  const float* rel_k = (const float*)d_in[21];
  const float* rel_v = (const float*)d_in[22];
  const float* ln1_g = (const float*)d_in[23];
  const float* ln1_b = (const float*)d_in[24];
  const float* ln2_g = (const float*)d_in[25];
  const float* ln2_b = (const float*)d_in[26];
  const float* ffn_w1 = (const float*)d_in[27];
  const float* ffn_b1 = (const float*)d_in[28];
  const float* ffn_w2 = (const float*)d_in[29];
  const float* ffn_b2 = (const float*)d_in[30];
  const float* style_key = (const float*)d_in[31];
  const float* sq_w = (const float*)d_in[32];
  const float* sq_b = (const float*)d_in[33];
  const float* sk_w = (const float*)d_in[34];
  const float* sk_b = (const float*)d_in[35];
  const float* sv_w = (const float*)d_in[36];
  const float* sv_b = (const float*)d_in[37];
  const float* so_w = (const float*)d_in[38];
  const float* so_b = (const float*)d_in[39];
  const float* sn_g = (const float*)d_in[40];
  const float* sn_b = (const float*)d_in[41];

  const int N = NROWS;
  char* cur = (char*)d_ws;
  auto nextF = [&](size_t n)->float*{ float* p=(float*)cur; cur += n*sizeof(float); return p; };
  auto nextU = [&](size_t n)->unsigned short*{ unsigned short* p=(unsigned short*)cur; cur += n*2; return p; };

  float* X   = nextF((size_t)N*512);
  float* T   = nextF((size_t)N*512);
  float* Qb  = nextF((size_t)N*512);
  float* Vb  = nextF((size_t)N*512);
  unsigned short* Xh = nextU((size_t)N*512);
  unsigned short* Xl = nextU((size_t)N*512);
  unsigned short* Th = nextU((size_t)N*512);
  unsigned short* Tl = nextU((size_t)N*512);
  unsigned short* Hbh = nextU((size_t)N*2048);
  unsigned short* Hbl = nextU((size_t)N*2048);
  unsigned short* QKVh = nextU((size_t)N*QKVS);
  unsigned short* QKVl = nextU((size_t)N*QKVS);
  unsigned short* VTh = nextU((size_t)8*512*512);
  unsigned short* VTl = nextU((size_t)8*512*512);
  // weight planes
  unsigned short* pw1h = nextU(4194304); unsigned short* pw1l = nextU(4194304);
  unsigned short* pw2h = nextU(4194304); unsigned short* pw2l = nextU(4194304);
  unsigned short* qkvh = nextU((size_t)6*QKVS*512); unsigned short* qkvl = nextU((size_t)6*QKVS*512);
  unsigned short* aoh  = nextU(1572864); unsigned short* aol  = nextU(1572864);
  unsigned short* f1h  = nextU(6291456); unsigned short* f1l  = nextU(6291456);
  unsigned short* f2h  = nextU(6291456); unsigned short* f2l  = nextU(6291456);
  unsigned short* sqh  = nextU(524288);  unsigned short* sql  = nextU(524288);
  unsigned short* soh  = nextU(524288);  unsigned short* sol  = nextU(524288);
  // style planes: KKp [2 layers][2 heads][64][256]; VTp [2][2][256][64]
  unsigned short* KKsh = nextU(65536); unsigned short* KKsl = nextU(65536);
  unsigned short* VTsh = nextU(65536); unsigned short* VTsl = nextU(65536);

  // ---- weight prep (single merged launch) ----
  split_all<<<dim3(512,8),256,0,stream>>>(cw_pw1_w, cw_pw2_w, ao_w, ffn_w1,
      ffn_w2, sq_w, so_w, aq_w, ak_w, av_w,
      pw1h, pw1l, pw2h, pw2l, aoh, aol, f1h, f1l, f2h, f2l,
      sqh, sql, soh, sol, qkvh, qkvl);

  dim3 gm512(8,64), gbig2048(16,32), gbigqkv(12,32), gbig512(4,32);

  embed_k<<<4096,128,0,stream>>>(tokens, embed_w, mask, X);

  // ---- ConvNeXt blocks (dwconv+LN fused; K=2048 pw2 via 128x128 tile) ----
  for (int i=0;i<4;i++){
    dwln_k<<<4096,128,0,stream>>>(X, cw_dw_w + (size_t)i*512*5, cw_dw_b + i*512,
        mask, cw_ln_g+i*512, cw_ln_b+i*512, Th, Tl);
    gemm_big<EPI_GELU,false,1><<<gbig2048,256,0,stream>>>(Th, Tl,
        pw1h + (size_t)i*1048576, pw1l + (size_t)i*1048576,
        cw_pw1_b+i*2048, nullptr, nullptr, nullptr, nullptr, Hbh, Hbl,
        nullptr, nullptr, 512, 2048, 0.f);
    if (i < 3)
      gemm_big<EPI_RES_GAMMA_MASK,false,0><<<gbig512,256,0,stream>>>(Hbh, Hbl,
          pw2h + (size_t)i*1048576, pw2l + (size_t)i*1048576,
          cw_pw2_b+i*512, X, cw_gamma+i*512, mask, X, nullptr, nullptr,
          nullptr, nullptr, 2048, 512, 0.f);
    else
      gemm_big<EPI_RES_GAMMA_MASK,false,3><<<gbig512,256,0,stream>>>(Hbh, Hbl,
          pw2h + (size_t)i*1048576, pw2l + (size_t)i*1048576,
          cw_pw2_b+i*512, X, cw_gamma+i*512, mask, X, Xh, Xl,
          nullptr, nullptr, 2048, 512, 0.f);
  }

  // ---- Attention layers ----
  for (int i=0;i<6;i++){
    gemm_big<EPI_QKV,false,2><<<gbigqkv,256,0,stream>>>(Xh, Xl,
        qkvh + (size_t)i*QKVS*512, qkvl + (size_t)i*QKVS*512,
        aq_b+i*512, ak_b+i*512, av_b+i*512, nullptr, nullptr, QKVh, QKVl,
        VTh, VTl, 512, QKVS, 0.125f);
    attn_mf<<<1024,256,0,stream>>>(QKVh, QKVl, VTh, VTl,
        rel_k + (size_t)i*9*64, rel_v + (size_t)i*9*64, mask, Th, Tl);
    gemm_ps<EPI_RES,false,0,2><<<gm512,256,0,stream>>>(Th, Tl,
        aoh + (size_t)i*262144, aol + (size_t)i*262144,
        ao_b+i*512, X, nullptr, nullptr, Qb, nullptr, nullptr,
        nullptr, nullptr, 512, 512, 0.f);
    ln_rows<true,false><<<1024,256,0,stream>>>(Qb, ln1_g+i*512, ln1_b+i*512,
        nullptr, X, Xh, Xl, N);
    gemm_big<EPI_RELU_MASK,true,1><<<gbig2048,256,0,stream>>>(Xh, Xl,
        f1h + (size_t)i*1048576, f1l + (size_t)i*1048576,
        ffn_b1+i*2048, nullptr, nullptr, mask, nullptr, Hbh, Hbl,
        nullptr, nullptr, 512, 2048, 0.f);
    gemm_big<EPI_RES_MASK,false,0><<<gbig512,256,0,stream>>>(Hbh, Hbl,
        f2h + (size_t)i*1048576, f2l + (size_t)i*1048576,
        ffn_b2+i*512, X, nullptr, mask, Qb, nullptr, nullptr,
        nullptr, nullptr, 2048, 512, 0.f);
    if (i < 5)
      ln_rows<true,false><<<1024,256,0,stream>>>(Qb, ln2_g+i*512, ln2_b+i*512,
          nullptr, X, Xh, Xl, N);
    else
      ln_rows<true,true><<<1024,256,0,stream>>>(Qb, ln2_g+i*512, ln2_b+i*512,
          mask, X, Xh, Xl, N);
  }

  // ---- Style attention (MFMA path) ----
  style_prep<<<dim3(8,4),256,0,stream>>>(style_key, style_v, sk_w, sk_b,
      sv_w, sv_b, KKsh, KKsl, VTsh, VTsl);

  // layer 0: xin = masked X -> Q planes -> style_mf -> so gemm (x1 planes)
  gemm_ps<EPI_BIAS,false,1,2><<<gm512,256,0,stream>>>(Xh, Xl, sqh, sql,
      sq_b, nullptr, nullptr, nullptr, nullptr, QKVh, QKVl,
      nullptr, nullptr, 512, 512, 0.f);
  style_mf<<<256,256,0,stream>>>(QKVh, QKVl, KKsh, KKsl, VTsh, VTsl,
      mask, Th, Tl);
  gemm_ps<EPI_RES_MASK,false,1,2><<<gm512,256,0,stream>>>(Th, Tl, soh, sol,
      so_b, X, nullptr, mask, nullptr, Hbh, Hbl,
      nullptr, nullptr, 512, 512, 0.f);   // x1 planes
  // layer 1: xin = x1 (planes); residual xt = X
  gemm_ps<EPI_BIAS,false,1,2><<<gm512,256,0,stream>>>(Hbh, Hbl, sqh+262144, sql+262144,
      sq_b+512, nullptr, nullptr, nullptr, nullptr, QKVh, QKVl,
      nullptr, nullptr, 512, 512, 0.f);
  style_mf<<<256,256,0,stream>>>(QKVh, QKVl, KKsh+32768, KKsl+32768,
      VTsh+32768, VTsl+32768, mask, Th, Tl);
  gemm_ps<EPI_RES_MASK,false,0,2><<<gm512,256,0,stream>>>(Th, Tl, soh+262144, sol+262144,
      so_b+512, X, nullptr, mask, Vb, nullptr, nullptr,
      nullptr, nullptr, 512, 512, 0.f);  // x2

  ln_rows<false,false><<<1024,256,0,stream>>>(Vb, sn_g, sn_b, nullptr,
      Qb, nullptr, nullptr, N);
  transpose_out_k<<<dim3(16,16,8),256,0,stream>>>(Qb, mask, (float*)d_out);
}

// Round 27
// 1706.339 us; speedup vs baseline: 1.1090x; 1.1090x over previous
//
#include <hip/hip_runtime.h>
#include <cstdint>

#define Bb 8
#define Ll 512
#define Cc 512
#define Hh 8
#define HD 64
#define Ff 2048
#define Ss 50
#define NROWS 4096   // B*L
#define QKVS 1536

typedef __attribute__((ext_vector_type(8))) short short8v;  // 8 bf16 (4 VGPR)
typedef __attribute__((ext_vector_type(4))) float f32x4;

__device__ __forceinline__ float wave_sum(float v){
  #pragma unroll
  for (int o=32;o>=1;o>>=1) v += __shfl_xor(v,o);
  return v;
}
__device__ __forceinline__ float bf2f(unsigned short u){
  return __uint_as_float(((unsigned)u) << 16);
}

// cheap split: hi = trunc-bf16(a); lo = trunc-bf16(a - hi). err ~ 2^-16 |a|
__device__ __forceinline__ void splitc(float a, unsigned short& hi, unsigned short& lo){
  unsigned u = __float_as_uint(a);
  hi = (unsigned short)(u >> 16);
  float l = a - __uint_as_float(u & 0xFFFF0000u);
  lo = (unsigned short)(__float_as_uint(l) >> 16);
}
__device__ __forceinline__ unsigned short f2bf_rne(float a){
  unsigned u = __float_as_uint(a);
  unsigned r = u + 0x7FFFu + ((u >> 16) & 1u);
  return (unsigned short)(r >> 16);
}
__device__ __forceinline__ void split4(float4 v, unsigned short* hi, unsigned short* lo){
  unsigned short h0,h1,h2,h3,l0,l1,l2,l3;
  splitc(v.x,h0,l0); splitc(v.y,h1,l1); splitc(v.z,h2,l2); splitc(v.w,h3,l3);
  *(ushort4*)hi = make_ushort4(h0,h1,h2,h3);
  *(ushort4*)lo = make_ushort4(l0,l1,l2,l3);
}

// ---------------- merged weight split: 8 segments in one launch --------------
__global__ __launch_bounds__(256) void split_all(
    const float* __restrict__ pw1w, const float* __restrict__ pw2w,
    const float* __restrict__ aow,  const float* __restrict__ f1w,
    const float* __restrict__ f2w,  const float* __restrict__ sqw,
    const float* __restrict__ sow,
    const float* __restrict__ aqw, const float* __restrict__ akw,
    const float* __restrict__ avw,
    unsigned short* __restrict__ pw1h, unsigned short* __restrict__ pw1l,
    unsigned short* __restrict__ pw2h, unsigned short* __restrict__ pw2l,
    unsigned short* __restrict__ aoh,  unsigned short* __restrict__ aol,
    unsigned short* __restrict__ f1h,  unsigned short* __restrict__ f1l,
    unsigned short* __restrict__ f2h,  unsigned short* __restrict__ f2l,
    unsigned short* __restrict__ sqh,  unsigned short* __restrict__ sql,
    unsigned short* __restrict__ soh,  unsigned short* __restrict__ sol,
    unsigned short* __restrict__ qkvh, unsigned short* __restrict__ qkvl)
{
  int seg = blockIdx.y;
  if (seg == 7){
    const int n4 = 6*QKVS*512/4;
    for (int i = blockIdx.x*256 + threadIdx.x; i < n4; i += gridDim.x*256){
      int e = i << 2;
      int layer = e / 786432;
      int r = e - layer*786432;
      int which = r >> 18;
      int off = r & 262143;
      const float* s = (which==0) ? aqw : (which==1) ? akw : avw;
      float4 vv = *(const float4*)(s + (size_t)layer*262144 + off);
      split4(vv, (unsigned short*)((ushort4*)qkvh + i),
                 (unsigned short*)((ushort4*)qkvl + i));
    }
    return;
  }
  const float* src; unsigned short* hi; unsigned short* lo; int n4;
  switch(seg){
    case 0: src=pw1w; hi=pw1h; lo=pw1l; n4=1048576; break;
    case 1: src=pw2w; hi=pw2h; lo=pw2l; n4=1048576; break;
    case 2: src=aow;  hi=aoh;  lo=aol;  n4=393216;  break;
    case 3: src=f1w;  hi=f1h;  lo=f1l;  n4=1572864; break;
    case 4: src=f2w;  hi=f2h;  lo=f2l;  n4=1572864; break;
    case 5: src=sqw;  hi=sqh;  lo=sql;  n4=131072;  break;
    default: src=sow; hi=soh;  lo=sol;  n4=131072;  break;
  }
  for (int i = blockIdx.x*256 + threadIdx.x; i < n4; i += gridDim.x*256){
    float4 v = ((const float4*)src)[i];
    split4(v, (unsigned short*)((ushort4*)hi + i), (unsigned short*)((ushort4*)lo + i));
  }
}

// ---------------- embed gather (mask fused) ----------------
__global__ __launch_bounds__(128) void embed_k(const int* __restrict__ tok,
    const float* __restrict__ emb, const float* __restrict__ mask,
    float* __restrict__ x){
  int n = blockIdx.x;
  int t = tok[n];
  float m = mask[n];
  float4 v = ((const float4*)(emb + ((size_t)t<<9)))[threadIdx.x];
  v.x*=m; v.y*=m; v.z*=m; v.w*=m;
  ((float4*)(x + ((size_t)n<<9)))[threadIdx.x] = v;
}

// ---------------- FUSED depthwise conv K=5 + bias + mask + LayerNorm + split --
__global__ __launch_bounds__(128) void dwln_k(const float* __restrict__ x,
    const float* __restrict__ w, const float* __restrict__ bias,
    const float* __restrict__ mask, const float* __restrict__ g,
    const float* __restrict__ bt, unsigned short* __restrict__ yh,
    unsigned short* __restrict__ yl){
  __shared__ float ws1[2], ws2[2];
  int n = blockIdx.x; int b_ = n >> 9, l = n & 511;
  int c0 = threadIdx.x * 4;
  float a0=bias[c0], a1=bias[c0+1], a2=bias[c0+2], a3=bias[c0+3];
  #pragma unroll
  for (int k=0;k<5;k++){
    int ls = l + k - 2; ls = ls < 0 ? 0 : (ls > 511 ? 511 : ls);
    const float4 xv = *(const float4*)&x[((size_t)(b_*512 + ls) << 9) + c0];
    a0 += w[(c0+0)*5+k]*xv.x;
    a1 += w[(c0+1)*5+k]*xv.y;
    a2 += w[(c0+2)*5+k]*xv.z;
    a3 += w[(c0+3)*5+k]*xv.w;
  }
  float mm = mask[n];
  a0*=mm; a1*=mm; a2*=mm; a3*=mm;
  int wv = threadIdx.x >> 6, ln_ = threadIdx.x & 63;
  float s = wave_sum(a0+a1+a2+a3);
  if (ln_ == 0) ws1[wv] = s;
  __syncthreads();
  float mean = (ws1[0] + ws1[1]) * (1.f/512.f);
  float d0=a0-mean, d1=a1-mean, d2=a2-mean, d3=a3-mean;
  float sq = wave_sum(d0*d0+d1*d1+d2*d2+d3*d3);
  if (ln_ == 0) ws2[wv] = sq;
  __syncthreads();
  float var = (ws2[0] + ws2[1]) * (1.f/512.f);
  float inv = 1.f/sqrtf(var + 1e-6f);
  float4 gv = *(const float4*)&g[c0];
  float4 bv = *(const float4*)&bt[c0];
  float4 o;
  o.x = d0*inv*gv.x + bv.x;
  o.y = d1*inv*gv.y + bv.y;
  o.z = d2*inv*gv.z + bv.z;
  o.w = d3*inv*gv.w + bv.w;
  size_t base = ((size_t)n << 9) + c0;
  split4(o, yh+base, yl+base);
}

// ---------------- rowwise LayerNorm over C=512 (optional split / mask) -------
template<bool SPLIT, bool MASK>
__global__ __launch_bounds__(256) void ln_rows(const float* __restrict__ x,
    const float* __restrict__ g, const float* __restrict__ bt,
    const float* __restrict__ rowmask,
    float* __restrict__ y, unsigned short* __restrict__ yh,
    unsigned short* __restrict__ yl, int nrows){
  int wid = threadIdx.x >> 6, lane = threadIdx.x & 63;
  int row = blockIdx.x*4 + wid;
  if (row >= nrows) return;
  const float4* xr = (const float4*)(x + ((size_t)row<<9));
  float4 a = xr[lane*2], b = xr[lane*2+1];
  float s = a.x+a.y+a.z+a.w+b.x+b.y+b.z+b.w;
  s = wave_sum(s);
  float m = s * (1.f/512.f);
  float d0=a.x-m,d1=a.y-m,d2=a.z-m,d3=a.w-m,d4=b.x-m,d5=b.y-m,d6=b.z-m,d7=b.w-m;
  float sq = d0*d0+d1*d1+d2*d2+d3*d3+d4*d4+d5*d5+d6*d6+d7*d7;
  sq = wave_sum(sq);
  float var = sq * (1.f/512.f);
  float inv = 1.f/sqrtf(var + 1e-6f);
  const float4* gr = (const float4*)g; const float4* br = (const float4*)bt;
  float4 g0=gr[lane*2], g1=gr[lane*2+1], b0=br[lane*2], b1=br[lane*2+1];
  float4 o0, o1;
  o0.x=d0*inv*g0.x+b0.x; o0.y=d1*inv*g0.y+b0.y; o0.z=d2*inv*g0.z+b0.z; o0.w=d3*inv*g0.w+b0.w;
  o1.x=d4*inv*g1.x+b1.x; o1.y=d5*inv*g1.y+b1.y; o1.z=d6*inv*g1.z+b1.z; o1.w=d7*inv*g1.w+b1.w;
  if constexpr (MASK){
    float mf = rowmask[row];
    o0.x*=mf; o0.y*=mf; o0.z*=mf; o0.w*=mf;
    o1.x*=mf; o1.y*=mf; o1.z*=mf; o1.w*=mf;
  }
  float4* yr = (float4*)(y + ((size_t)row<<9));
  yr[lane*2]=o0; yr[lane*2+1]=o1;
  if constexpr (SPLIT){
    size_t base = ((size_t)row<<9) + lane*8;
    split4(o0, yh+base,   yl+base);
    split4(o1, yh+base+4, yl+base+4);
  }
}

#define EPI_BIAS 0
#define EPI_SCALE 1
#define EPI_GELU 2
#define EPI_RES 3
#define EPI_RELU_MASK 4
#define EPI_RES_MASK 5
#define EPI_RES_GAMMA_MASK 6
#define EPI_TANH 7
#define EPI_QKV 8

// ---------------- style K/V prep -> bf16 planes (zero-padded to 64 keys) -----
__global__ __launch_bounds__(256) void style_prep(
    const float* __restrict__ style_key, const float* __restrict__ style_v,
    const float* __restrict__ sk_w, const float* __restrict__ sk_b,
    const float* __restrict__ sv_w, const float* __restrict__ sv_b,
    unsigned short* __restrict__ KKh, unsigned short* __restrict__ KKl,
    unsigned short* __restrict__ VTh_s, unsigned short* __restrict__ VTl_s)
{
  __shared__ float As[16][68];
  __shared__ float Bs[16][68];
  int sel = blockIdx.y;
  bool is_k = (sel < 2);
  int layer = sel & 1;
  const float* A = is_k ? style_key : style_v;
  const float* W = (sel==0) ? sk_w : (sel==1) ? sk_w+262144 :
                   (sel==2) ? sv_w : sv_w+262144;
  const float* bias = (sel==0) ? sk_b : (sel==1) ? sk_b+512 :
                      (sel==2) ? sv_b : sv_b+512;
  const int N = 50, K = 512;
  int t = threadIdx.x;
  int tx = t & 15, ty = t >> 4;
  int col0 = blockIdx.x << 6;
  int lr = t >> 2, lk = (t & 3) << 2;
  float acc[4][4] = {};
  bool arok = lr < N;
  const float* Ap = A + (size_t)(arok ? lr : 0) * K + lk;
  const float* Wp = W + (size_t)(col0 + lr) * K + lk;
  for (int k0 = 0; k0 < K; k0 += 16) {
    float4 av;
    if (arok) av = *(const float4*)(Ap + k0);
    else { av.x=0;av.y=0;av.z=0;av.w=0; }
    float4 bv = *(const float4*)(Wp + k0);
    As[lk+0][lr]=av.x; As[lk+1][lr]=av.y; As[lk+2][lr]=av.z; As[lk+3][lr]=av.w;
    Bs[lk+0][lr]=bv.x; Bs[lk+1][lr]=bv.y; Bs[lk+2][lr]=bv.z; Bs[lk+3][lr]=bv.w;
    __syncthreads();
    #pragma unroll
    for (int k=0;k<16;k++){
      float4 af = *(const float4*)&As[k][ty<<2];
      float4 bf = *(const float4*)&Bs[k][tx<<2];
      float a4[4]={af.x,af.y,af.z,af.w};
      float b4[4]={bf.x,bf.y,bf.z,bf.w};
      #pragma unroll
      for (int i=0;i<4;i++)
        #pragma unroll
        for (int j=0;j<4;j++)
          acc[i][j] += a4[i]*b4[j];
    }
    __syncthreads();
  }
  #pragma unroll
  for (int i=0;i<4;i++){
    int row = (ty<<2) + i;                 // 0..63 (padded keys zeroed)
    #pragma unroll
    for (int j=0;j<4;j++){
      int col = col0 + (tx<<2) + j;
      int head = col >> 8, d = col & 255;
      float v = 0.f;
      if (row < N){
        v = acc[i][j] + bias[col];
        if (is_k) v = tanhf(v);
      }
      unsigned short hh, ll_;
      splitc(v, hh, ll_);
      if (is_k){
        size_t o = (((size_t)layer*2 + head)<<14) + row*256 + d;
        KKh[o]=hh; KKl[o]=ll_;
      } else {
        size_t o = (((size_t)layer*2 + head)<<14) + d*64 + row;
        VTh_s[o]=hh; VTl_s[o]=ll_;
      }
    }
  }
}

// ---------------- MFMA style attention: block = 16 rows x 2 heads ------------
__global__ __launch_bounds__(256) void style_mf(
    const unsigned short* __restrict__ Qh_g, const unsigned short* __restrict__ Ql_g,
    const unsigned short* __restrict__ KKh, const unsigned short* __restrict__ KKl,
    const unsigned short* __restrict__ VTh_s, const unsigned short* __restrict__ VTl_s,
    const float* __restrict__ mask,
    unsigned short* __restrict__ Oh, unsigned short* __restrict__ Ol)
{
  __shared__ float Sc[2][16][68];
  __shared__ unsigned short Pph[2][16][72], Ppl[2][16][72];
  int t = threadIdx.x, lane = t & 63, w = t >> 6;
  int head = w >> 1, nh = w & 1;
  int rowbase = blockIdx.x * 16;
  int fr = lane & 15, fc = (lane >> 4) << 3, qbase = (lane >> 4) << 2;

  // ---- QK: S = Q_h . KK_h^T ----
  f32x4 s2[2] = {};
  #pragma unroll
  for (int ks = 0; ks < 8; ++ks){
    size_t qoff = (size_t)(rowbase + fr)*512 + head*256 + ks*32 + fc;
    short8v ah = *(const short8v*)(Qh_g + qoff);
    short8v al = *(const short8v*)(Ql_g + qoff);
    #pragma unroll
    for (int nt = 0; nt < 2; ++nt){
      int key = nh*32 + nt*16 + fr;
      size_t ko = (((size_t)head)<<14) + key*256 + ks*32 + fc;
      short8v bh = *(const short8v*)(KKh + ko);
      short8v bl = *(const short8v*)(KKl + ko);
      f32x4 c = s2[nt];
      c = __builtin_amdgcn_mfma_f32_16x16x32_bf16(ah,bh,c,0,0,0);
      c = __builtin_amdgcn_mfma_f32_16x16x32_bf16(ah,bl,c,0,0,0);
      c = __builtin_amdgcn_mfma_f32_16x16x32_bf16(al,bh,c,0,0,0);
      s2[nt] = c;
    }
  }
  #pragma unroll
  for (int nt = 0; nt < 2; ++nt)
    #pragma unroll
    for (int j = 0; j < 4; ++j)
      Sc[head][qbase+j][nh*32 + nt*16 + fr] = s2[nt][j] * 0.044194173824159216f;
  __syncthreads();

  // ---- softmax over 50 keys (32 threads: head x row); keep/sum folded in ----
  if (t < 32){
    int h2 = t >> 4, r = t & 15;
    float mx = -3.4e38f;
    for (int ss = 0; ss < 50; ++ss) mx = fmaxf(mx, Sc[h2][r][ss]);
    float sum = 0.f;
    for (int ss = 0; ss < 50; ++ss) sum += expf(Sc[h2][r][ss] - mx);
    float keep = (mask[rowbase + r] == 0.f) ? 0.f : 1.f;
    float inv = keep / sum;
    for (int ss = 0; ss < 64; ++ss){
      float p = (ss < 50) ? expf(Sc[h2][r][ss] - mx) * inv : 0.f;
      unsigned short hh, ll_;
      splitc(p, hh, ll_);
      Pph[h2][r][ss] = hh; Ppl[h2][r][ss] = ll_;
    }
  }
  __syncthreads();

  // ---- AV: O = P . V ----
  f32x4 av[8] = {};
  #pragma unroll
  for (int ks = 0; ks < 2; ++ks){
    short8v ah = *(const short8v*)&Pph[head][fr][ks*32 + fc];
    short8v al = *(const short8v*)&Ppl[head][fr][ks*32 + fc];
    #pragma unroll
    for (int nt = 0; nt < 8; ++nt){
      int d = nh*128 + nt*16 + fr;
      size_t vo = (((size_t)head)<<14) + d*64 + ks*32 + fc;
      short8v bh = *(const short8v*)(VTh_s + vo);
      short8v bl = *(const short8v*)(VTl_s + vo);
      f32x4 c = av[nt];
      c = __builtin_amdgcn_mfma_f32_16x16x32_bf16(ah,bh,c,0,0,0);
      c = __builtin_amdgcn_mfma_f32_16x16x32_bf16(ah,bl,c,0,0,0);
      c = __builtin_amdgcn_mfma_f32_16x16x32_bf16(al,bh,c,0,0,0);
      av[nt] = c;
    }
  }
  #pragma unroll
  for (int nt = 0; nt < 8; ++nt)
    #pragma unroll
    for (int j = 0; j < 4; ++j){
      int row = rowbase + qbase + j;
      int d = nh*128 + nt*16 + fr;
      unsigned short hh, ll_;
      splitc(av[nt][j], hh, ll_);
      size_t o = (size_t)row*512 + head*256 + d;
      Oh[o] = hh; Ol[o] = ll_;
    }
}

// ---------------- pre-split MFMA GEMM, double-buffered LDS (64-row tiles) ----
// OUT: 0 = fp32 Y, 1 = planes, 2 = QKV mode, 3 = fp32 Y + planes.
template<int EPI, bool AMASK, int OUT, int NF>
__global__ __launch_bounds__(256) void gemm_ps(
    const unsigned short* __restrict__ Ah, const unsigned short* __restrict__ Al,
    const unsigned short* __restrict__ Wh, const unsigned short* __restrict__ Wl,
    const float* __restrict__ bias, const float* __restrict__ res,
    const float* __restrict__ gamma, const float* __restrict__ rowmask,
    float* __restrict__ Y, unsigned short* __restrict__ Yh,
    unsigned short* __restrict__ Yl, unsigned short* __restrict__ VTh,
    unsigned short* __restrict__ VTl, int K, int O, float scale)
{
  __shared__ unsigned short AhS[2][64][40], AlS[2][64][40];
  __shared__ unsigned short BhS[2][NF*32][40], BlS[2][NF*32][40];
  int t = threadIdx.x;
  int row0 = blockIdx.y << 6;
  int col0 = blockIdx.x << (NF==4 ? 7 : 6);
  int lane = t & 63, wid = t >> 6;
  int wr = wid >> 1, wc = wid & 1;

  int sr = t >> 2, sc = (t & 3) << 3;
  const unsigned short* Ahg = Ah + (size_t)(row0 + sr)*K + sc;
  const unsigned short* Alg = Al + (size_t)(row0 + sr)*K + sc;
  const unsigned short* Bhg = Wh + (size_t)(col0 + sr)*K + sc;
  const unsigned short* Blg = Wl + (size_t)(col0 + sr)*K + sc;
  float am = 1.f;
  if (AMASK) am = rowmask[row0 + sr];

  f32x4 acc[2][NF] = {};
  int nsteps = K >> 5;
  short8v ah_, al_, bh0_, bl0_, bh1_, bl1_;
  ah_ = *(const short8v*)(Ahg);
  al_ = *(const short8v*)(Alg);
  bh0_ = *(const short8v*)(Bhg);
  bl0_ = *(const short8v*)(Blg);
  if constexpr (NF==4){
    bh1_ = *(const short8v*)(Bhg + (size_t)64*K);
    bl1_ = *(const short8v*)(Blg + (size_t)64*K);
  }
  if (AMASK && am == 0.f){ ah_ ^= ah_; al_ ^= al_; }
  *(short8v*)&AhS[0][sr][sc] = ah_;
  *(short8v*)&AlS[0][sr][sc] = al_;
  *(short8v*)&BhS[0][sr][sc] = bh0_;
  *(short8v*)&BlS[0][sr][sc] = bl0_;
  if constexpr (NF==4){
    *(short8v*)&BhS[0][sr+64][sc] = bh1_;
    *(short8v*)&BlS[0][sr+64][sc] = bl1_;
  }

  int st = 0;
  for (int s = 0; s < nsteps; ++s){
    if (s+1 < nsteps){
      int ko = (s+1) << 5;
      ah_ = *(const short8v*)(Ahg + ko);
      al_ = *(const short8v*)(Alg + ko);
      bh0_ = *(const short8v*)(Bhg + ko);
      bl0_ = *(const short8v*)(Blg + ko);
      if constexpr (NF==4){
        bh1_ = *(const short8v*)(Bhg + (size_t)64*K + ko);
        bl1_ = *(const short8v*)(Blg + (size_t)64*K + ko);
      }
      if (AMASK && am == 0.f){ ah_ ^= ah_; al_ ^= al_; }
    }
    __syncthreads();
    int fr = lane & 15, fc = (lane >> 4) << 3;
    short8v ahf[2], alf[2], bhf[NF], blf[NF];
    #pragma unroll
    for (int mt=0; mt<2; ++mt){
      int r = (wr<<5) + (mt<<4) + fr;
      ahf[mt] = *(const short8v*)&AhS[st][r][fc];
      alf[mt] = *(const short8v*)&AlS[st][r][fc];
    }
    #pragma unroll
    for (int nt=0; nt<NF; ++nt){
      int r = (NF==4 ? (wc<<6) : (wc<<5)) + (nt<<4) + fr;
      bhf[nt] = *(const short8v*)&BhS[st][r][fc];
      blf[nt] = *(const short8v*)&BlS[st][r][fc];
    }
    #pragma unroll
    for (int mt=0; mt<2; ++mt)
      #pragma unroll
      for (int nt=0; nt<NF; ++nt){
        f32x4 c = acc[mt][nt];
        c = __builtin_amdgcn_mfma_f32_16x16x32_bf16(ahf[mt], bhf[nt], c, 0,0,0);
        c = __builtin_amdgcn_mfma_f32_16x16x32_bf16(ahf[mt], blf[nt], c, 0,0,0);
        c = __builtin_amdgcn_mfma_f32_16x16x32_bf16(alf[mt], bhf[nt], c, 0,0,0);
        acc[mt][nt] = c;
      }
    if (s+1 < nsteps){
      int nb = st ^ 1;
      *(short8v*)&AhS[nb][sr][sc] = ah_;
      *(short8v*)&AlS[nb][sr][sc] = al_;
      *(short8v*)&BhS[nb][sr][sc] = bh0_;
      *(short8v*)&BlS[nb][sr][sc] = bl0_;
      if constexpr (NF==4){
        *(short8v*)&BhS[nb][sr+64][sc] = bh1_;
        *(short8v*)&BlS[nb][sr+64][sc] = bl1_;
      }
    }
    st ^= 1;
  }

  int rb = row0 + (wr<<5) + ((lane>>4)<<2);
  int cb = col0 + (NF==4 ? (wc<<6) : (wc<<5)) + (lane & 15);
  float bs[NF], gm[NF];
  int which = 0;
  if constexpr (EPI==EPI_QKV) which = blockIdx.x >> 2;
  #pragma unroll
  for (int nt=0; nt<NF; ++nt){
    int col = cb + (nt<<4);
    if constexpr (EPI==EPI_QKV){
      const float* bp = (which==0) ? bias : (which==1) ? res : gamma;
      bs[nt] = bp[col & 511];
    } else {
      bs[nt] = bias[col];
      if constexpr (EPI==EPI_RES_GAMMA_MASK) gm[nt] = gamma[col];
    }
  }
  float qscale = 1.f;
  if constexpr (EPI==EPI_QKV) qscale = (which==0) ? scale : 1.f;

  if constexpr (OUT==2){
    if (which == 2){
      #pragma unroll
      for (int mt=0; mt<2; ++mt){
        int row = rb + (mt<<4);
        int b = row >> 9, tok = row & 511;
        #pragma unroll
        for (int nt=0; nt<NF; ++nt){
          int dglob = cb + (nt<<4) - 1024;
          size_t vt = ((size_t)b*512 + dglob)*512 + tok;
          unsigned short h4[4], l4[4];
          #pragma unroll
          for (int j=0; j<4; ++j)
            splitc(acc[mt][nt][j] + bs[nt], h4[j], l4[j]);
          *(ushort4*)&VTh[vt] = make_ushort4(h4[0],h4[1],h4[2],h4[3]);
          *(ushort4*)&VTl[vt] = make_ushort4(l4[0],l4[1],l4[2],l4[3]);
        }
      }
      return;
    }
    #pragma unroll
    for (int mt=0; mt<2; ++mt)
      #pragma unroll
      for (int j=0; j<4; ++j){
        int row = rb + (mt<<4) + j;
        #pragma unroll
        for (int nt=0; nt<NF; ++nt){
          float v = (acc[mt][nt][j] + bs[nt]) * qscale;
          size_t oidx = (size_t)row*O + cb + (nt<<4);
          unsigned short h,l; splitc(v,h,l); Yh[oidx]=h; Yl[oidx]=l;
        }
      }
    return;
  }

  #pragma unroll
  for (int mt=0; mt<2; ++mt)
    #pragma unroll
    for (int j=0; j<4; ++j){
      int row = rb + (mt<<4) + j;
      float rm = 1.f;
      if constexpr (EPI==EPI_RELU_MASK || EPI==EPI_RES_MASK || EPI==EPI_RES_GAMMA_MASK)
        rm = rowmask[row];
      const float* rr = nullptr;
      if constexpr (EPI==EPI_RES || EPI==EPI_RES_MASK || EPI==EPI_RES_GAMMA_MASK)
        rr = res + (size_t)row*O + cb;
      #pragma unroll
      for (int nt=0; nt<NF; ++nt){
        float v = acc[mt][nt][j] + bs[nt];
        if constexpr (EPI==EPI_SCALE) v *= scale;
        else if constexpr (EPI==EPI_QKV) v *= qscale;
        else if constexpr (EPI==EPI_GELU) v = 0.5f*v*(1.f+erff(v*0.7071067811865475f));
        else if constexpr (EPI==EPI_RES) v = rr[nt<<4] + v;
        else if constexpr (EPI==EPI_RELU_MASK) v = fmaxf(v,0.f)*rm;
        else if constexpr (EPI==EPI_RES_MASK) v = rr[nt<<4] + v*rm;
        else if constexpr (EPI==EPI_RES_GAMMA_MASK) v = (rr[nt<<4] + gm[nt]*v)*rm;
        size_t oidx = (size_t)row*O + cb + (nt<<4);
        if constexpr (OUT==0) Y[oidx] = v;
        else if constexpr (OUT==3){
          Y[oidx] = v;
          unsigned short h,l; splitc(v,h,l); Yh[oidx]=h; Yl[oidx]=l;
        }
        else { unsigned short h,l; splitc(v,h,l); Yh[oidx]=h; Yl[oidx]=l; }
      }
    }
}

// ---------------- 128x128x32 MFMA GEMM (big-O GEMMs: pw1/ffn1/QKV) -----------
template<int EPI, bool AMASK, int OUT>
__global__ __launch_bounds__(256) void gemm_big(
    const unsigned short* __restrict__ Ah, const unsigned short* __restrict__ Al,
    const unsigned short* __restrict__ Wh, const unsigned short* __restrict__ Wl,
    const float* __restrict__ bias, const float* __restrict__ res,
    const float* __restrict__ gamma, const float* __restrict__ rowmask,
    float* __restrict__ Y, unsigned short* __restrict__ Yh,
    unsigned short* __restrict__ Yl, unsigned short* __restrict__ VTh,
    unsigned short* __restrict__ VTl, int K, int O, float scale)
{
  __shared__ unsigned short AhS[128][40], AlS[128][40];
  __shared__ unsigned short BhS[128][40], BlS[128][40];
  int t = threadIdx.x;
  int row0 = blockIdx.y << 7, col0 = blockIdx.x << 7;
  int lane = t & 63, wid = t >> 6;
  int wr = wid >> 1, wc = wid & 1;

  int sr = t >> 2, sc = (t & 3) << 3;
  const unsigned short* Ahg = Ah + (size_t)(row0 + sr)*K + sc;
  const unsigned short* Alg = Al + (size_t)(row0 + sr)*K + sc;
  const unsigned short* Bhg = Wh + (size_t)(col0 + sr)*K + sc;
  const unsigned short* Blg = Wl + (size_t)(col0 + sr)*K + sc;
  bool az0 = false, az1 = false;
  if (AMASK){ az0 = (rowmask[row0+sr] == 0.f); az1 = (rowmask[row0+sr+64] == 0.f); }

  f32x4 acc[4][4] = {};
  int nsteps = K >> 5;
  short8v a0h,a0l,a1h,a1l,b0h,b0l,b1h,b1l;
  a0h = *(const short8v*)(Ahg);
  a0l = *(const short8v*)(Alg);
  a1h = *(const short8v*)(Ahg + (size_t)64*K);
  a1l = *(const short8v*)(Alg + (size_t)64*K);
  b0h = *(const short8v*)(Bhg);
  b0l = *(const short8v*)(Blg);
  b1h = *(const short8v*)(Bhg + (size_t)64*K);
  b1l = *(const short8v*)(Blg + (size_t)64*K);

  for (int s = 0; s < nsteps; ++s){
    if (AMASK){
      if (az0){ a0h ^= a0h; a0l ^= a0l; }
      if (az1){ a1h ^= a1h; a1l ^= a1l; }
    }
    __syncthreads();
    *(short8v*)&AhS[sr][sc] = a0h;    *(short8v*)&AlS[sr][sc] = a0l;
    *(short8v*)&AhS[sr+64][sc] = a1h; *(short8v*)&AlS[sr+64][sc] = a1l;
    *(short8v*)&BhS[sr][sc] = b0h;    *(short8v*)&BlS[sr][sc] = b0l;
    *(short8v*)&BhS[sr+64][sc] = b1h; *(short8v*)&BlS[sr+64][sc] = b1l;
    __syncthreads();
    if (s+1 < nsteps){
      int ko = (s+1) << 5;
      a0h = *(const short8v*)(Ahg + ko);
      a0l = *(const short8v*)(Alg + ko);
      a1h = *(const short8v*)(Ahg + (size_t)64*K + ko);
      a1l = *(const short8v*)(Alg + (size_t)64*K + ko);
      b0h = *(const short8v*)(Bhg + ko);
      b0l = *(const short8v*)(Blg + ko);
      b1h = *(const short8v*)(Bhg + (size_t)64*K + ko);
      b1l = *(const short8v*)(Blg + (size_t)64*K + ko);
    }
    int fr = lane & 15, fc = (lane >> 4) << 3;
    short8v ahf[4], alf[4], bhf[4], blf[4];
    #pragma unroll
    for (int mt=0; mt<4; ++mt){
      int r = (wr<<6) + (mt<<4) + fr;
      ahf[mt] = *(const short8v*)&AhS[r][fc];
      alf[mt] = *(const short8v*)&AlS[r][fc];
    }
    #pragma unroll
    for (int nt=0; nt<4; ++nt){
      int r = (wc<<6) + (nt<<4) + fr;
      bhf[nt] = *(const short8v*)&BhS[r][fc];
      blf[nt] = *(const short8v*)&BlS[r][fc];
    }
    #pragma unroll
    for (int mt=0; mt<4; ++mt)
      #pragma unroll
      for (int nt=0; nt<4; ++nt){
        f32x4 c = acc[mt][nt];
        c = __builtin_amdgcn_mfma_f32_16x16x32_bf16(ahf[mt], bhf[nt], c, 0,0,0);
        c = __builtin_amdgcn_mfma_f32_16x16x32_bf16(ahf[mt], blf[nt], c, 0,0,0);
        c = __builtin_amdgcn_mfma_f32_16x16x32_bf16(alf[mt], bhf[nt], c, 0,0,0);
        acc[mt][nt] = c;
      }
  }

  int rb = row0 + (wr<<6) + ((lane>>4)<<2);
  int cb = col0 + (wc<<6) + (lane & 15);
  float bs[4];
  int which = 0;
  if constexpr (EPI==EPI_QKV) which = blockIdx.x >> 2;
  #pragma unroll
  for (int nt=0; nt<4; ++nt){
    int col = cb + (nt<<4);
    if constexpr (EPI==EPI_QKV){
      const float* bp = (which==0) ? bias : (which==1) ? res : gamma;
      bs[nt] = bp[col & 511];
    } else {
      bs[nt] = bias[col];
    }
  }
  float qscale = 1.f;
  if constexpr (EPI==EPI_QKV) qscale = (which==0) ? scale : 1.f;

  if constexpr (OUT==2){
    if (which == 2){
      #pragma unroll
      for (int mt=0; mt<4; ++mt){
        int row = rb + (mt<<4);
        int b = row >> 9, tok = row & 511;
        #pragma unroll
        for (int nt=0; nt<4; ++nt){
          int dglob = cb + (nt<<4) - 1024;
          size_t vt = ((size_t)b*512 + dglob)*512 + tok;
          unsigned short h4[4], l4[4];
          #pragma unroll
          for (int j=0; j<4; ++j)
            splitc(acc[mt][nt][j] + bs[nt], h4[j], l4[j]);
          *(ushort4*)&VTh[vt] = make_ushort4(h4[0],h4[1],h4[2],h4[3]);
          *(ushort4*)&VTl[vt] = make_ushort4(l4[0],l4[1],l4[2],l4[3]);
        }
      }
      return;
    }
    #pragma unroll
    for (int mt=0; mt<4; ++mt)
      #pragma unroll
      for (int j=0; j<4; ++j){
        int row = rb + (mt<<4) + j;
        #pragma unroll
        for (int nt=0; nt<4; ++nt){
          float v = (acc[mt][nt][j] + bs[nt]) * qscale;
          size_t oidx = (size_t)row*O + cb + (nt<<4);
          unsigned short h,l; splitc(v,h,l); Yh[oidx]=h; Yl[oidx]=l;
        }
      }
    return;
  }

  #pragma unroll
  for (int mt=0; mt<4; ++mt)
    #pragma unroll
    for (int j=0; j<4; ++j){
      int row = rb + (mt<<4) + j;
      float rm = 1.f;
      if constexpr (EPI==EPI_RELU_MASK) rm = rowmask[row];
      #pragma unroll
      for (int nt=0; nt<4; ++nt){
        float v = acc[mt][nt][j] + bs[nt];
        if constexpr (EPI==EPI_GELU) v = 0.5f*v*(1.f+erff(v*0.7071067811865475f));
        else if constexpr (EPI==EPI_RELU_MASK) v = fmaxf(v,0.f)*rm;
        size_t oidx = (size_t)row*O + cb + (nt<<4);
        if constexpr (OUT==0) Y[oidx] = v;
        else { unsigned short h,l; splitc(v,h,l); Yh[oidx]=h; Yl[oidx]=l; }
      }
    }
}

// ---------------- MFMA windowed-rel attention v4: 2 Q-tiles per block --------
// 32 Q-rows/block; K/V fragment loads amortized over 2x MFMA work.
// Single RNE bf16 P plane (proven accuracy-safe in v3.5).
__global__ __launch_bounds__(256) void attn_mf(
    const unsigned short* __restrict__ Ph_g, const unsigned short* __restrict__ Pl_g,
    const unsigned short* __restrict__ VTh_g, const unsigned short* __restrict__ VTl_g,
    const float* __restrict__ relk, const float* __restrict__ relv,
    const float* __restrict__ mask, unsigned short* __restrict__ Oh,
    unsigned short* __restrict__ Ol)
{
  __shared__ float ms_[512];
  __shared__ float rv[9][64];
  __shared__ float qrel[32][16];
  __shared__ float red1[4][32];
  __shared__ float red2[4][32];
  __shared__ __align__(16) unsigned short Spool[32*520];
  // overlay views (valid only before the qrel barrier):
  unsigned short (*Qh)[72]  = (unsigned short(*)[72])(Spool);          // [32][72]
  unsigned short (*Ql)[72]  = (unsigned short(*)[72])(Spool + 2304);   // [32][72]
  unsigned short (*Rkh)[72] = (unsigned short(*)[72])(Spool + 4608);   // [16][72]
  unsigned short (*Rkl)[72] = (unsigned short(*)[72])(Spool + 5760);   // [16][72]
  // P view (valid only after the qrel barrier): [32][520]
  unsigned short (*Sp)[520] = (unsigned short(*)[520])(Spool);

  int id = blockIdx.x;
  int xcd = id & 7, kk = id >> 3;
  int bh_ = xcd*8 + (kk >> 4);
  int qt = kk & 15;
  int h = bh_ & 7, b_ = bh_ >> 3;
  int t = threadIdx.x;
  int l0 = qt * 32;
  const size_t rowoff = (size_t)b_ * 512;
  int lane = t & 63, w = t >> 6;

  ms_[t] = mask[rowoff + t]; ms_[t+256] = mask[rowoff + t + 256];
  for (int i = t; i < 576; i += 256) ((float*)rv)[i] = relv[i];
  {
    int r = t >> 4, c = (t & 15) << 2;
    float4 v;
    if (r < 9) v = *(const float4*)&relk[r*64 + c];
    else { v.x=0.f; v.y=0.f; v.z=0.f; v.w=0.f; }
    split4(v, &Rkh[r][c], &Rkl[r][c]);
  }
  // Q load: 32 rows x 64 cols x 2 planes; 512 chunks of 8 shorts, 2/thread
  for (int i = t; i < 512; i += 256){
    int r = (i & 255) >> 3, c = (i & 7) << 3;
    size_t g = (rowoff + l0 + r)*QKVS + h*64 + c;
    if (i < 256) *(short8v*)&Qh[r][c] = *(const short8v*)&Ph_g[g];
    else         *(short8v*)&Ql[r][c] = *(const short8v*)&Pl_g[g];
  }
  __syncthreads();

  int fr = lane & 15, fc = (lane >> 4) << 3;
  int qbase = (lane>>4) << 2;
  // tile0 rows fr, tile1 rows 16+fr
  short8v a0h0 = *(const short8v*)&Qh[fr][fc];
  short8v a0h1 = *(const short8v*)&Qh[fr][32+fc];
  short8v a0l0 = *(const short8v*)&Ql[fr][fc];
  short8v a0l1 = *(const short8v*)&Ql[fr][32+fc];
  short8v a1h0 = *(const short8v*)&Qh[16+fr][fc];
  short8v a1h1 = *(const short8v*)&Qh[16+fr][32+fc];
  short8v a1l0 = *(const short8v*)&Ql[16+fr][fc];
  short8v a1l1 = *(const short8v*)&Ql[16+fr][32+fc];

  // qrel for both tiles: wave 0 -> rows 0..15, wave 1 -> rows 16..31
  if (w < 2){
    short8v rh0 = *(const short8v*)&Rkh[fr][fc];
    short8v rh1 = *(const short8v*)&Rkh[fr][32+fc];
    short8v rl0 = *(const short8v*)&Rkl[fr][fc];
    short8v rl1 = *(const short8v*)&Rkl[fr][32+fc];
    short8v qa0 = (w==0) ? a0h0 : a1h0;
    short8v qa1 = (w==0) ? a0h1 : a1h1;
    short8v qb0 = (w==0) ? a0l0 : a1l0;
    short8v qb1 = (w==0) ? a0l1 : a1l1;
    f32x4 c4 = {};
    c4 = __builtin_amdgcn_mfma_f32_16x16x32_bf16(qa0,rh0,c4,0,0,0);
    c4 = __builtin_amdgcn_mfma_f32_16x16x32_bf16(qa1,rh1,c4,0,0,0);
    c4 = __builtin_amdgcn_mfma_f32_16x16x32_bf16(qa0,rl0,c4,0,0,0);
    c4 = __builtin_amdgcn_mfma_f32_16x16x32_bf16(qa1,rl1,c4,0,0,0);
    c4 = __builtin_amdgcn_mfma_f32_16x16x32_bf16(qb0,rh0,c4,0,0,0);
    c4 = __builtin_amdgcn_mfma_f32_16x16x32_bf16(qb1,rh1,c4,0,0,0);
    #pragma unroll
    for (int j = 0; j < 4; ++j) qrel[w*16 + qbase + j][fr] = c4[j];
  }
  __syncthreads();   // after this: Q/Rk LDS dead, P region live

  // ---- QK for both tiles; K frags loaded once ----
  f32x4 sreg0[8], sreg1[8];
  #pragma unroll
  for (int tt = 0; tt < 8; ++tt){
    int br = tt*64 + w*16 + fr;
    const unsigned short* krh = Ph_g + (rowoff + br)*QKVS + 512 + h*64;
    const unsigned short* krl = Pl_g + (rowoff + br)*QKVS + 512 + h*64;
    short8v bh0 = *(const short8v*)(krh + fc);
    short8v bh1 = *(const short8v*)(krh + 32 + fc);
    short8v bl0 = *(const short8v*)(krl + fc);
    short8v bl1 = *(const short8v*)(krl + 32 + fc);
    f32x4 c0 = {}, c1 = {};
    c0 = __builtin_amdgcn_mfma_f32_16x16x32_bf16(a0h0,bh0,c0,0,0,0);
    c1 = __builtin_amdgcn_mfma_f32_16x16x32_bf16(a1h0,bh0,c1,0,0,0);
    c0 = __builtin_amdgcn_mfma_f32_16x16x32_bf16(a0h1,bh1,c0,0,0,0);
    c1 = __builtin_amdgcn_mfma_f32_16x16x32_bf16(a1h1,bh1,c1,0,0,0);
    c0 = __builtin_amdgcn_mfma_f32_16x16x32_bf16(a0h0,bl0,c0,0,0,0);
    c1 = __builtin_amdgcn_mfma_f32_16x16x32_bf16(a1h0,bl0,c1,0,0,0);
    c0 = __builtin_amdgcn_mfma_f32_16x16x32_bf16(a0h1,bl1,c0,0,0,0);
    c1 = __builtin_amdgcn_mfma_f32_16x16x32_bf16(a1h1,bl1,c1,0,0,0);
    c0 = __builtin_amdgcn_mfma_f32_16x16x32_bf16(a0l0,bh0,c0,0,0,0);
    c1 = __builtin_amdgcn_mfma_f32_16x16x32_bf16(a1l0,bh0,c1,0,0,0);
    c0 = __builtin_amdgcn_mfma_f32_16x16x32_bf16(a0l1,bh1,c0,0,0,0);
    c1 = __builtin_amdgcn_mfma_f32_16x16x32_bf16(a1l1,bh1,c1,0,0,0);
    int m = tt*64 + w*16 + fr;
    float mm_ = ms_[m];
    #pragma unroll
    for (int j = 0; j < 4; ++j){
      int q = qbase + j;
      // tile 0
      {
        int l = l0 + q;
        float s = c0[j];
        int dlt = m - l + 4;
        if (dlt >= 0 && dlt <= 8) s += qrel[q][dlt];
        if (ms_[l] * mm_ == 0.f) s = -10000.f;
        c0[j] = s;
      }
      // tile 1
      {
        int l = l0 + 16 + q;
        float s = c1[j];
        int dlt = m - l + 4;
        if (dlt >= 0 && dlt <= 8) s += qrel[16 + q][dlt];
        if (ms_[l] * mm_ == 0.f) s = -10000.f;
        c1[j] = s;
      }
    }
    sreg0[tt] = c0; sreg1[tt] = c1;
  }

  float mx0[4], mx1[4], sm0[4], sm1[4], inv0[4], inv1[4];
  #pragma unroll
  for (int j = 0; j < 4; ++j){
    float v0 = sreg0[0][j], v1 = sreg1[0][j];
    #pragma unroll
    for (int tt = 1; tt < 8; ++tt){
      v0 = fmaxf(v0, sreg0[tt][j]);
      v1 = fmaxf(v1, sreg1[tt][j]);
    }
    #pragma unroll
    for (int o = 8; o >= 1; o >>= 1){
      v0 = fmaxf(v0, __shfl_xor(v0, o));
      v1 = fmaxf(v1, __shfl_xor(v1, o));
    }
    mx0[j] = v0; mx1[j] = v1;
  }
  if (fr == 0){
    #pragma unroll
    for (int j = 0; j < 4; ++j){
      red1[w][qbase + j] = mx0[j];
      red1[w][16 + qbase + j] = mx1[j];
    }
  }
  __syncthreads();
  #pragma unroll
  for (int j = 0; j < 4; ++j){
    int q = qbase + j;
    mx0[j] = fmaxf(fmaxf(red1[0][q], red1[1][q]), fmaxf(red1[2][q], red1[3][q]));
    mx1[j] = fmaxf(fmaxf(red1[0][16+q], red1[1][16+q]), fmaxf(red1[2][16+q], red1[3][16+q]));
  }
  #pragma unroll
  for (int j = 0; j < 4; ++j){ sm0[j] = 0.f; sm1[j] = 0.f; }
  #pragma unroll
  for (int tt = 0; tt < 8; ++tt){
    f32x4 c0 = sreg0[tt], c1 = sreg1[tt];
    #pragma unroll
    for (int j = 0; j < 4; ++j){
      float e0 = expf(c0[j] - mx0[j]);
      float e1 = expf(c1[j] - mx1[j]);
      c0[j] = e0; c1[j] = e1;
      sm0[j] += e0; sm1[j] += e1;
    }
    sreg0[tt] = c0; sreg1[tt] = c1;
  }
  #pragma unroll
  for (int j = 0; j < 4; ++j){
    float v0 = sm0[j], v1 = sm1[j];
    #pragma unroll
    for (int o = 8; o >= 1; o >>= 1){
      v0 += __shfl_xor(v0, o);
      v1 += __shfl_xor(v1, o);
    }
    sm0[j] = v0; sm1[j] = v1;
  }
  if (fr == 0){
    #pragma unroll
    for (int j = 0; j < 4; ++j){
      red2[w][qbase + j] = sm0[j];
      red2[w][16 + qbase + j] = sm1[j];
    }
  }
  #pragma unroll
  for (int tt = 0; tt < 8; ++tt){
    int m = tt*64 + w*16 + fr;
    #pragma unroll
    for (int j = 0; j < 4; ++j){
      Sp[qbase + j][m]      = f2bf_rne(sreg0[tt][j]);
      Sp[16 + qbase + j][m] = f2bf_rne(sreg1[tt][j]);
    }
  }
  __syncthreads();
  #pragma unroll
  for (int j = 0; j < 4; ++j){
    int q = qbase + j;
    inv0[j] = 1.f / (red2[0][q] + red2[1][q] + red2[2][q] + red2[3][q]);
    inv1[j] = 1.f / (red2[0][16+q] + red2[1][16+q] + red2[2][16+q] + red2[3][16+q]);
  }

  // ---- AV for both tiles; V frags loaded once ----
  f32x4 oacc0 = {}, oacc1 = {};
  const unsigned short* vrh = VTh_g + ((size_t)b_*512 + h*64 + w*16 + fr)*512;
  const unsigned short* vrl = VTl_g + ((size_t)b_*512 + h*64 + w*16 + fr)*512;
  #pragma unroll
  for (int tt = 0; tt < 8; ++tt){
    #pragma unroll
    for (int ks = 0; ks < 2; ++ks){
      int moff = tt*64 + ks*32 + fc;
      short8v ap0 = *(const short8v*)&Sp[fr][moff];
      short8v ap1 = *(const short8v*)&Sp[16+fr][moff];
      short8v bh = *(const short8v*)(vrh + moff);
      short8v bl = *(const short8v*)(vrl + moff);
      oacc0 = __builtin_amdgcn_mfma_f32_16x16x32_bf16(ap0,bh,oacc0,0,0,0);
      oacc1 = __builtin_amdgcn_mfma_f32_16x16x32_bf16(ap1,bh,oacc1,0,0,0);
      oacc0 = __builtin_amdgcn_mfma_f32_16x16x32_bf16(ap0,bl,oacc0,0,0,0);
      oacc1 = __builtin_amdgcn_mfma_f32_16x16x32_bf16(ap1,bl,oacc1,0,0,0);
    }
  }
  {
    int d = w*16 + fr;
    #pragma unroll
    for (int j = 0; j < 4; ++j){
      // tile 0
      {
        int q = qbase + j;
        int l = l0 + q;
        float val = oacc0[j];
        #pragma unroll
        for (int dlt = 0; dlt < 9; ++dlt){
          int m = l + dlt - 4;
          if (m >= 0 && m < 512){
            float e = bf2f(Sp[q][m]);
            val += e * rv[dlt][d];
          }
        }
        val *= inv0[j];
        unsigned short hh, ll_; splitc(val, hh, ll_);
        size_t oidx = ((rowoff + l) << 9) + h*64 + d;
        Oh[oidx] = hh; Ol[oidx] = ll_;
      }
      // tile 1
      {
        int q = 16 + qbase + j;
        int l = l0 + q;
        float val = oacc1[j];
        #pragma unroll
        for (int dlt = 0; dlt < 9; ++dlt){
          int m = l + dlt - 4;
          if (m >= 0 && m < 512){
            float e = bf2f(Sp[q][m]);
            val += e * rv[dlt][d];
          }
        }
        val *= inv1[j];
        unsigned short hh, ll_; splitc(val, hh, ll_);
        size_t oidx = ((rowoff + l) << 9) + h*64 + d;
        Oh[oidx] = hh; Ol[oidx] = ll_;
      }
    }
  }
}

// ---------------- final transpose ----------------
__global__ __launch_bounds__(256) void transpose_out_k(const float* __restrict__ xn,
    const float* __restrict__ mask, float* __restrict__ out){
  __shared__ float tile[32][33];
  int b_ = blockIdx.z; int c0 = blockIdx.x*32; int l0 = blockIdx.y*32;
  int tx = threadIdx.x & 31, ty = threadIdx.x >> 5;
  #pragma unroll
  for (int r=0;r<4;r++){
    int l = l0 + ty + r*8;
    tile[ty + r*8][tx] = xn[(((size_t)(b_*512 + l))<<9) + c0 + tx];
  }
  __syncthreads();
  float mm = mask[b_*512 + l0 + tx];
  #pragma unroll
  for (int r=0;r<4;r++){
    int c = c0 + ty + r*8;
    out[(((size_t)(b_*512 + c))<<9) + l0 + tx] = tile[tx][ty + r*8] * mm;
  }
}

extern "C" void kernel_launch(void* const* d_in, const int* in_sizes, int n_in,
                              void* d_out, int out_size, void* d_ws, size_t ws_size,
                              hipStream_t stream) {
  const int*   tokens   = (const int*)  d_in[0];
  const float* style_v  = (const float*)d_in[1];
  const float* mask     = (const float*)d_in[2];
  const float* embed_w  = (const float*)d_in[3];
  const float* cw_dw_w  = (const float*)d_in[4];
  const float* cw_dw_b  = (const float*)d_in[5];
  const float* cw_ln_g  = (const float*)d_in[6];
  const float* cw_ln_b  = (const float*)d_in[7];
  const float* cw_pw1_w = (const float*)d_in[8];
  const float* cw_pw1_b = (const float*)d_in[9];
  const float* cw_pw2_w = (const float*)d_in[10];
  const float* cw_pw2_b = (const float*)d_in[11];
  const float* cw_gamma = (const float*)d_in[12];
  const float* aq_w = (const float*)d_in[13];
  const float* aq_b = (const float*)d_in[14];
  const float* ak_w = (const float*)d_in[15];
  const float* ak_b = (const float*)d_in[16];
  const float* av_w = (const float*)d_in[17];
  const float* av_b = (const float*)d_in[18];
  const float* ao_w = (const float*)d_in[19];
  const float* ao_b = (const float*)d_in[20];
  const float* rel_k = (const float*)d_in[21];
  const float* rel_v = (const float*)d_in[22];
  const float* ln1_g = (const float*)d_in[23];
  const float* ln1_b = (const float*)d_in[24];
  const float* ln2_g = (const float*)d_in[25];
  const float* ln2_b = (const float*)d_in[26];
  const float* ffn_w1 = (const float*)d_in[27];
  const float* ffn_b1 = (const float*)d_in[28];
  const float* ffn_w2 = (const float*)d_in[29];
  const float* ffn_b2 = (const float*)d_in[30];
  const float* style_key = (const float*)d_in[31];
  const float* sq_w = (const float*)d_in[32];
  const float* sq_b = (const float*)d_in[33];
  const float* sk_w = (const float*)d_in[34];
  const float* sk_b = (const float*)d_in[35];
  const float* sv_w = (const float*)d_in[36];
  const float* sv_b = (const float*)d_in[37];
  const float* so_w = (const float*)d_in[38];
  const float* so_b = (const float*)d_in[39];
  const float* sn_g = (const float*)d_in[40];
  const float* sn_b = (const float*)d_in[41];

  const int N = NROWS;
  char* cur = (char*)d_ws;
  auto nextF = [&](size_t n)->float*{ float* p=(float*)cur; cur += n*sizeof(float); return p; };
  auto nextU = [&](size_t n)->unsigned short*{ unsigned short* p=(unsigned short*)cur; cur += n*2; return p; };

  float* X   = nextF((size_t)N*512);
  float* T   = nextF((size_t)N*512);
  float* Qb  = nextF((size_t)N*512);
  float* Vb  = nextF((size_t)N*512);
  unsigned short* Xh = nextU((size_t)N*512);
  unsigned short* Xl = nextU((size_t)N*512);
  unsigned short* Th = nextU((size_t)N*512);
  unsigned short* Tl = nextU((size_t)N*512);
  unsigned short* Hbh = nextU((size_t)N*2048);
  unsigned short* Hbl = nextU((size_t)N*2048);
  unsigned short* QKVh = nextU((size_t)N*QKVS);
  unsigned short* QKVl = nextU((size_t)N*QKVS);
  unsigned short* VTh = nextU((size_t)8*512*512);
  unsigned short* VTl = nextU((size_t)8*512*512);
  // weight planes
  unsigned short* pw1h = nextU(4194304); unsigned short* pw1l = nextU(4194304);
  unsigned short* pw2h = nextU(4194304); unsigned short* pw2l = nextU(4194304);
  unsigned short* qkvh = nextU((size_t)6*QKVS*512); unsigned short* qkvl = nextU((size_t)6*QKVS*512);
  unsigned short* aoh  = nextU(1572864); unsigned short* aol  = nextU(1572864);
  unsigned short* f1h  = nextU(6291456); unsigned short* f1l  = nextU(6291456);
  unsigned short* f2h  = nextU(6291456); unsigned short* f2l  = nextU(6291456);
  unsigned short* sqh  = nextU(524288);  unsigned short* sql  = nextU(524288);
  unsigned short* soh  = nextU(524288);  unsigned short* sol  = nextU(524288);
  // style planes: KKp [2 layers][2 heads][64][256]; VTp [2][2][256][64]
  unsigned short* KKsh = nextU(65536); unsigned short* KKsl = nextU(65536);
  unsigned short* VTsh = nextU(65536); unsigned short* VTsl = nextU(65536);

  // ---- weight prep (single merged launch) ----
  split_all<<<dim3(512,8),256,0,stream>>>(cw_pw1_w, cw_pw2_w, ao_w, ffn_w1,
      ffn_w2, sq_w, so_w, aq_w, ak_w, av_w,
      pw1h, pw1l, pw2h, pw2l, aoh, aol, f1h, f1l, f2h, f2l,
      sqh, sql, soh, sol, qkvh, qkvl);

  dim3 gm512(8,64), gbig2048(16,32), gbigqkv(12,32);

  embed_k<<<4096,128,0,stream>>>(tokens, embed_w, mask, X);

  // ---- ConvNeXt blocks (dwconv+LN fused; last pw2 also emits planes) ----
  for (int i=0;i<4;i++){
    dwln_k<<<4096,128,0,stream>>>(X, cw_dw_w + (size_t)i*512*5, cw_dw_b + i*512,
        mask, cw_ln_g+i*512, cw_ln_b+i*512, Th, Tl);
    gemm_big<EPI_GELU,false,1><<<gbig2048,256,0,stream>>>(Th, Tl,
        pw1h + (size_t)i*1048576, pw1l + (size_t)i*1048576,
        cw_pw1_b+i*2048, nullptr, nullptr, nullptr, nullptr, Hbh, Hbl,
        nullptr, nullptr, 512, 2048, 0.f);
    if (i < 3)
      gemm_ps<EPI_RES_GAMMA_MASK,false,0,2><<<gm512,256,0,stream>>>(Hbh, Hbl,
          pw2h + (size_t)i*1048576, pw2l + (size_t)i*1048576,
          cw_pw2_b+i*512, X, cw_gamma+i*512, mask, X, nullptr, nullptr,
          nullptr, nullptr, 2048, 512, 0.f);
    else
      gemm_ps<EPI_RES_GAMMA_MASK,false,3,2><<<gm512,256,0,stream>>>(Hbh, Hbl,
          pw2h + (size_t)i*1048576, pw2l + (size_t)i*1048576,
          cw_pw2_b+i*512, X, cw_gamma+i*512, mask, X, Xh, Xl,
          nullptr, nullptr, 2048, 512, 0.f);
  }

  // ---- Attention layers ----
  for (int i=0;i<6;i++){
    gemm_big<EPI_QKV,false,2><<<gbigqkv,256,0,stream>>>(Xh, Xl,
        qkvh + (size_t)i*QKVS*512, qkvl + (size_t)i*QKVS*512,
        aq_b+i*512, ak_b+i*512, av_b+i*512, nullptr, nullptr, QKVh, QKVl,
        VTh, VTl, 512, QKVS, 0.125f);
    attn_mf<<<1024,256,0,stream>>>(QKVh, QKVl, VTh, VTl,
        rel_k + (size_t)i*9*64, rel_v + (size_t)i*9*64, mask, Th, Tl);
    gemm_ps<EPI_RES,false,0,2><<<gm512,256,0,stream>>>(Th, Tl,
        aoh + (size_t)i*262144, aol + (size_t)i*262144,
        ao_b+i*512, X, nullptr, nullptr, Qb, nullptr, nullptr,
        nullptr, nullptr, 512, 512, 0.f);
    ln_rows<true,false><<<1024,256,0,stream>>>(Qb, ln1_g+i*512, ln1_b+i*512,
        nullptr, X, Xh, Xl, N);
    gemm_big<EPI_RELU_MASK,true,1><<<gbig2048,256,0,stream>>>(Xh, Xl,
        f1h + (size_t)i*1048576, f1l + (size_t)i*1048576,
        ffn_b1+i*2048, nullptr, nullptr, mask, nullptr, Hbh, Hbl,
        nullptr, nullptr, 512, 2048, 0.f);
    gemm_ps<EPI_RES_MASK,false,0,2><<<gm512,256,0,stream>>>(Hbh, Hbl,
        f2h + (size_t)i*1048576, f2l + (size_t)i*1048576,
        ffn_b2+i*512, X, nullptr, mask, Qb, nullptr, nullptr,
        nullptr, nullptr, 2048, 512, 0.f);
    if (i < 5)
      ln_rows<true,false><<<1024,256,0,stream>>>(Qb, ln2_g+i*512, ln2_b+i*512,
          nullptr, X, Xh, Xl, N);
    else
      ln_rows<true,true><<<1024,256,0,stream>>>(Qb, ln2_g+i*512, ln2_b+i*512,
          mask, X, Xh, Xl, N);
  }

  // ---- Style attention (MFMA path) ----
  style_prep<<<dim3(8,4),256,0,stream>>>(style_key, style_v, sk_w, sk_b,
      sv_w, sv_b, KKsh, KKsl, VTsh, VTsl);

  // layer 0: xin = masked X -> Q planes -> style_mf -> so gemm (x1 planes)
  gemm_ps<EPI_BIAS,false,1,2><<<gm512,256,0,stream>>>(Xh, Xl, sqh, sql,
      sq_b, nullptr, nullptr, nullptr, nullptr, QKVh, QKVl,
      nullptr, nullptr, 512, 512, 0.f);
  style_mf<<<256,256,0,stream>>>(QKVh, QKVl, KKsh, KKsl, VTsh, VTsl,
      mask, Th, Tl);
  gemm_ps<EPI_RES_MASK,false,1,2><<<gm512,256,0,stream>>>(Th, Tl, soh, sol,
      so_b, X, nullptr, mask, nullptr, Hbh, Hbl,
      nullptr, nullptr, 512, 512, 0.f);   // x1 planes
  // layer 1: xin = x1 (planes); residual xt = X
  gemm_ps<EPI_BIAS,false,1,2><<<gm512,256,0,stream>>>(Hbh, Hbl, sqh+262144, sql+262144,
      sq_b+512, nullptr, nullptr, nullptr, nullptr, QKVh, QKVl,
      nullptr, nullptr, 512, 512, 0.f);
  style_mf<<<256,256,0,stream>>>(QKVh, QKVl, KKsh+32768, KKsl+32768,
      VTsh+32768, VTsl+32768, mask, Th, Tl);
  gemm_ps<EPI_RES_MASK,false,0,2><<<gm512,256,0,stream>>>(Th, Tl, soh+262144, sol+262144,
      so_b+512, X, nullptr, mask, Vb, nullptr, nullptr,
      nullptr, nullptr, 512, 512, 0.f);  // x2

  ln_rows<false,false><<<1024,256,0,stream>>>(Vb, sn_g, sn_b, nullptr,
      Qb, nullptr, nullptr, N);
  transpose_out_k<<<dim3(16,16,8),256,0,stream>>>(Qb, mask, (float*)d_out);
}

// Round 28
// 1662.084 us; speedup vs baseline: 1.1385x; 1.0266x over previous
//
#include <hip/hip_runtime.h>
#include <cstdint>

#define Bb 8
#define Ll 512
#define Cc 512
#define Hh 8
#define HD 64
#define Ff 2048
#define Ss 50
#define NROWS 4096   // B*L
#define QKVS 1536

typedef __attribute__((ext_vector_type(8))) short short8v;  // 8 bf16 (4 VGPR)
typedef __attribute__((ext_vector_type(4))) float f32x4;

__device__ __forceinline__ float wave_sum(float v){
  #pragma unroll
  for (int o=32;o>=1;o>>=1) v += __shfl_xor(v,o);
  return v;
}
__device__ __forceinline__ float bf2f(unsigned short u){
  return __uint_as_float(((unsigned)u) << 16);
}

// cheap split: hi = trunc-bf16(a); lo = trunc-bf16(a - hi). err ~ 2^-16 |a|
__device__ __forceinline__ void splitc(float a, unsigned short& hi, unsigned short& lo){
  unsigned u = __float_as_uint(a);
  hi = (unsigned short)(u >> 16);
  float l = a - __uint_as_float(u & 0xFFFF0000u);
  lo = (unsigned short)(__float_as_uint(l) >> 16);
}
__device__ __forceinline__ unsigned short f2bf_rne(float a){
  unsigned u = __float_as_uint(a);
  unsigned r = u + 0x7FFFu + ((u >> 16) & 1u);
  return (unsigned short)(r >> 16);
}
__device__ __forceinline__ void split4(float4 v, unsigned short* hi, unsigned short* lo){
  unsigned short h0,h1,h2,h3,l0,l1,l2,l3;
  splitc(v.x,h0,l0); splitc(v.y,h1,l1); splitc(v.z,h2,l2); splitc(v.w,h3,l3);
  *(ushort4*)hi = make_ushort4(h0,h1,h2,h3);
  *(ushort4*)lo = make_ushort4(l0,l1,l2,l3);
}

// ---------------- merged weight split: 8 segments in one launch --------------
__global__ __launch_bounds__(256) void split_all(
    const float* __restrict__ pw1w, const float* __restrict__ pw2w,
    const float* __restrict__ aow,  const float* __restrict__ f1w,
    const float* __restrict__ f2w,  const float* __restrict__ sqw,
    const float* __restrict__ sow,
    const float* __restrict__ aqw, const float* __restrict__ akw,
    const float* __restrict__ avw,
    unsigned short* __restrict__ pw1h, unsigned short* __restrict__ pw1l,
    unsigned short* __restrict__ pw2h, unsigned short* __restrict__ pw2l,
    unsigned short* __restrict__ aoh,  unsigned short* __restrict__ aol,
    unsigned short* __restrict__ f1h,  unsigned short* __restrict__ f1l,
    unsigned short* __restrict__ f2h,  unsigned short* __restrict__ f2l,
    unsigned short* __restrict__ sqh,  unsigned short* __restrict__ sql,
    unsigned short* __restrict__ soh,  unsigned short* __restrict__ sol,
    unsigned short* __restrict__ qkvh, unsigned short* __restrict__ qkvl)
{
  int seg = blockIdx.y;
  if (seg == 7){
    const int n4 = 6*QKVS*512/4;
    for (int i = blockIdx.x*256 + threadIdx.x; i < n4; i += gridDim.x*256){
      int e = i << 2;
      int layer = e / 786432;
      int r = e - layer*786432;
      int which = r >> 18;
      int off = r & 262143;
      const float* s = (which==0) ? aqw : (which==1) ? akw : avw;
      float4 vv = *(const float4*)(s + (size_t)layer*262144 + off);
      split4(vv, (unsigned short*)((ushort4*)qkvh + i),
                 (unsigned short*)((ushort4*)qkvl + i));
    }
    return;
  }
  const float* src; unsigned short* hi; unsigned short* lo; int n4;
  switch(seg){
    case 0: src=pw1w; hi=pw1h; lo=pw1l; n4=1048576; break;
    case 1: src=pw2w; hi=pw2h; lo=pw2l; n4=1048576; break;
    case 2: src=aow;  hi=aoh;  lo=aol;  n4=393216;  break;
    case 3: src=f1w;  hi=f1h;  lo=f1l;  n4=1572864; break;
    case 4: src=f2w;  hi=f2h;  lo=f2l;  n4=1572864; break;
    case 5: src=sqw;  hi=sqh;  lo=sql;  n4=131072;  break;
    default: src=sow; hi=soh;  lo=sol;  n4=131072;  break;
  }
  for (int i = blockIdx.x*256 + threadIdx.x; i < n4; i += gridDim.x*256){
    float4 v = ((const float4*)src)[i];
    split4(v, (unsigned short*)((ushort4*)hi + i), (unsigned short*)((ushort4*)lo + i));
  }
}

// ---------------- embed gather (mask fused) ----------------
__global__ __launch_bounds__(128) void embed_k(const int* __restrict__ tok,
    const float* __restrict__ emb, const float* __restrict__ mask,
    float* __restrict__ x){
  int n = blockIdx.x;
  int t = tok[n];
  float m = mask[n];
  float4 v = ((const float4*)(emb + ((size_t)t<<9)))[threadIdx.x];
  v.x*=m; v.y*=m; v.z*=m; v.w*=m;
  ((float4*)(x + ((size_t)n<<9)))[threadIdx.x] = v;
}

// ---------------- FUSED depthwise conv K=5 + bias + mask + LayerNorm + split --
__global__ __launch_bounds__(128) void dwln_k(const float* __restrict__ x,
    const float* __restrict__ w, const float* __restrict__ bias,
    const float* __restrict__ mask, const float* __restrict__ g,
    const float* __restrict__ bt, unsigned short* __restrict__ yh,
    unsigned short* __restrict__ yl){
  __shared__ float ws1[2], ws2[2];
  int n = blockIdx.x; int b_ = n >> 9, l = n & 511;
  int c0 = threadIdx.x * 4;
  float a0=bias[c0], a1=bias[c0+1], a2=bias[c0+2], a3=bias[c0+3];
  #pragma unroll
  for (int k=0;k<5;k++){
    int ls = l + k - 2; ls = ls < 0 ? 0 : (ls > 511 ? 511 : ls);
    const float4 xv = *(const float4*)&x[((size_t)(b_*512 + ls) << 9) + c0];
    a0 += w[(c0+0)*5+k]*xv.x;
    a1 += w[(c0+1)*5+k]*xv.y;
    a2 += w[(c0+2)*5+k]*xv.z;
    a3 += w[(c0+3)*5+k]*xv.w;
  }
  float mm = mask[n];
  a0*=mm; a1*=mm; a2*=mm; a3*=mm;
  int wv = threadIdx.x >> 6, ln_ = threadIdx.x & 63;
  float s = wave_sum(a0+a1+a2+a3);
  if (ln_ == 0) ws1[wv] = s;
  __syncthreads();
  float mean = (ws1[0] + ws1[1]) * (1.f/512.f);
  float d0=a0-mean, d1=a1-mean, d2=a2-mean, d3=a3-mean;
  float sq = wave_sum(d0*d0+d1*d1+d2*d2+d3*d3);
  if (ln_ == 0) ws2[wv] = sq;
  __syncthreads();
  float var = (ws2[0] + ws2[1]) * (1.f/512.f);
  float inv = 1.f/sqrtf(var + 1e-6f);
  float4 gv = *(const float4*)&g[c0];
  float4 bv = *(const float4*)&bt[c0];
  float4 o;
  o.x = d0*inv*gv.x + bv.x;
  o.y = d1*inv*gv.y + bv.y;
  o.z = d2*inv*gv.z + bv.z;
  o.w = d3*inv*gv.w + bv.w;
  size_t base = ((size_t)n << 9) + c0;
  split4(o, yh+base, yl+base);
}

// ---------------- rowwise LayerNorm over C=512 (optional split / mask) -------
template<bool SPLIT, bool MASK>
__global__ __launch_bounds__(256) void ln_rows(const float* __restrict__ x,
    const float* __restrict__ g, const float* __restrict__ bt,
    const float* __restrict__ rowmask,
    float* __restrict__ y, unsigned short* __restrict__ yh,
    unsigned short* __restrict__ yl, int nrows){
  int wid = threadIdx.x >> 6, lane = threadIdx.x & 63;
  int row = blockIdx.x*4 + wid;
  if (row >= nrows) return;
  const float4* xr = (const float4*)(x + ((size_t)row<<9));
  float4 a = xr[lane*2], b = xr[lane*2+1];
  float s = a.x+a.y+a.z+a.w+b.x+b.y+b.z+b.w;
  s = wave_sum(s);
  float m = s * (1.f/512.f);
  float d0=a.x-m,d1=a.y-m,d2=a.z-m,d3=a.w-m,d4=b.x-m,d5=b.y-m,d6=b.z-m,d7=b.w-m;
  float sq = d0*d0+d1*d1+d2*d2+d3*d3+d4*d4+d5*d5+d6*d6+d7*d7;
  sq = wave_sum(sq);
  float var = sq * (1.f/512.f);
  float inv = 1.f/sqrtf(var + 1e-6f);
  const float4* gr = (const float4*)g; const float4* br = (const float4*)bt;
  float4 g0=gr[lane*2], g1=gr[lane*2+1], b0=br[lane*2], b1=br[lane*2+1];
  float4 o0, o1;
  o0.x=d0*inv*g0.x+b0.x; o0.y=d1*inv*g0.y+b0.y; o0.z=d2*inv*g0.z+b0.z; o0.w=d3*inv*g0.w+b0.w;
  o1.x=d4*inv*g1.x+b1.x; o1.y=d5*inv*g1.y+b1.y; o1.z=d6*inv*g1.z+b1.z; o1.w=d7*inv*g1.w+b1.w;
  if constexpr (MASK){
    float mf = rowmask[row];
    o0.x*=mf; o0.y*=mf; o0.z*=mf; o0.w*=mf;
    o1.x*=mf; o1.y*=mf; o1.z*=mf; o1.w*=mf;
  }
  float4* yr = (float4*)(y + ((size_t)row<<9));
  yr[lane*2]=o0; yr[lane*2+1]=o1;
  if constexpr (SPLIT){
    size_t base = ((size_t)row<<9) + lane*8;
    split4(o0, yh+base,   yl+base);
    split4(o1, yh+base+4, yl+base+4);
  }
}

#define EPI_BIAS 0
#define EPI_SCALE 1
#define EPI_GELU 2
#define EPI_RES 3
#define EPI_RELU_MASK 4
#define EPI_RES_MASK 5
#define EPI_RES_GAMMA_MASK 6
#define EPI_TANH 7
#define EPI_QKV 8

// ---------------- style K/V prep -> bf16 planes (zero-padded to 64 keys) -----
__global__ __launch_bounds__(256) void style_prep(
    const float* __restrict__ style_key, const float* __restrict__ style_v,
    const float* __restrict__ sk_w, const float* __restrict__ sk_b,
    const float* __restrict__ sv_w, const float* __restrict__ sv_b,
    unsigned short* __restrict__ KKh, unsigned short* __restrict__ KKl,
    unsigned short* __restrict__ VTh_s, unsigned short* __restrict__ VTl_s)
{
  __shared__ float As[16][68];
  __shared__ float Bs[16][68];
  int sel = blockIdx.y;
  bool is_k = (sel < 2);
  int layer = sel & 1;
  const float* A = is_k ? style_key : style_v;
  const float* W = (sel==0) ? sk_w : (sel==1) ? sk_w+262144 :
                   (sel==2) ? sv_w : sv_w+262144;
  const float* bias = (sel==0) ? sk_b : (sel==1) ? sk_b+512 :
                      (sel==2) ? sv_b : sv_b+512;
  const int N = 50, K = 512;
  int t = threadIdx.x;
  int tx = t & 15, ty = t >> 4;
  int col0 = blockIdx.x << 6;
  int lr = t >> 2, lk = (t & 3) << 2;
  float acc[4][4] = {};
  bool arok = lr < N;
  const float* Ap = A + (size_t)(arok ? lr : 0) * K + lk;
  const float* Wp = W + (size_t)(col0 + lr) * K + lk;
  for (int k0 = 0; k0 < K; k0 += 16) {
    float4 av;
    if (arok) av = *(const float4*)(Ap + k0);
    else { av.x=0;av.y=0;av.z=0;av.w=0; }
    float4 bv = *(const float4*)(Wp + k0);
    As[lk+0][lr]=av.x; As[lk+1][lr]=av.y; As[lk+2][lr]=av.z; As[lk+3][lr]=av.w;
    Bs[lk+0][lr]=bv.x; Bs[lk+1][lr]=bv.y; Bs[lk+2][lr]=bv.z; Bs[lk+3][lr]=bv.w;
    __syncthreads();
    #pragma unroll
    for (int k=0;k<16;k++){
      float4 af = *(const float4*)&As[k][ty<<2];
      float4 bf = *(const float4*)&Bs[k][tx<<2];
      float a4[4]={af.x,af.y,af.z,af.w};
      float b4[4]={bf.x,bf.y,bf.z,bf.w};
      #pragma unroll
      for (int i=0;i<4;i++)
        #pragma unroll
        for (int j=0;j<4;j++)
          acc[i][j] += a4[i]*b4[j];
    }
    __syncthreads();
  }
  #pragma unroll
  for (int i=0;i<4;i++){
    int row = (ty<<2) + i;                 // 0..63 (padded keys zeroed)
    #pragma unroll
    for (int j=0;j<4;j++){
      int col = col0 + (tx<<2) + j;
      int head = col >> 8, d = col & 255;
      float v = 0.f;
      if (row < N){
        v = acc[i][j] + bias[col];
        if (is_k) v = tanhf(v);
      }
      unsigned short hh, ll_;
      splitc(v, hh, ll_);
      if (is_k){
        size_t o = (((size_t)layer*2 + head)<<14) + row*256 + d;
        KKh[o]=hh; KKl[o]=ll_;
      } else {
        size_t o = (((size_t)layer*2 + head)<<14) + d*64 + row;
        VTh_s[o]=hh; VTl_s[o]=ll_;
      }
    }
  }
}

// ---------------- MFMA style attention: block = 16 rows x 2 heads ------------
__global__ __launch_bounds__(256) void style_mf(
    const unsigned short* __restrict__ Qh_g, const unsigned short* __restrict__ Ql_g,
    const unsigned short* __restrict__ KKh, const unsigned short* __restrict__ KKl,
    const unsigned short* __restrict__ VTh_s, const unsigned short* __restrict__ VTl_s,
    const float* __restrict__ mask,
    unsigned short* __restrict__ Oh, unsigned short* __restrict__ Ol)
{
  __shared__ float Sc[2][16][68];
  __shared__ unsigned short Pph[2][16][72], Ppl[2][16][72];
  int t = threadIdx.x, lane = t & 63, w = t >> 6;
  int head = w >> 1, nh = w & 1;
  int rowbase = blockIdx.x * 16;
  int fr = lane & 15, fc = (lane >> 4) << 3, qbase = (lane >> 4) << 2;

  // ---- QK: S = Q_h . KK_h^T ----
  f32x4 s2[2] = {};
  #pragma unroll
  for (int ks = 0; ks < 8; ++ks){
    size_t qoff = (size_t)(rowbase + fr)*512 + head*256 + ks*32 + fc;
    short8v ah = *(const short8v*)(Qh_g + qoff);
    short8v al = *(const short8v*)(Ql_g + qoff);
    #pragma unroll
    for (int nt = 0; nt < 2; ++nt){
      int key = nh*32 + nt*16 + fr;
      size_t ko = (((size_t)head)<<14) + key*256 + ks*32 + fc;
      short8v bh = *(const short8v*)(KKh + ko);
      short8v bl = *(const short8v*)(KKl + ko);
      f32x4 c = s2[nt];
      c = __builtin_amdgcn_mfma_f32_16x16x32_bf16(ah,bh,c,0,0,0);
      c = __builtin_amdgcn_mfma_f32_16x16x32_bf16(ah,bl,c,0,0,0);
      c = __builtin_amdgcn_mfma_f32_16x16x32_bf16(al,bh,c,0,0,0);
      s2[nt] = c;
    }
  }
  #pragma unroll
  for (int nt = 0; nt < 2; ++nt)
    #pragma unroll
    for (int j = 0; j < 4; ++j)
      Sc[head][qbase+j][nh*32 + nt*16 + fr] = s2[nt][j] * 0.044194173824159216f;
  __syncthreads();

  // ---- softmax over 50 keys (32 threads: head x row); keep/sum folded in ----
  if (t < 32){
    int h2 = t >> 4, r = t & 15;
    float mx = -3.4e38f;
    for (int ss = 0; ss < 50; ++ss) mx = fmaxf(mx, Sc[h2][r][ss]);
    float sum = 0.f;
    for (int ss = 0; ss < 50; ++ss) sum += expf(Sc[h2][r][ss] - mx);
    float keep = (mask[rowbase + r] == 0.f) ? 0.f : 1.f;
    float inv = keep / sum;
    for (int ss = 0; ss < 64; ++ss){
      float p = (ss < 50) ? expf(Sc[h2][r][ss] - mx) * inv : 0.f;
      unsigned short hh, ll_;
      splitc(p, hh, ll_);
      Pph[h2][r][ss] = hh; Ppl[h2][r][ss] = ll_;
    }
  }
  __syncthreads();

  // ---- AV: O = P . V ----
  f32x4 av[8] = {};
  #pragma unroll
  for (int ks = 0; ks < 2; ++ks){
    short8v ah = *(const short8v*)&Pph[head][fr][ks*32 + fc];
    short8v al = *(const short8v*)&Ppl[head][fr][ks*32 + fc];
    #pragma unroll
    for (int nt = 0; nt < 8; ++nt){
      int d = nh*128 + nt*16 + fr;
      size_t vo = (((size_t)head)<<14) + d*64 + ks*32 + fc;
      short8v bh = *(const short8v*)(VTh_s + vo);
      short8v bl = *(const short8v*)(VTl_s + vo);
      f32x4 c = av[nt];
      c = __builtin_amdgcn_mfma_f32_16x16x32_bf16(ah,bh,c,0,0,0);
      c = __builtin_amdgcn_mfma_f32_16x16x32_bf16(ah,bl,c,0,0,0);
      c = __builtin_amdgcn_mfma_f32_16x16x32_bf16(al,bh,c,0,0,0);
      av[nt] = c;
    }
  }
  #pragma unroll
  for (int nt = 0; nt < 8; ++nt)
    #pragma unroll
    for (int j = 0; j < 4; ++j){
      int row = rowbase + qbase + j;
      int d = nh*128 + nt*16 + fr;
      unsigned short hh, ll_;
      splitc(av[nt][j], hh, ll_);
      size_t o = (size_t)row*512 + head*256 + d;
      Oh[o] = hh; Ol[o] = ll_;
    }
}

// ---------------- pre-split MFMA GEMM, double-buffered LDS (64-row tiles) ----
// OUT: 0 = fp32 Y, 1 = planes, 2 = QKV mode, 3 = fp32 Y + planes.
// SWZ=1: 1D grid, XCD-aware remap so col-blocks sharing an A-row co-locate
// on one XCD (A-tile becomes L2-resident; used for K=2048 O=512 GEMMs).
template<int EPI, bool AMASK, int OUT, int NF, int SWZ>
__global__ __launch_bounds__(256) void gemm_ps(
    const unsigned short* __restrict__ Ah, const unsigned short* __restrict__ Al,
    const unsigned short* __restrict__ Wh, const unsigned short* __restrict__ Wl,
    const float* __restrict__ bias, const float* __restrict__ res,
    const float* __restrict__ gamma, const float* __restrict__ rowmask,
    float* __restrict__ Y, unsigned short* __restrict__ Yh,
    unsigned short* __restrict__ Yl, unsigned short* __restrict__ VTh,
    unsigned short* __restrict__ VTl, int K, int O, float scale)
{
  __shared__ unsigned short AhS[2][64][40], AlS[2][64][40];
  __shared__ unsigned short BhS[2][NF*32][40], BlS[2][NF*32][40];
  int t = threadIdx.x;
  int row0, col0;
  if constexpr (SWZ){
    int id = blockIdx.x;          // 512 blocks; XCD = id & 7
    int slot = id >> 3;           // 0..63
    row0 = ((id & 7) + ((slot >> 3) << 3)) << 6;   // rows == xcd (mod 8)
    col0 = (slot & 7) << 6;                        // 8 col-blocks per row
  } else {
    row0 = blockIdx.y << 6;
    col0 = blockIdx.x << (NF==4 ? 7 : 6);
  }
  int lane = t & 63, wid = t >> 6;
  int wr = wid >> 1, wc = wid & 1;

  int sr = t >> 2, sc = (t & 3) << 3;
  const unsigned short* Ahg = Ah + (size_t)(row0 + sr)*K + sc;
  const unsigned short* Alg = Al + (size_t)(row0 + sr)*K + sc;
  const unsigned short* Bhg = Wh + (size_t)(col0 + sr)*K + sc;
  const unsigned short* Blg = Wl + (size_t)(col0 + sr)*K + sc;
  float am = 1.f;
  if (AMASK) am = rowmask[row0 + sr];

  f32x4 acc[2][NF] = {};
  int nsteps = K >> 5;
  short8v ah_, al_, bh0_, bl0_, bh1_, bl1_;
  ah_ = *(const short8v*)(Ahg);
  al_ = *(const short8v*)(Alg);
  bh0_ = *(const short8v*)(Bhg);
  bl0_ = *(const short8v*)(Blg);
  if constexpr (NF==4){
    bh1_ = *(const short8v*)(Bhg + (size_t)64*K);
    bl1_ = *(const short8v*)(Blg + (size_t)64*K);
  }
  if (AMASK && am == 0.f){ ah_ ^= ah_; al_ ^= al_; }
  *(short8v*)&AhS[0][sr][sc] = ah_;
  *(short8v*)&AlS[0][sr][sc] = al_;
  *(short8v*)&BhS[0][sr][sc] = bh0_;
  *(short8v*)&BlS[0][sr][sc] = bl0_;
  if constexpr (NF==4){
    *(short8v*)&BhS[0][sr+64][sc] = bh1_;
    *(short8v*)&BlS[0][sr+64][sc] = bl1_;
  }

  int st = 0;
  for (int s = 0; s < nsteps; ++s){
    if (s+1 < nsteps){
      int ko = (s+1) << 5;
      ah_ = *(const short8v*)(Ahg + ko);
      al_ = *(const short8v*)(Alg + ko);
      bh0_ = *(const short8v*)(Bhg + ko);
      bl0_ = *(const short8v*)(Blg + ko);
      if constexpr (NF==4){
        bh1_ = *(const short8v*)(Bhg + (size_t)64*K + ko);
        bl1_ = *(const short8v*)(Blg + (size_t)64*K + ko);
      }
      if (AMASK && am == 0.f){ ah_ ^= ah_; al_ ^= al_; }
    }
    __syncthreads();
    int fr = lane & 15, fc = (lane >> 4) << 3;
    short8v ahf[2], alf[2], bhf[NF], blf[NF];
    #pragma unroll
    for (int mt=0; mt<2; ++mt){
      int r = (wr<<5) + (mt<<4) + fr;
      ahf[mt] = *(const short8v*)&AhS[st][r][fc];
      alf[mt] = *(const short8v*)&AlS[st][r][fc];
    }
    #pragma unroll
    for (int nt=0; nt<NF; ++nt){
      int r = (NF==4 ? (wc<<6) : (wc<<5)) + (nt<<4) + fr;
      bhf[nt] = *(const short8v*)&BhS[st][r][fc];
      blf[nt] = *(const short8v*)&BlS[st][r][fc];
    }
    #pragma unroll
    for (int mt=0; mt<2; ++mt)
      #pragma unroll
      for (int nt=0; nt<NF; ++nt){
        f32x4 c = acc[mt][nt];
        c = __builtin_amdgcn_mfma_f32_16x16x32_bf16(ahf[mt], bhf[nt], c, 0,0,0);
        c = __builtin_amdgcn_mfma_f32_16x16x32_bf16(ahf[mt], blf[nt], c, 0,0,0);
        c = __builtin_amdgcn_mfma_f32_16x16x32_bf16(alf[mt], bhf[nt], c, 0,0,0);
        acc[mt][nt] = c;
      }
    if (s+1 < nsteps){
      int nb = st ^ 1;
      *(short8v*)&AhS[nb][sr][sc] = ah_;
      *(short8v*)&AlS[nb][sr][sc] = al_;
      *(short8v*)&BhS[nb][sr][sc] = bh0_;
      *(short8v*)&BlS[nb][sr][sc] = bl0_;
      if constexpr (NF==4){
        *(short8v*)&BhS[nb][sr+64][sc] = bh1_;
        *(short8v*)&BlS[nb][sr+64][sc] = bl1_;
      }
    }
    st ^= 1;
  }

  int rb = row0 + (wr<<5) + ((lane>>4)<<2);
  int cb = col0 + (NF==4 ? (wc<<6) : (wc<<5)) + (lane & 15);
  float bs[NF], gm[NF];
  int which = 0;
  if constexpr (EPI==EPI_QKV) which = blockIdx.x >> 2;
  #pragma unroll
  for (int nt=0; nt<NF; ++nt){
    int col = cb + (nt<<4);
    if constexpr (EPI==EPI_QKV){
      const float* bp = (which==0) ? bias : (which==1) ? res : gamma;
      bs[nt] = bp[col & 511];
    } else {
      bs[nt] = bias[col];
      if constexpr (EPI==EPI_RES_GAMMA_MASK) gm[nt] = gamma[col];
    }
  }
  float qscale = 1.f;
  if constexpr (EPI==EPI_QKV) qscale = (which==0) ? scale : 1.f;

  if constexpr (OUT==2){
    if (which == 2){
      #pragma unroll
      for (int mt=0; mt<2; ++mt){
        int row = rb + (mt<<4);
        int b = row >> 9, tok = row & 511;
        #pragma unroll
        for (int nt=0; nt<NF; ++nt){
          int dglob = cb + (nt<<4) - 1024;
          size_t vt = ((size_t)b*512 + dglob)*512 + tok;
          unsigned short h4[4], l4[4];
          #pragma unroll
          for (int j=0; j<4; ++j)
            splitc(acc[mt][nt][j] + bs[nt], h4[j], l4[j]);
          *(ushort4*)&VTh[vt] = make_ushort4(h4[0],h4[1],h4[2],h4[3]);
          *(ushort4*)&VTl[vt] = make_ushort4(l4[0],l4[1],l4[2],l4[3]);
        }
      }
      return;
    }
    #pragma unroll
    for (int mt=0; mt<2; ++mt)
      #pragma unroll
      for (int j=0; j<4; ++j){
        int row = rb + (mt<<4) + j;
        #pragma unroll
        for (int nt=0; nt<NF; ++nt){
          float v = (acc[mt][nt][j] + bs[nt]) * qscale;
          size_t oidx = (size_t)row*O + cb + (nt<<4);
          unsigned short h,l; splitc(v,h,l); Yh[oidx]=h; Yl[oidx]=l;
        }
      }
    return;
  }

  #pragma unroll
  for (int mt=0; mt<2; ++mt)
    #pragma unroll
    for (int j=0; j<4; ++j){
      int row = rb + (mt<<4) + j;
      float rm = 1.f;
      if constexpr (EPI==EPI_RELU_MASK || EPI==EPI_RES_MASK || EPI==EPI_RES_GAMMA_MASK)
        rm = rowmask[row];
      const float* rr = nullptr;
      if constexpr (EPI==EPI_RES || EPI==EPI_RES_MASK || EPI==EPI_RES_GAMMA_MASK)
        rr = res + (size_t)row*O + cb;
      #pragma unroll
      for (int nt=0; nt<NF; ++nt){
        float v = acc[mt][nt][j] + bs[nt];
        if constexpr (EPI==EPI_SCALE) v *= scale;
        else if constexpr (EPI==EPI_QKV) v *= qscale;
        else if constexpr (EPI==EPI_GELU) v = 0.5f*v*(1.f+erff(v*0.7071067811865475f));
        else if constexpr (EPI==EPI_RES) v = rr[nt<<4] + v;
        else if constexpr (EPI==EPI_RELU_MASK) v = fmaxf(v,0.f)*rm;
        else if constexpr (EPI==EPI_RES_MASK) v = rr[nt<<4] + v*rm;
        else if constexpr (EPI==EPI_RES_GAMMA_MASK) v = (rr[nt<<4] + gm[nt]*v)*rm;
        size_t oidx = (size_t)row*O + cb + (nt<<4);
        if constexpr (OUT==0) Y[oidx] = v;
        else if constexpr (OUT==3){
          Y[oidx] = v;
          unsigned short h,l; splitc(v,h,l); Yh[oidx]=h; Yl[oidx]=l;
        }
        else { unsigned short h,l; splitc(v,h,l); Yh[oidx]=h; Yl[oidx]=l; }
      }
    }
}

// ---------------- 128x128x32 MFMA GEMM (big-O GEMMs: pw1/ffn1/QKV) -----------
template<int EPI, bool AMASK, int OUT>
__global__ __launch_bounds__(256) void gemm_big(
    const unsigned short* __restrict__ Ah, const unsigned short* __restrict__ Al,
    const unsigned short* __restrict__ Wh, const unsigned short* __restrict__ Wl,
    const float* __restrict__ bias, const float* __restrict__ res,
    const float* __restrict__ gamma, const float* __restrict__ rowmask,
    float* __restrict__ Y, unsigned short* __restrict__ Yh,
    unsigned short* __restrict__ Yl, unsigned short* __restrict__ VTh,
    unsigned short* __restrict__ VTl, int K, int O, float scale)
{
  __shared__ unsigned short AhS[128][40], AlS[128][40];
  __shared__ unsigned short BhS[128][40], BlS[128][40];
  int t = threadIdx.x;
  int row0 = blockIdx.y << 7, col0 = blockIdx.x << 7;
  int lane = t & 63, wid = t >> 6;
  int wr = wid >> 1, wc = wid & 1;

  int sr = t >> 2, sc = (t & 3) << 3;
  const unsigned short* Ahg = Ah + (size_t)(row0 + sr)*K + sc;
  const unsigned short* Alg = Al + (size_t)(row0 + sr)*K + sc;
  const unsigned short* Bhg = Wh + (size_t)(col0 + sr)*K + sc;
  const unsigned short* Blg = Wl + (size_t)(col0 + sr)*K + sc;
  bool az0 = false, az1 = false;
  if (AMASK){ az0 = (rowmask[row0+sr] == 0.f); az1 = (rowmask[row0+sr+64] == 0.f); }

  f32x4 acc[4][4] = {};
  int nsteps = K >> 5;
  short8v a0h,a0l,a1h,a1l,b0h,b0l,b1h,b1l;
  a0h = *(const short8v*)(Ahg);
  a0l = *(const short8v*)(Alg);
  a1h = *(const short8v*)(Ahg + (size_t)64*K);
  a1l = *(const short8v*)(Alg + (size_t)64*K);
  b0h = *(const short8v*)(Bhg);
  b0l = *(const short8v*)(Blg);
  b1h = *(const short8v*)(Bhg + (size_t)64*K);
  b1l = *(const short8v*)(Blg + (size_t)64*K);

  for (int s = 0; s < nsteps; ++s){
    if (AMASK){
      if (az0){ a0h ^= a0h; a0l ^= a0l; }
      if (az1){ a1h ^= a1h; a1l ^= a1l; }
    }
    __syncthreads();
    *(short8v*)&AhS[sr][sc] = a0h;    *(short8v*)&AlS[sr][sc] = a0l;
    *(short8v*)&AhS[sr+64][sc] = a1h; *(short8v*)&AlS[sr+64][sc] = a1l;
    *(short8v*)&BhS[sr][sc] = b0h;    *(short8v*)&BlS[sr][sc] = b0l;
    *(short8v*)&BhS[sr+64][sc] = b1h; *(short8v*)&BlS[sr+64][sc] = b1l;
    __syncthreads();
    if (s+1 < nsteps){
      int ko = (s+1) << 5;
      a0h = *(const short8v*)(Ahg + ko);
      a0l = *(const short8v*)(Alg + ko);
      a1h = *(const short8v*)(Ahg + (size_t)64*K + ko);
      a1l = *(const short8v*)(Alg + (size_t)64*K + ko);
      b0h = *(const short8v*)(Bhg + ko);
      b0l = *(const short8v*)(Blg + ko);
      b1h = *(const short8v*)(Bhg + (size_t)64*K + ko);
      b1l = *(const short8v*)(Blg + (size_t)64*K + ko);
    }
    int fr = lane & 15, fc = (lane >> 4) << 3;
    short8v ahf[4], alf[4], bhf[4], blf[4];
    #pragma unroll
    for (int mt=0; mt<4; ++mt){
      int r = (wr<<6) + (mt<<4) + fr;
      ahf[mt] = *(const short8v*)&AhS[r][fc];
      alf[mt] = *(const short8v*)&AlS[r][fc];
    }
    #pragma unroll
    for (int nt=0; nt<4; ++nt){
      int r = (wc<<6) + (nt<<4) + fr;
      bhf[nt] = *(const short8v*)&BhS[r][fc];
      blf[nt] = *(const short8v*)&BlS[r][fc];
    }
    #pragma unroll
    for (int mt=0; mt<4; ++mt)
      #pragma unroll
      for (int nt=0; nt<4; ++nt){
        f32x4 c = acc[mt][nt];
        c = __builtin_amdgcn_mfma_f32_16x16x32_bf16(ahf[mt], bhf[nt], c, 0,0,0);
        c = __builtin_amdgcn_mfma_f32_16x16x32_bf16(ahf[mt], blf[nt], c, 0,0,0);
        c = __builtin_amdgcn_mfma_f32_16x16x32_bf16(alf[mt], bhf[nt], c, 0,0,0);
        acc[mt][nt] = c;
      }
  }

  int rb = row0 + (wr<<6) + ((lane>>4)<<2);
  int cb = col0 + (wc<<6) + (lane & 15);
  float bs[4];
  int which = 0;
  if constexpr (EPI==EPI_QKV) which = blockIdx.x >> 2;
  #pragma unroll
  for (int nt=0; nt<4; ++nt){
    int col = cb + (nt<<4);
    if constexpr (EPI==EPI_QKV){
      const float* bp = (which==0) ? bias : (which==1) ? res : gamma;
      bs[nt] = bp[col & 511];
    } else {
      bs[nt] = bias[col];
    }
  }
  float qscale = 1.f;
  if constexpr (EPI==EPI_QKV) qscale = (which==0) ? scale : 1.f;

  if constexpr (OUT==2){
    if (which == 2){
      #pragma unroll
      for (int mt=0; mt<4; ++mt){
        int row = rb + (mt<<4);
        int b = row >> 9, tok = row & 511;
        #pragma unroll
        for (int nt=0; nt<4; ++nt){
          int dglob = cb + (nt<<4) - 1024;
          size_t vt = ((size_t)b*512 + dglob)*512 + tok;
          unsigned short h4[4], l4[4];
          #pragma unroll
          for (int j=0; j<4; ++j)
            splitc(acc[mt][nt][j] + bs[nt], h4[j], l4[j]);
          *(ushort4*)&VTh[vt] = make_ushort4(h4[0],h4[1],h4[2],h4[3]);
          *(ushort4*)&VTl[vt] = make_ushort4(l4[0],l4[1],l4[2],l4[3]);
        }
      }
      return;
    }
    #pragma unroll
    for (int mt=0; mt<4; ++mt)
      #pragma unroll
      for (int j=0; j<4; ++j){
        int row = rb + (mt<<4) + j;
        #pragma unroll
        for (int nt=0; nt<4; ++nt){
          float v = (acc[mt][nt][j] + bs[nt]) * qscale;
          size_t oidx = (size_t)row*O + cb + (nt<<4);
          unsigned short h,l; splitc(v,h,l); Yh[oidx]=h; Yl[oidx]=l;
        }
      }
    return;
  }

  #pragma unroll
  for (int mt=0; mt<4; ++mt)
    #pragma unroll
    for (int j=0; j<4; ++j){
      int row = rb + (mt<<4) + j;
      float rm = 1.f;
      if constexpr (EPI==EPI_RELU_MASK) rm = rowmask[row];
      #pragma unroll
      for (int nt=0; nt<4; ++nt){
        float v = acc[mt][nt][j] + bs[nt];
        if constexpr (EPI==EPI_GELU) v = 0.5f*v*(1.f+erff(v*0.7071067811865475f));
        else if constexpr (EPI==EPI_RELU_MASK) v = fmaxf(v,0.f)*rm;
        size_t oidx = (size_t)row*O + cb + (nt<<4);
        if constexpr (OUT==0) Y[oidx] = v;
        else { unsigned short h,l; splitc(v,h,l); Yh[oidx]=h; Yl[oidx]=l; }
      }
    }
}

// ---------------- MFMA windowed-rel attention v4: 2 Q-tiles per block --------
// 32 Q-rows/block; K/V fragment loads amortized over 2x MFMA work.
// Single RNE bf16 P plane (proven accuracy-safe in v3.5).
__global__ __launch_bounds__(256) void attn_mf(
    const unsigned short* __restrict__ Ph_g, const unsigned short* __restrict__ Pl_g,
    const unsigned short* __restrict__ VTh_g, const unsigned short* __restrict__ VTl_g,
    const float* __restrict__ relk, const float* __restrict__ relv,
    const float* __restrict__ mask, unsigned short* __restrict__ Oh,
    unsigned short* __restrict__ Ol)
{
  __shared__ float ms_[512];
  __shared__ float rv[9][64];
  __shared__ float qrel[32][16];
  __shared__ float red1[4][32];
  __shared__ float red2[4][32];
  __shared__ __align__(16) unsigned short Spool[32*520];
  // overlay views (valid only before the qrel barrier):
  unsigned short (*Qh)[72]  = (unsigned short(*)[72])(Spool);          // [32][72]
  unsigned short (*Ql)[72]  = (unsigned short(*)[72])(Spool + 2304);   // [32][72]
  unsigned short (*Rkh)[72] = (unsigned short(*)[72])(Spool + 4608);   // [16][72]
  unsigned short (*Rkl)[72] = (unsigned short(*)[72])(Spool + 5760);   // [16][72]
  // P view (valid only after the qrel barrier): [32][520]
  unsigned short (*Sp)[520] = (unsigned short(*)[520])(Spool);

  int id = blockIdx.x;
  int xcd = id & 7, kk = id >> 3;
  int bh_ = xcd*8 + (kk >> 4);
  int qt = kk & 15;
  int h = bh_ & 7, b_ = bh_ >> 3;
  int t = threadIdx.x;
  int l0 = qt * 32;
  const size_t rowoff = (size_t)b_ * 512;
  int lane = t & 63, w = t >> 6;

  ms_[t] = mask[rowoff + t]; ms_[t+256] = mask[rowoff + t + 256];
  for (int i = t; i < 576; i += 256) ((float*)rv)[i] = relv[i];
  {
    int r = t >> 4, c = (t & 15) << 2;
    float4 v;
    if (r < 9) v = *(const float4*)&relk[r*64 + c];
    else { v.x=0.f; v.y=0.f; v.z=0.f; v.w=0.f; }
    split4(v, &Rkh[r][c], &Rkl[r][c]);
  }
  // Q load: 32 rows x 64 cols x 2 planes; 512 chunks of 8 shorts, 2/thread
  for (int i = t; i < 512; i += 256){
    int r = (i & 255) >> 3, c = (i & 7) << 3;
    size_t g = (rowoff + l0 + r)*QKVS + h*64 + c;
    if (i < 256) *(short8v*)&Qh[r][c] = *(const short8v*)&Ph_g[g];
    else         *(short8v*)&Ql[r][c] = *(const short8v*)&Pl_g[g];
  }
  __syncthreads();

  int fr = lane & 15, fc = (lane >> 4) << 3;
  int qbase = (lane>>4) << 2;
  // tile0 rows fr, tile1 rows 16+fr
  short8v a0h0 = *(const short8v*)&Qh[fr][fc];
  short8v a0h1 = *(const short8v*)&Qh[fr][32+fc];
  short8v a0l0 = *(const short8v*)&Ql[fr][fc];
  short8v a0l1 = *(const short8v*)&Ql[fr][32+fc];
  short8v a1h0 = *(const short8v*)&Qh[16+fr][fc];
  short8v a1h1 = *(const short8v*)&Qh[16+fr][32+fc];
  short8v a1l0 = *(const short8v*)&Ql[16+fr][fc];
  short8v a1l1 = *(const short8v*)&Ql[16+fr][32+fc];

  // qrel for both tiles: wave 0 -> rows 0..15, wave 1 -> rows 16..31
  if (w < 2){
    short8v rh0 = *(const short8v*)&Rkh[fr][fc];
    short8v rh1 = *(const short8v*)&Rkh[fr][32+fc];
    short8v rl0 = *(const short8v*)&Rkl[fr][fc];
    short8v rl1 = *(const short8v*)&Rkl[fr][32+fc];
    short8v qa0 = (w==0) ? a0h0 : a1h0;
    short8v qa1 = (w==0) ? a0h1 : a1h1;
    short8v qb0 = (w==0) ? a0l0 : a1l0;
    short8v qb1 = (w==0) ? a0l1 : a1l1;
    f32x4 c4 = {};
    c4 = __builtin_amdgcn_mfma_f32_16x16x32_bf16(qa0,rh0,c4,0,0,0);
    c4 = __builtin_amdgcn_mfma_f32_16x16x32_bf16(qa1,rh1,c4,0,0,0);
    c4 = __builtin_amdgcn_mfma_f32_16x16x32_bf16(qa0,rl0,c4,0,0,0);
    c4 = __builtin_amdgcn_mfma_f32_16x16x32_bf16(qa1,rl1,c4,0,0,0);
    c4 = __builtin_amdgcn_mfma_f32_16x16x32_bf16(qb0,rh0,c4,0,0,0);
    c4 = __builtin_amdgcn_mfma_f32_16x16x32_bf16(qb1,rh1,c4,0,0,0);
    #pragma unroll
    for (int j = 0; j < 4; ++j) qrel[w*16 + qbase + j][fr] = c4[j];
  }
  __syncthreads();   // after this: Q/Rk LDS dead, P region live

  // ---- QK for both tiles; K frags loaded once ----
  f32x4 sreg0[8], sreg1[8];
  #pragma unroll
  for (int tt = 0; tt < 8; ++tt){
    int br = tt*64 + w*16 + fr;
    const unsigned short* krh = Ph_g + (rowoff + br)*QKVS + 512 + h*64;
    const unsigned short* krl = Pl_g + (rowoff + br)*QKVS + 512 + h*64;
    short8v bh0 = *(const short8v*)(krh + fc);
    short8v bh1 = *(const short8v*)(krh + 32 + fc);
    short8v bl0 = *(const short8v*)(krl + fc);
    short8v bl1 = *(const short8v*)(krl + 32 + fc);
    f32x4 c0 = {}, c1 = {};
    c0 = __builtin_amdgcn_mfma_f32_16x16x32_bf16(a0h0,bh0,c0,0,0,0);
    c1 = __builtin_amdgcn_mfma_f32_16x16x32_bf16(a1h0,bh0,c1,0,0,0);
    c0 = __builtin_amdgcn_mfma_f32_16x16x32_bf16(a0h1,bh1,c0,0,0,0);
    c1 = __builtin_amdgcn_mfma_f32_16x16x32_bf16(a1h1,bh1,c1,0,0,0);
    c0 = __builtin_amdgcn_mfma_f32_16x16x32_bf16(a0h0,bl0,c0,0,0,0);
    c1 = __builtin_amdgcn_mfma_f32_16x16x32_bf16(a1h0,bl0,c1,0,0,0);
    c0 = __builtin_amdgcn_mfma_f32_16x16x32_bf16(a0h1,bl1,c0,0,0,0);
    c1 = __builtin_amdgcn_mfma_f32_16x16x32_bf16(a1h1,bl1,c1,0,0,0);
    c0 = __builtin_amdgcn_mfma_f32_16x16x32_bf16(a0l0,bh0,c0,0,0,0);
    c1 = __builtin_amdgcn_mfma_f32_16x16x32_bf16(a1l0,bh0,c1,0,0,0);
    c0 = __builtin_amdgcn_mfma_f32_16x16x32_bf16(a0l1,bh1,c0,0,0,0);
    c1 = __builtin_amdgcn_mfma_f32_16x16x32_bf16(a1l1,bh1,c1,0,0,0);
    int m = tt*64 + w*16 + fr;
    float mm_ = ms_[m];
    #pragma unroll
    for (int j = 0; j < 4; ++j){
      int q = qbase + j;
      // tile 0
      {
        int l = l0 + q;
        float s = c0[j];
        int dlt = m - l + 4;
        if (dlt >= 0 && dlt <= 8) s += qrel[q][dlt];
        if (ms_[l] * mm_ == 0.f) s = -10000.f;
        c0[j] = s;
      }
      // tile 1
      {
        int l = l0 + 16 + q;
        float s = c1[j];
        int dlt = m - l + 4;
        if (dlt >= 0 && dlt <= 8) s += qrel[16 + q][dlt];
        if (ms_[l] * mm_ == 0.f) s = -10000.f;
        c1[j] = s;
      }
    }
    sreg0[tt] = c0; sreg1[tt] = c1;
  }

  float mx0[4], mx1[4], sm0[4], sm1[4], inv0[4], inv1[4];
  #pragma unroll
  for (int j = 0; j < 4; ++j){
    float v0 = sreg0[0][j], v1 = sreg1[0][j];
    #pragma unroll
    for (int tt = 1; tt < 8; ++tt){
      v0 = fmaxf(v0, sreg0[tt][j]);
      v1 = fmaxf(v1, sreg1[tt][j]);
    }
    #pragma unroll
    for (int o = 8; o >= 1; o >>= 1){
      v0 = fmaxf(v0, __shfl_xor(v0, o));
      v1 = fmaxf(v1, __shfl_xor(v1, o));
    }
    mx0[j] = v0; mx1[j] = v1;
  }
  if (fr == 0){
    #pragma unroll
    for (int j = 0; j < 4; ++j){
      red1[w][qbase + j] = mx0[j];
      red1[w][16 + qbase + j] = mx1[j];
    }
  }
  __syncthreads();
  #pragma unroll
  for (int j = 0; j < 4; ++j){
    int q = qbase + j;
    mx0[j] = fmaxf(fmaxf(red1[0][q], red1[1][q]), fmaxf(red1[2][q], red1[3][q]));
    mx1[j] = fmaxf(fmaxf(red1[0][16+q], red1[1][16+q]), fmaxf(red1[2][16+q], red1[3][16+q]));
  }
  #pragma unroll
  for (int j = 0; j < 4; ++j){ sm0[j] = 0.f; sm1[j] = 0.f; }
  #pragma unroll
  for (int tt = 0; tt < 8; ++tt){
    f32x4 c0 = sreg0[tt], c1 = sreg1[tt];
    #pragma unroll
    for (int j = 0; j < 4; ++j){
      float e0 = expf(c0[j] - mx0[j]);
      float e1 = expf(c1[j] - mx1[j]);
      c0[j] = e0; c1[j] = e1;
      sm0[j] += e0; sm1[j] += e1;
    }
    sreg0[tt] = c0; sreg1[tt] = c1;
  }
  #pragma unroll
  for (int j = 0; j < 4; ++j){
    float v0 = sm0[j], v1 = sm1[j];
    #pragma unroll
    for (int o = 8; o >= 1; o >>= 1){
      v0 += __shfl_xor(v0, o);
      v1 += __shfl_xor(v1, o);
    }
    sm0[j] = v0; sm1[j] = v1;
  }
  if (fr == 0){
    #pragma unroll
    for (int j = 0; j < 4; ++j){
      red2[w][qbase + j] = sm0[j];
      red2[w][16 + qbase + j] = sm1[j];
    }
  }
  #pragma unroll
  for (int tt = 0; tt < 8; ++tt){
    int m = tt*64 + w*16 + fr;
    #pragma unroll
    for (int j = 0; j < 4; ++j){
      Sp[qbase + j][m]      = f2bf_rne(sreg0[tt][j]);
      Sp[16 + qbase + j][m] = f2bf_rne(sreg1[tt][j]);
    }
  }
  __syncthreads();
  #pragma unroll
  for (int j = 0; j < 4; ++j){
    int q = qbase + j;
    inv0[j] = 1.f / (red2[0][q] + red2[1][q] + red2[2][q] + red2[3][q]);
    inv1[j] = 1.f / (red2[0][16+q] + red2[1][16+q] + red2[2][16+q] + red2[3][16+q]);
  }

  // ---- AV for both tiles; V frags loaded once ----
  f32x4 oacc0 = {}, oacc1 = {};
  const unsigned short* vrh = VTh_g + ((size_t)b_*512 + h*64 + w*16 + fr)*512;
  const unsigned short* vrl = VTl_g + ((size_t)b_*512 + h*64 + w*16 + fr)*512;
  #pragma unroll
  for (int tt = 0; tt < 8; ++tt){
    #pragma unroll
    for (int ks = 0; ks < 2; ++ks){
      int moff = tt*64 + ks*32 + fc;
      short8v ap0 = *(const short8v*)&Sp[fr][moff];
      short8v ap1 = *(const short8v*)&Sp[16+fr][moff];
      short8v bh = *(const short8v*)(vrh + moff);
      short8v bl = *(const short8v*)(vrl + moff);
      oacc0 = __builtin_amdgcn_mfma_f32_16x16x32_bf16(ap0,bh,oacc0,0,0,0);
      oacc1 = __builtin_amdgcn_mfma_f32_16x16x32_bf16(ap1,bh,oacc1,0,0,0);
      oacc0 = __builtin_amdgcn_mfma_f32_16x16x32_bf16(ap0,bl,oacc0,0,0,0);
      oacc1 = __builtin_amdgcn_mfma_f32_16x16x32_bf16(ap1,bl,oacc1,0,0,0);
    }
  }
  {
    int d = w*16 + fr;
    #pragma unroll
    for (int j = 0; j < 4; ++j){
      // tile 0
      {
        int q = qbase + j;
        int l = l0 + q;
        float val = oacc0[j];
        #pragma unroll
        for (int dlt = 0; dlt < 9; ++dlt){
          int m = l + dlt - 4;
          if (m >= 0 && m < 512){
            float e = bf2f(Sp[q][m]);
            val += e * rv[dlt][d];
          }
        }
        val *= inv0[j];
        unsigned short hh, ll_; splitc(val, hh, ll_);
        size_t oidx = ((rowoff + l) << 9) + h*64 + d;
        Oh[oidx] = hh; Ol[oidx] = ll_;
      }
      // tile 1
      {
        int q = 16 + qbase + j;
        int l = l0 + q;
        float val = oacc1[j];
        #pragma unroll
        for (int dlt = 0; dlt < 9; ++dlt){
          int m = l + dlt - 4;
          if (m >= 0 && m < 512){
            float e = bf2f(Sp[q][m]);
            val += e * rv[dlt][d];
          }
        }
        val *= inv1[j];
        unsigned short hh, ll_; splitc(val, hh, ll_);
        size_t oidx = ((rowoff + l) << 9) + h*64 + d;
        Oh[oidx] = hh; Ol[oidx] = ll_;
      }
    }
  }
}

// ---------------- final transpose ----------------
__global__ __launch_bounds__(256) void transpose_out_k(const float* __restrict__ xn,
    const float* __restrict__ mask, float* __restrict__ out){
  __shared__ float tile[32][33];
  int b_ = blockIdx.z; int c0 = blockIdx.x*32; int l0 = blockIdx.y*32;
  int tx = threadIdx.x & 31, ty = threadIdx.x >> 5;
  #pragma unroll
  for (int r=0;r<4;r++){
    int l = l0 + ty + r*8;
    tile[ty + r*8][tx] = xn[(((size_t)(b_*512 + l))<<9) + c0 + tx];
  }
  __syncthreads();
  float mm = mask[b_*512 + l0 + tx];
  #pragma unroll
  for (int r=0;r<4;r++){
    int c = c0 + ty + r*8;
    out[(((size_t)(b_*512 + c))<<9) + l0 + tx] = tile[tx][ty + r*8] * mm;
  }
}

extern "C" void kernel_launch(void* const* d_in, const int* in_sizes, int n_in,
                              void* d_out, int out_size, void* d_ws, size_t ws_size,
                              hipStream_t stream) {
  const int*   tokens   = (const int*)  d_in[0];
  const float* style_v  = (const float*)d_in[1];
  const float* mask     = (const float*)d_in[2];
  const float* embed_w  = (const float*)d_in[3];
  const float* cw_dw_w  = (const float*)d_in[4];
  const float* cw_dw_b  = (const float*)d_in[5];
  const float* cw_ln_g  = (const float*)d_in[6];
  const float* cw_ln_b  = (const float*)d_in[7];
  const float* cw_pw1_w = (const float*)d_in[8];
  const float* cw_pw1_b = (const float*)d_in[9];
  const float* cw_pw2_w = (const float*)d_in[10];
  const float* cw_pw2_b = (const float*)d_in[11];
  const float* cw_gamma = (const float*)d_in[12];
  const float* aq_w = (const float*)d_in[13];
  const float* aq_b = (const float*)d_in[14];
  const float* ak_w = (const float*)d_in[15];
  const float* ak_b = (const float*)d_in[16];
  const float* av_w = (const float*)d_in[17];
  const float* av_b = (const float*)d_in[18];
  const float* ao_w = (const float*)d_in[19];
  const float* ao_b = (const float*)d_in[20];
  const float* rel_k = (const float*)d_in[21];
  const float* rel_v = (const float*)d_in[22];
  const float* ln1_g = (const float*)d_in[23];
  const float* ln1_b = (const float*)d_in[24];
  const float* ln2_g = (const float*)d_in[25];
  const float* ln2_b = (const float*)d_in[26];
  const float* ffn_w1 = (const float*)d_in[27];
  const float* ffn_b1 = (const float*)d_in[28];
  const float* ffn_w2 = (const float*)d_in[29];
  const float* ffn_b2 = (const float*)d_in[30];
  const float* style_key = (const float*)d_in[31];
  const float* sq_w = (const float*)d_in[32];
  const float* sq_b = (const float*)d_in[33];
  const float* sk_w = (const float*)d_in[34];
  const float* sk_b = (const float*)d_in[35];
  const float* sv_w = (const float*)d_in[36];
  const float* sv_b = (const float*)d_in[37];
  const float* so_w = (const float*)d_in[38];
  const float* so_b = (const float*)d_in[39];
  const float* sn_g = (const float*)d_in[40];
  const float* sn_b = (const float*)d_in[41];

  const int N = NROWS;
  char* cur = (char*)d_ws;
  auto nextF = [&](size_t n)->float*{ float* p=(float*)cur; cur += n*sizeof(float); return p; };
  auto nextU = [&](size_t n)->unsigned short*{ unsigned short* p=(unsigned short*)cur; cur += n*2; return p; };

  float* X   = nextF((size_t)N*512);
  float* T   = nextF((size_t)N*512);
  float* Qb  = nextF((size_t)N*512);
  float* Vb  = nextF((size_t)N*512);
  unsigned short* Xh = nextU((size_t)N*512);
  unsigned short* Xl = nextU((size_t)N*512);
  unsigned short* Th = nextU((size_t)N*512);
  unsigned short* Tl = nextU((size_t)N*512);
  unsigned short* Hbh = nextU((size_t)N*2048);
  unsigned short* Hbl = nextU((size_t)N*2048);
  unsigned short* QKVh = nextU((size_t)N*QKVS);
  unsigned short* QKVl = nextU((size_t)N*QKVS);
  unsigned short* VTh = nextU((size_t)8*512*512);
  unsigned short* VTl = nextU((size_t)8*512*512);
  // weight planes
  unsigned short* pw1h = nextU(4194304); unsigned short* pw1l = nextU(4194304);
  unsigned short* pw2h = nextU(4194304); unsigned short* pw2l = nextU(4194304);
  unsigned short* qkvh = nextU((size_t)6*QKVS*512); unsigned short* qkvl = nextU((size_t)6*QKVS*512);
  unsigned short* aoh  = nextU(1572864); unsigned short* aol  = nextU(1572864);
  unsigned short* f1h  = nextU(6291456); unsigned short* f1l  = nextU(6291456);
  unsigned short* f2h  = nextU(6291456); unsigned short* f2l  = nextU(6291456);
  unsigned short* sqh  = nextU(524288);  unsigned short* sql  = nextU(524288);
  unsigned short* soh  = nextU(524288);  unsigned short* sol  = nextU(524288);
  // style planes: KKp [2 layers][2 heads][64][256]; VTp [2][2][256][64]
  unsigned short* KKsh = nextU(65536); unsigned short* KKsl = nextU(65536);
  unsigned short* VTsh = nextU(65536); unsigned short* VTsl = nextU(65536);

  // ---- weight prep (single merged launch) ----
  split_all<<<dim3(512,8),256,0,stream>>>(cw_pw1_w, cw_pw2_w, ao_w, ffn_w1,
      ffn_w2, sq_w, so_w, aq_w, ak_w, av_w,
      pw1h, pw1l, pw2h, pw2l, aoh, aol, f1h, f1l, f2h, f2l,
      sqh, sql, soh, sol, qkvh, qkvl);

  dim3 gm512(8,64), gbig2048(16,32), gbigqkv(12,32);

  embed_k<<<4096,128,0,stream>>>(tokens, embed_w, mask, X);

  // ---- ConvNeXt blocks (dwconv+LN fused; K=2048 pw2 XCD-swizzled) ----
  for (int i=0;i<4;i++){
    dwln_k<<<4096,128,0,stream>>>(X, cw_dw_w + (size_t)i*512*5, cw_dw_b + i*512,
        mask, cw_ln_g+i*512, cw_ln_b+i*512, Th, Tl);
    gemm_big<EPI_GELU,false,1><<<gbig2048,256,0,stream>>>(Th, Tl,
        pw1h + (size_t)i*1048576, pw1l + (size_t)i*1048576,
        cw_pw1_b+i*2048, nullptr, nullptr, nullptr, nullptr, Hbh, Hbl,
        nullptr, nullptr, 512, 2048, 0.f);
    if (i < 3)
      gemm_ps<EPI_RES_GAMMA_MASK,false,0,2,1><<<512,256,0,stream>>>(Hbh, Hbl,
          pw2h + (size_t)i*1048576, pw2l + (size_t)i*1048576,
          cw_pw2_b+i*512, X, cw_gamma+i*512, mask, X, nullptr, nullptr,
          nullptr, nullptr, 2048, 512, 0.f);
    else
      gemm_ps<EPI_RES_GAMMA_MASK,false,3,2,1><<<512,256,0,stream>>>(Hbh, Hbl,
          pw2h + (size_t)i*1048576, pw2l + (size_t)i*1048576,
          cw_pw2_b+i*512, X, cw_gamma+i*512, mask, X, Xh, Xl,
          nullptr, nullptr, 2048, 512, 0.f);
  }

  // ---- Attention layers ----
  for (int i=0;i<6;i++){
    gemm_big<EPI_QKV,false,2><<<gbigqkv,256,0,stream>>>(Xh, Xl,
        qkvh + (size_t)i*QKVS*512, qkvl + (size_t)i*QKVS*512,
        aq_b+i*512, ak_b+i*512, av_b+i*512, nullptr, nullptr, QKVh, QKVl,
        VTh, VTl, 512, QKVS, 0.125f);
    attn_mf<<<1024,256,0,stream>>>(QKVh, QKVl, VTh, VTl,
        rel_k + (size_t)i*9*64, rel_v + (size_t)i*9*64, mask, Th, Tl);
    gemm_ps<EPI_RES,false,0,2,0><<<gm512,256,0,stream>>>(Th, Tl,
        aoh + (size_t)i*262144, aol + (size_t)i*262144,
        ao_b+i*512, X, nullptr, nullptr, Qb, nullptr, nullptr,
        nullptr, nullptr, 512, 512, 0.f);
    ln_rows<true,false><<<1024,256,0,stream>>>(Qb, ln1_g+i*512, ln1_b+i*512,
        nullptr, X, Xh, Xl, N);
    gemm_big<EPI_RELU_MASK,true,1><<<gbig2048,256,0,stream>>>(Xh, Xl,
        f1h + (size_t)i*1048576, f1l + (size_t)i*1048576,
        ffn_b1+i*2048, nullptr, nullptr, mask, nullptr, Hbh, Hbl,
        nullptr, nullptr, 512, 2048, 0.f);
    gemm_ps<EPI_RES_MASK,false,0,2,1><<<512,256,0,stream>>>(Hbh, Hbl,
        f2h + (size_t)i*1048576, f2l + (size_t)i*1048576,
        ffn_b2+i*512, X, nullptr, mask, Qb, nullptr, nullptr,
        nullptr, nullptr, 2048, 512, 0.f);
    if (i < 5)
      ln_rows<true,false><<<1024,256,0,stream>>>(Qb, ln2_g+i*512, ln2_b+i*512,
          nullptr, X, Xh, Xl, N);
    else
      ln_rows<true,true><<<1024,256,0,stream>>>(Qb, ln2_g+i*512, ln2_b+i*512,
          mask, X, Xh, Xl, N);
  }

  // ---- Style attention (MFMA path) ----
  style_prep<<<dim3(8,4),256,0,stream>>>(style_key, style_v, sk_w, sk_b,
      sv_w, sv_b, KKsh, KKsl, VTsh, VTsl);

  // layer 0: xin = masked X -> Q planes -> style_mf -> so gemm (x1 planes)
  gemm_ps<EPI_BIAS,false,1,2,0><<<gm512,256,0,stream>>>(Xh, Xl, sqh, sql,
      sq_b, nullptr, nullptr, nullptr, nullptr, QKVh, QKVl,
      nullptr, nullptr, 512, 512, 0.f);
  style_mf<<<256,256,0,stream>>>(QKVh, QKVl, KKsh, KKsl, VTsh, VTsl,
      mask, Th, Tl);
  gemm_ps<EPI_RES_MASK,false,1,2,0><<<gm512,256,0,stream>>>(Th, Tl, soh, sol,
      so_b, X, nullptr, mask, nullptr, Hbh, Hbl,
      nullptr, nullptr, 512, 512, 0.f);   // x1 planes
  // layer 1: xin = x1 (planes); residual xt = X
  gemm_ps<EPI_BIAS,false,1,2,0><<<gm512,256,0,stream>>>(Hbh, Hbl, sqh+262144, sql+262144,
      sq_b+512, nullptr, nullptr, nullptr, nullptr, QKVh, QKVl,
      nullptr, nullptr, 512, 512, 0.f);
  style_mf<<<256,256,0,stream>>>(QKVh, QKVl, KKsh+32768, KKsl+32768,
      VTsh+32768, VTsl+32768, mask, Th, Tl);
  gemm_ps<EPI_RES_MASK,false,0,2,0><<<gm512,256,0,stream>>>(Th, Tl, soh+262144, sol+262144,
      so_b+512, X, nullptr, mask, Vb, nullptr, nullptr,
      nullptr, nullptr, 512, 512, 0.f);  // x2

  ln_rows<false,false><<<1024,256,0,stream>>>(Vb, sn_g, sn_b, nullptr,
      Qb, nullptr, nullptr, N);
  transpose_out_k<<<dim3(16,16,8),256,0,stream>>>(Qb, mask, (float*)d_out);
}

// Round 29
// 1635.703 us; speedup vs baseline: 1.1569x; 1.0161x over previous
//
#include <hip/hip_runtime.h>
#include <cstdint>

#define Bb 8
#define Ll 512
#define Cc 512
#define Hh 8
#define HD 64
#define Ff 2048
#define Ss 50
#define NROWS 4096   // B*L
#define QKVS 1536

typedef __attribute__((ext_vector_type(8))) short short8v;  // 8 bf16 (4 VGPR)
typedef __attribute__((ext_vector_type(4))) float f32x4;

__device__ __forceinline__ float wave_sum(float v){
  #pragma unroll
  for (int o=32;o>=1;o>>=1) v += __shfl_xor(v,o);
  return v;
}
__device__ __forceinline__ float bf2f(unsigned short u){
  return __uint_as_float(((unsigned)u) << 16);
}

// cheap split: hi = trunc-bf16(a); lo = trunc-bf16(a - hi). err ~ 2^-16 |a|
__device__ __forceinline__ void splitc(float a, unsigned short& hi, unsigned short& lo){
  unsigned u = __float_as_uint(a);
  hi = (unsigned short)(u >> 16);
  float l = a - __uint_as_float(u & 0xFFFF0000u);
  lo = (unsigned short)(__float_as_uint(l) >> 16);
}
__device__ __forceinline__ unsigned short f2bf_rne(float a){
  unsigned u = __float_as_uint(a);
  unsigned r = u + 0x7FFFu + ((u >> 16) & 1u);
  return (unsigned short)(r >> 16);
}
__device__ __forceinline__ void split4(float4 v, unsigned short* hi, unsigned short* lo){
  unsigned short h0,h1,h2,h3,l0,l1,l2,l3;
  splitc(v.x,h0,l0); splitc(v.y,h1,l1); splitc(v.z,h2,l2); splitc(v.w,h3,l3);
  *(ushort4*)hi = make_ushort4(h0,h1,h2,h3);
  *(ushort4*)lo = make_ushort4(l0,l1,l2,l3);
}

// ---------------- merged weight split: 8 segments in one launch --------------
__global__ __launch_bounds__(256) void split_all(
    const float* __restrict__ pw1w, const float* __restrict__ pw2w,
    const float* __restrict__ aow,  const float* __restrict__ f1w,
    const float* __restrict__ f2w,  const float* __restrict__ sqw,
    const float* __restrict__ sow,
    const float* __restrict__ aqw, const float* __restrict__ akw,
    const float* __restrict__ avw,
    unsigned short* __restrict__ pw1h, unsigned short* __restrict__ pw1l,
    unsigned short* __restrict__ pw2h, unsigned short* __restrict__ pw2l,
    unsigned short* __restrict__ aoh,  unsigned short* __restrict__ aol,
    unsigned short* __restrict__ f1h,  unsigned short* __restrict__ f1l,
    unsigned short* __restrict__ f2h,  unsigned short* __restrict__ f2l,
    unsigned short* __restrict__ sqh,  unsigned short* __restrict__ sql,
    unsigned short* __restrict__ soh,  unsigned short* __restrict__ sol,
    unsigned short* __restrict__ qkvh, unsigned short* __restrict__ qkvl)
{
  int seg = blockIdx.y;
  if (seg == 7){
    const int n4 = 6*QKVS*512/4;
    for (int i = blockIdx.x*256 + threadIdx.x; i < n4; i += gridDim.x*256){
      int e = i << 2;
      int layer = e / 786432;
      int r = e - layer*786432;
      int which = r >> 18;
      int off = r & 262143;
      const float* s = (which==0) ? aqw : (which==1) ? akw : avw;
      float4 vv = *(const float4*)(s + (size_t)layer*262144 + off);
      split4(vv, (unsigned short*)((ushort4*)qkvh + i),
                 (unsigned short*)((ushort4*)qkvl + i));
    }
    return;
  }
  const float* src; unsigned short* hi; unsigned short* lo; int n4;
  switch(seg){
    case 0: src=pw1w; hi=pw1h; lo=pw1l; n4=1048576; break;
    case 1: src=pw2w; hi=pw2h; lo=pw2l; n4=1048576; break;
    case 2: src=aow;  hi=aoh;  lo=aol;  n4=393216;  break;
    case 3: src=f1w;  hi=f1h;  lo=f1l;  n4=1572864; break;
    case 4: src=f2w;  hi=f2h;  lo=f2l;  n4=1572864; break;
    case 5: src=sqw;  hi=sqh;  lo=sql;  n4=131072;  break;
    default: src=sow; hi=soh;  lo=sol;  n4=131072;  break;
  }
  for (int i = blockIdx.x*256 + threadIdx.x; i < n4; i += gridDim.x*256){
    float4 v = ((const float4*)src)[i];
    split4(v, (unsigned short*)((ushort4*)hi + i), (unsigned short*)((ushort4*)lo + i));
  }
}

// ---------------- embed gather (mask fused) ----------------
__global__ __launch_bounds__(128) void embed_k(const int* __restrict__ tok,
    const float* __restrict__ emb, const float* __restrict__ mask,
    float* __restrict__ x){
  int n = blockIdx.x;
  int t = tok[n];
  float m = mask[n];
  float4 v = ((const float4*)(emb + ((size_t)t<<9)))[threadIdx.x];
  v.x*=m; v.y*=m; v.z*=m; v.w*=m;
  ((float4*)(x + ((size_t)n<<9)))[threadIdx.x] = v;
}

// ---------------- FUSED depthwise conv K=5 + bias + mask + LayerNorm + split --
__global__ __launch_bounds__(128) void dwln_k(const float* __restrict__ x,
    const float* __restrict__ w, const float* __restrict__ bias,
    const float* __restrict__ mask, const float* __restrict__ g,
    const float* __restrict__ bt, unsigned short* __restrict__ yh,
    unsigned short* __restrict__ yl){
  __shared__ float ws1[2], ws2[2];
  int n = blockIdx.x; int b_ = n >> 9, l = n & 511;
  int c0 = threadIdx.x * 4;
  float a0=bias[c0], a1=bias[c0+1], a2=bias[c0+2], a3=bias[c0+3];
  #pragma unroll
  for (int k=0;k<5;k++){
    int ls = l + k - 2; ls = ls < 0 ? 0 : (ls > 511 ? 511 : ls);
    const float4 xv = *(const float4*)&x[((size_t)(b_*512 + ls) << 9) + c0];
    a0 += w[(c0+0)*5+k]*xv.x;
    a1 += w[(c0+1)*5+k]*xv.y;
    a2 += w[(c0+2)*5+k]*xv.z;
    a3 += w[(c0+3)*5+k]*xv.w;
  }
  float mm = mask[n];
  a0*=mm; a1*=mm; a2*=mm; a3*=mm;
  int wv = threadIdx.x >> 6, ln_ = threadIdx.x & 63;
  float s = wave_sum(a0+a1+a2+a3);
  if (ln_ == 0) ws1[wv] = s;
  __syncthreads();
  float mean = (ws1[0] + ws1[1]) * (1.f/512.f);
  float d0=a0-mean, d1=a1-mean, d2=a2-mean, d3=a3-mean;
  float sq = wave_sum(d0*d0+d1*d1+d2*d2+d3*d3);
  if (ln_ == 0) ws2[wv] = sq;
  __syncthreads();
  float var = (ws2[0] + ws2[1]) * (1.f/512.f);
  float inv = 1.f/sqrtf(var + 1e-6f);
  float4 gv = *(const float4*)&g[c0];
  float4 bv = *(const float4*)&bt[c0];
  float4 o;
  o.x = d0*inv*gv.x + bv.x;
  o.y = d1*inv*gv.y + bv.y;
  o.z = d2*inv*gv.z + bv.z;
  o.w = d3*inv*gv.w + bv.w;
  size_t base = ((size_t)n << 9) + c0;
  split4(o, yh+base, yl+base);
}

// ---------------- rowwise LayerNorm over C=512 (optional split / mask) -------
template<bool SPLIT, bool MASK>
__global__ __launch_bounds__(256) void ln_rows(const float* __restrict__ x,
    const float* __restrict__ g, const float* __restrict__ bt,
    const float* __restrict__ rowmask,
    float* __restrict__ y, unsigned short* __restrict__ yh,
    unsigned short* __restrict__ yl, int nrows){
  int wid = threadIdx.x >> 6, lane = threadIdx.x & 63;
  int row = blockIdx.x*4 + wid;
  if (row >= nrows) return;
  const float4* xr = (const float4*)(x + ((size_t)row<<9));
  float4 a = xr[lane*2], b = xr[lane*2+1];
  float s = a.x+a.y+a.z+a.w+b.x+b.y+b.z+b.w;
  s = wave_sum(s);
  float m = s * (1.f/512.f);
  float d0=a.x-m,d1=a.y-m,d2=a.z-m,d3=a.w-m,d4=b.x-m,d5=b.y-m,d6=b.z-m,d7=b.w-m;
  float sq = d0*d0+d1*d1+d2*d2+d3*d3+d4*d4+d5*d5+d6*d6+d7*d7;
  sq = wave_sum(sq);
  float var = sq * (1.f/512.f);
  float inv = 1.f/sqrtf(var + 1e-6f);
  const float4* gr = (const float4*)g; const float4* br = (const float4*)bt;
  float4 g0=gr[lane*2], g1=gr[lane*2+1], b0=br[lane*2], b1=br[lane*2+1];
  float4 o0, o1;
  o0.x=d0*inv*g0.x+b0.x; o0.y=d1*inv*g0.y+b0.y; o0.z=d2*inv*g0.z+b0.z; o0.w=d3*inv*g0.w+b0.w;
  o1.x=d4*inv*g1.x+b1.x; o1.y=d5*inv*g1.y+b1.y; o1.z=d6*inv*g1.z+b1.z; o1.w=d7*inv*g1.w+b1.w;
  if constexpr (MASK){
    float mf = rowmask[row];
    o0.x*=mf; o0.y*=mf; o0.z*=mf; o0.w*=mf;
    o1.x*=mf; o1.y*=mf; o1.z*=mf; o1.w*=mf;
  }
  float4* yr = (float4*)(y + ((size_t)row<<9));
  yr[lane*2]=o0; yr[lane*2+1]=o1;
  if constexpr (SPLIT){
    size_t base = ((size_t)row<<9) + lane*8;
    split4(o0, yh+base,   yl+base);
    split4(o1, yh+base+4, yl+base+4);
  }
}

#define EPI_BIAS 0
#define EPI_SCALE 1
#define EPI_GELU 2
#define EPI_RES 3
#define EPI_RELU_MASK 4
#define EPI_RES_MASK 5
#define EPI_RES_GAMMA_MASK 6
#define EPI_TANH 7
#define EPI_QKV 8

// ---------------- style K/V prep -> bf16 planes (zero-padded to 64 keys) -----
__global__ __launch_bounds__(256) void style_prep(
    const float* __restrict__ style_key, const float* __restrict__ style_v,
    const float* __restrict__ sk_w, const float* __restrict__ sk_b,
    const float* __restrict__ sv_w, const float* __restrict__ sv_b,
    unsigned short* __restrict__ KKh, unsigned short* __restrict__ KKl,
    unsigned short* __restrict__ VTh_s, unsigned short* __restrict__ VTl_s)
{
  __shared__ float As[16][68];
  __shared__ float Bs[16][68];
  int sel = blockIdx.y;
  bool is_k = (sel < 2);
  int layer = sel & 1;
  const float* A = is_k ? style_key : style_v;
  const float* W = (sel==0) ? sk_w : (sel==1) ? sk_w+262144 :
                   (sel==2) ? sv_w : sv_w+262144;
  const float* bias = (sel==0) ? sk_b : (sel==1) ? sk_b+512 :
                      (sel==2) ? sv_b : sv_b+512;
  const int N = 50, K = 512;
  int t = threadIdx.x;
  int tx = t & 15, ty = t >> 4;
  int col0 = blockIdx.x << 6;
  int lr = t >> 2, lk = (t & 3) << 2;
  float acc[4][4] = {};
  bool arok = lr < N;
  const float* Ap = A + (size_t)(arok ? lr : 0) * K + lk;
  const float* Wp = W + (size_t)(col0 + lr) * K + lk;
  for (int k0 = 0; k0 < K; k0 += 16) {
    float4 av;
    if (arok) av = *(const float4*)(Ap + k0);
    else { av.x=0;av.y=0;av.z=0;av.w=0; }
    float4 bv = *(const float4*)(Wp + k0);
    As[lk+0][lr]=av.x; As[lk+1][lr]=av.y; As[lk+2][lr]=av.z; As[lk+3][lr]=av.w;
    Bs[lk+0][lr]=bv.x; Bs[lk+1][lr]=bv.y; Bs[lk+2][lr]=bv.z; Bs[lk+3][lr]=bv.w;
    __syncthreads();
    #pragma unroll
    for (int k=0;k<16;k++){
      float4 af = *(const float4*)&As[k][ty<<2];
      float4 bf = *(const float4*)&Bs[k][tx<<2];
      float a4[4]={af.x,af.y,af.z,af.w};
      float b4[4]={bf.x,bf.y,bf.z,bf.w};
      #pragma unroll
      for (int i=0;i<4;i++)
        #pragma unroll
        for (int j=0;j<4;j++)
          acc[i][j] += a4[i]*b4[j];
    }
    __syncthreads();
  }
  #pragma unroll
  for (int i=0;i<4;i++){
    int row = (ty<<2) + i;                 // 0..63 (padded keys zeroed)
    #pragma unroll
    for (int j=0;j<4;j++){
      int col = col0 + (tx<<2) + j;
      int head = col >> 8, d = col & 255;
      float v = 0.f;
      if (row < N){
        v = acc[i][j] + bias[col];
        if (is_k) v = tanhf(v);
      }
      unsigned short hh, ll_;
      splitc(v, hh, ll_);
      if (is_k){
        size_t o = (((size_t)layer*2 + head)<<14) + row*256 + d;
        KKh[o]=hh; KKl[o]=ll_;
      } else {
        size_t o = (((size_t)layer*2 + head)<<14) + d*64 + row;
        VTh_s[o]=hh; VTl_s[o]=ll_;
      }
    }
  }
}

// ---------------- MFMA style attention: block = 16 rows x 2 heads ------------
__global__ __launch_bounds__(256) void style_mf(
    const unsigned short* __restrict__ Qh_g, const unsigned short* __restrict__ Ql_g,
    const unsigned short* __restrict__ KKh, const unsigned short* __restrict__ KKl,
    const unsigned short* __restrict__ VTh_s, const unsigned short* __restrict__ VTl_s,
    const float* __restrict__ mask,
    unsigned short* __restrict__ Oh, unsigned short* __restrict__ Ol)
{
  __shared__ float Sc[2][16][68];
  __shared__ unsigned short Pph[2][16][72], Ppl[2][16][72];
  int t = threadIdx.x, lane = t & 63, w = t >> 6;
  int head = w >> 1, nh = w & 1;
  int rowbase = blockIdx.x * 16;
  int fr = lane & 15, fc = (lane >> 4) << 3, qbase = (lane >> 4) << 2;

  // ---- QK: S = Q_h . KK_h^T ----
  f32x4 s2[2] = {};
  #pragma unroll
  for (int ks = 0; ks < 8; ++ks){
    size_t qoff = (size_t)(rowbase + fr)*512 + head*256 + ks*32 + fc;
    short8v ah = *(const short8v*)(Qh_g + qoff);
    short8v al = *(const short8v*)(Ql_g + qoff);
    #pragma unroll
    for (int nt = 0; nt < 2; ++nt){
      int key = nh*32 + nt*16 + fr;
      size_t ko = (((size_t)head)<<14) + key*256 + ks*32 + fc;
      short8v bh = *(const short8v*)(KKh + ko);
      short8v bl = *(const short8v*)(KKl + ko);
      f32x4 c = s2[nt];
      c = __builtin_amdgcn_mfma_f32_16x16x32_bf16(ah,bh,c,0,0,0);
      c = __builtin_amdgcn_mfma_f32_16x16x32_bf16(ah,bl,c,0,0,0);
      c = __builtin_amdgcn_mfma_f32_16x16x32_bf16(al,bh,c,0,0,0);
      s2[nt] = c;
    }
  }
  #pragma unroll
  for (int nt = 0; nt < 2; ++nt)
    #pragma unroll
    for (int j = 0; j < 4; ++j)
      Sc[head][qbase+j][nh*32 + nt*16 + fr] = s2[nt][j] * 0.044194173824159216f;
  __syncthreads();

  // ---- softmax over 50 keys (32 threads: head x row); keep/sum folded in ----
  if (t < 32){
    int h2 = t >> 4, r = t & 15;
    float mx = -3.4e38f;
    for (int ss = 0; ss < 50; ++ss) mx = fmaxf(mx, Sc[h2][r][ss]);
    float sum = 0.f;
    for (int ss = 0; ss < 50; ++ss) sum += expf(Sc[h2][r][ss] - mx);
    float keep = (mask[rowbase + r] == 0.f) ? 0.f : 1.f;
    float inv = keep / sum;
    for (int ss = 0; ss < 64; ++ss){
      float p = (ss < 50) ? expf(Sc[h2][r][ss] - mx) * inv : 0.f;
      unsigned short hh, ll_;
      splitc(p, hh, ll_);
      Pph[h2][r][ss] = hh; Ppl[h2][r][ss] = ll_;
    }
  }
  __syncthreads();

  // ---- AV: O = P . V ----
  f32x4 av[8] = {};
  #pragma unroll
  for (int ks = 0; ks < 2; ++ks){
    short8v ah = *(const short8v*)&Pph[head][fr][ks*32 + fc];
    short8v al = *(const short8v*)&Ppl[head][fr][ks*32 + fc];
    #pragma unroll
    for (int nt = 0; nt < 8; ++nt){
      int d = nh*128 + nt*16 + fr;
      size_t vo = (((size_t)head)<<14) + d*64 + ks*32 + fc;
      short8v bh = *(const short8v*)(VTh_s + vo);
      short8v bl = *(const short8v*)(VTl_s + vo);
      f32x4 c = av[nt];
      c = __builtin_amdgcn_mfma_f32_16x16x32_bf16(ah,bh,c,0,0,0);
      c = __builtin_amdgcn_mfma_f32_16x16x32_bf16(ah,bl,c,0,0,0);
      c = __builtin_amdgcn_mfma_f32_16x16x32_bf16(al,bh,c,0,0,0);
      av[nt] = c;
    }
  }
  #pragma unroll
  for (int nt = 0; nt < 8; ++nt)
    #pragma unroll
    for (int j = 0; j < 4; ++j){
      int row = rowbase + qbase + j;
      int d = nh*128 + nt*16 + fr;
      unsigned short hh, ll_;
      splitc(av[nt][j], hh, ll_);
      size_t o = (size_t)row*512 + head*256 + d;
      Oh[o] = hh; Ol[o] = ll_;
    }
}

// ---------------- pre-split MFMA GEMM, double-buffered LDS (64-row tiles) ----
// OUT: 0 = fp32 Y, 1 = planes, 2 = QKV mode, 3 = fp32 Y + planes.
// SWZ=1: 1D grid 512; col-blocks sharing an A-row co-locate on one XCD.
template<int EPI, bool AMASK, int OUT, int NF, int SWZ>
__global__ __launch_bounds__(256) void gemm_ps(
    const unsigned short* __restrict__ Ah, const unsigned short* __restrict__ Al,
    const unsigned short* __restrict__ Wh, const unsigned short* __restrict__ Wl,
    const float* __restrict__ bias, const float* __restrict__ res,
    const float* __restrict__ gamma, const float* __restrict__ rowmask,
    float* __restrict__ Y, unsigned short* __restrict__ Yh,
    unsigned short* __restrict__ Yl, unsigned short* __restrict__ VTh,
    unsigned short* __restrict__ VTl, int K, int O, float scale)
{
  __shared__ unsigned short AhS[2][64][40], AlS[2][64][40];
  __shared__ unsigned short BhS[2][NF*32][40], BlS[2][NF*32][40];
  int t = threadIdx.x;
  int row0, col0;
  if constexpr (SWZ){
    int id = blockIdx.x;          // 512 blocks; XCD = id & 7
    int slot = id >> 3;           // 0..63
    row0 = ((id & 7) + ((slot >> 3) << 3)) << 6;   // rows == xcd (mod 8)
    col0 = (slot & 7) << 6;                        // 8 col-blocks per row
  } else {
    row0 = blockIdx.y << 6;
    col0 = blockIdx.x << (NF==4 ? 7 : 6);
  }
  int lane = t & 63, wid = t >> 6;
  int wr = wid >> 1, wc = wid & 1;

  int sr = t >> 2, sc = (t & 3) << 3;
  const unsigned short* Ahg = Ah + (size_t)(row0 + sr)*K + sc;
  const unsigned short* Alg = Al + (size_t)(row0 + sr)*K + sc;
  const unsigned short* Bhg = Wh + (size_t)(col0 + sr)*K + sc;
  const unsigned short* Blg = Wl + (size_t)(col0 + sr)*K + sc;
  float am = 1.f;
  if (AMASK) am = rowmask[row0 + sr];

  f32x4 acc[2][NF] = {};
  int nsteps = K >> 5;
  short8v ah_, al_, bh0_, bl0_, bh1_, bl1_;
  ah_ = *(const short8v*)(Ahg);
  al_ = *(const short8v*)(Alg);
  bh0_ = *(const short8v*)(Bhg);
  bl0_ = *(const short8v*)(Blg);
  if constexpr (NF==4){
    bh1_ = *(const short8v*)(Bhg + (size_t)64*K);
    bl1_ = *(const short8v*)(Blg + (size_t)64*K);
  }
  if (AMASK && am == 0.f){ ah_ ^= ah_; al_ ^= al_; }
  *(short8v*)&AhS[0][sr][sc] = ah_;
  *(short8v*)&AlS[0][sr][sc] = al_;
  *(short8v*)&BhS[0][sr][sc] = bh0_;
  *(short8v*)&BlS[0][sr][sc] = bl0_;
  if constexpr (NF==4){
    *(short8v*)&BhS[0][sr+64][sc] = bh1_;
    *(short8v*)&BlS[0][sr+64][sc] = bl1_;
  }

  int st = 0;
  for (int s = 0; s < nsteps; ++s){
    if (s+1 < nsteps){
      int ko = (s+1) << 5;
      ah_ = *(const short8v*)(Ahg + ko);
      al_ = *(const short8v*)(Alg + ko);
      bh0_ = *(const short8v*)(Bhg + ko);
      bl0_ = *(const short8v*)(Blg + ko);
      if constexpr (NF==4){
        bh1_ = *(const short8v*)(Bhg + (size_t)64*K + ko);
        bl1_ = *(const short8v*)(Blg + (size_t)64*K + ko);
      }
      if (AMASK && am == 0.f){ ah_ ^= ah_; al_ ^= al_; }
    }
    __syncthreads();
    int fr = lane & 15, fc = (lane >> 4) << 3;
    short8v ahf[2], alf[2], bhf[NF], blf[NF];
    #pragma unroll
    for (int mt=0; mt<2; ++mt){
      int r = (wr<<5) + (mt<<4) + fr;
      ahf[mt] = *(const short8v*)&AhS[st][r][fc];
      alf[mt] = *(const short8v*)&AlS[st][r][fc];
    }
    #pragma unroll
    for (int nt=0; nt<NF; ++nt){
      int r = (NF==4 ? (wc<<6) : (wc<<5)) + (nt<<4) + fr;
      bhf[nt] = *(const short8v*)&BhS[st][r][fc];
      blf[nt] = *(const short8v*)&BlS[st][r][fc];
    }
    #pragma unroll
    for (int mt=0; mt<2; ++mt)
      #pragma unroll
      for (int nt=0; nt<NF; ++nt){
        f32x4 c = acc[mt][nt];
        c = __builtin_amdgcn_mfma_f32_16x16x32_bf16(ahf[mt], bhf[nt], c, 0,0,0);
        c = __builtin_amdgcn_mfma_f32_16x16x32_bf16(ahf[mt], blf[nt], c, 0,0,0);
        c = __builtin_amdgcn_mfma_f32_16x16x32_bf16(alf[mt], bhf[nt], c, 0,0,0);
        acc[mt][nt] = c;
      }
    if (s+1 < nsteps){
      int nb = st ^ 1;
      *(short8v*)&AhS[nb][sr][sc] = ah_;
      *(short8v*)&AlS[nb][sr][sc] = al_;
      *(short8v*)&BhS[nb][sr][sc] = bh0_;
      *(short8v*)&BlS[nb][sr][sc] = bl0_;
      if constexpr (NF==4){
        *(short8v*)&BhS[nb][sr+64][sc] = bh1_;
        *(short8v*)&BlS[nb][sr+64][sc] = bl1_;
      }
    }
    st ^= 1;
  }

  int rb = row0 + (wr<<5) + ((lane>>4)<<2);
  int cb = col0 + (NF==4 ? (wc<<6) : (wc<<5)) + (lane & 15);
  float bs[NF], gm[NF];
  int which = 0;
  if constexpr (EPI==EPI_QKV) which = blockIdx.x >> 2;
  #pragma unroll
  for (int nt=0; nt<NF; ++nt){
    int col = cb + (nt<<4);
    if constexpr (EPI==EPI_QKV){
      const float* bp = (which==0) ? bias : (which==1) ? res : gamma;
      bs[nt] = bp[col & 511];
    } else {
      bs[nt] = bias[col];
      if constexpr (EPI==EPI_RES_GAMMA_MASK) gm[nt] = gamma[col];
    }
  }
  float qscale = 1.f;
  if constexpr (EPI==EPI_QKV) qscale = (which==0) ? scale : 1.f;

  if constexpr (OUT==2){
    if (which == 2){
      #pragma unroll
      for (int mt=0; mt<2; ++mt){
        int row = rb + (mt<<4);
        int b = row >> 9, tok = row & 511;
        #pragma unroll
        for (int nt=0; nt<NF; ++nt){
          int dglob = cb + (nt<<4) - 1024;
          size_t vt = ((size_t)b*512 + dglob)*512 + tok;
          unsigned short h4[4], l4[4];
          #pragma unroll
          for (int j=0; j<4; ++j)
            splitc(acc[mt][nt][j] + bs[nt], h4[j], l4[j]);
          *(ushort4*)&VTh[vt] = make_ushort4(h4[0],h4[1],h4[2],h4[3]);
          *(ushort4*)&VTl[vt] = make_ushort4(l4[0],l4[1],l4[2],l4[3]);
        }
      }
      return;
    }
    #pragma unroll
    for (int mt=0; mt<2; ++mt)
      #pragma unroll
      for (int j=0; j<4; ++j){
        int row = rb + (mt<<4) + j;
        #pragma unroll
        for (int nt=0; nt<NF; ++nt){
          float v = (acc[mt][nt][j] + bs[nt]) * qscale;
          size_t oidx = (size_t)row*O + cb + (nt<<4);
          unsigned short h,l; splitc(v,h,l); Yh[oidx]=h; Yl[oidx]=l;
        }
      }
    return;
  }

  #pragma unroll
  for (int mt=0; mt<2; ++mt)
    #pragma unroll
    for (int j=0; j<4; ++j){
      int row = rb + (mt<<4) + j;
      float rm = 1.f;
      if constexpr (EPI==EPI_RELU_MASK || EPI==EPI_RES_MASK || EPI==EPI_RES_GAMMA_MASK)
        rm = rowmask[row];
      const float* rr = nullptr;
      if constexpr (EPI==EPI_RES || EPI==EPI_RES_MASK || EPI==EPI_RES_GAMMA_MASK)
        rr = res + (size_t)row*O + cb;
      #pragma unroll
      for (int nt=0; nt<NF; ++nt){
        float v = acc[mt][nt][j] + bs[nt];
        if constexpr (EPI==EPI_SCALE) v *= scale;
        else if constexpr (EPI==EPI_QKV) v *= qscale;
        else if constexpr (EPI==EPI_GELU) v = 0.5f*v*(1.f+erff(v*0.7071067811865475f));
        else if constexpr (EPI==EPI_RES) v = rr[nt<<4] + v;
        else if constexpr (EPI==EPI_RELU_MASK) v = fmaxf(v,0.f)*rm;
        else if constexpr (EPI==EPI_RES_MASK) v = rr[nt<<4] + v*rm;
        else if constexpr (EPI==EPI_RES_GAMMA_MASK) v = (rr[nt<<4] + gm[nt]*v)*rm;
        size_t oidx = (size_t)row*O + cb + (nt<<4);
        if constexpr (OUT==0) Y[oidx] = v;
        else if constexpr (OUT==3){
          Y[oidx] = v;
          unsigned short h,l; splitc(v,h,l); Yh[oidx]=h; Yl[oidx]=l;
        }
        else { unsigned short h,l; splitc(v,h,l); Yh[oidx]=h; Yl[oidx]=l; }
      }
    }
}

// ---------------- 128x128x32 MFMA GEMM (big-O GEMMs: pw1/ffn1/QKV) -----------
// SWZ=1: 1D grid 512 (32 rows x 16 cols); col-blocks of a row co-locate on one XCD.
template<int EPI, bool AMASK, int OUT, int SWZ>
__global__ __launch_bounds__(256) void gemm_big(
    const unsigned short* __restrict__ Ah, const unsigned short* __restrict__ Al,
    const unsigned short* __restrict__ Wh, const unsigned short* __restrict__ Wl,
    const float* __restrict__ bias, const float* __restrict__ res,
    const float* __restrict__ gamma, const float* __restrict__ rowmask,
    float* __restrict__ Y, unsigned short* __restrict__ Yh,
    unsigned short* __restrict__ Yl, unsigned short* __restrict__ VTh,
    unsigned short* __restrict__ VTl, int K, int O, float scale)
{
  __shared__ unsigned short AhS[128][40], AlS[128][40];
  __shared__ unsigned short BhS[128][40], BlS[128][40];
  int t = threadIdx.x;
  int row0, col0;
  if constexpr (SWZ){
    int id = blockIdx.x;          // 512 blocks; XCD = id & 7
    int slot = id >> 3;           // 0..63
    row0 = ((id & 7) + ((slot >> 4) << 3)) << 7;   // 32 rows: xcd + 8*(slot>>4)
    col0 = (slot & 15) << 7;                       // 16 col-blocks per row
  } else {
    row0 = blockIdx.y << 7;
    col0 = blockIdx.x << 7;
  }
  int lane = t & 63, wid = t >> 6;
  int wr = wid >> 1, wc = wid & 1;

  int sr = t >> 2, sc = (t & 3) << 3;
  const unsigned short* Ahg = Ah + (size_t)(row0 + sr)*K + sc;
  const unsigned short* Alg = Al + (size_t)(row0 + sr)*K + sc;
  const unsigned short* Bhg = Wh + (size_t)(col0 + sr)*K + sc;
  const unsigned short* Blg = Wl + (size_t)(col0 + sr)*K + sc;
  bool az0 = false, az1 = false;
  if (AMASK){ az0 = (rowmask[row0+sr] == 0.f); az1 = (rowmask[row0+sr+64] == 0.f); }

  f32x4 acc[4][4] = {};
  int nsteps = K >> 5;
  short8v a0h,a0l,a1h,a1l,b0h,b0l,b1h,b1l;
  a0h = *(const short8v*)(Ahg);
  a0l = *(const short8v*)(Alg);
  a1h = *(const short8v*)(Ahg + (size_t)64*K);
  a1l = *(const short8v*)(Alg + (size_t)64*K);
  b0h = *(const short8v*)(Bhg);
  b0l = *(const short8v*)(Blg);
  b1h = *(const short8v*)(Bhg + (size_t)64*K);
  b1l = *(const short8v*)(Blg + (size_t)64*K);

  for (int s = 0; s < nsteps; ++s){
    if (AMASK){
      if (az0){ a0h ^= a0h; a0l ^= a0l; }
      if (az1){ a1h ^= a1h; a1l ^= a1l; }
    }
    __syncthreads();
    *(short8v*)&AhS[sr][sc] = a0h;    *(short8v*)&AlS[sr][sc] = a0l;
    *(short8v*)&AhS[sr+64][sc] = a1h; *(short8v*)&AlS[sr+64][sc] = a1l;
    *(short8v*)&BhS[sr][sc] = b0h;    *(short8v*)&BlS[sr][sc] = b0l;
    *(short8v*)&BhS[sr+64][sc] = b1h; *(short8v*)&BlS[sr+64][sc] = b1l;
    __syncthreads();
    if (s+1 < nsteps){
      int ko = (s+1) << 5;
      a0h = *(const short8v*)(Ahg + ko);
      a0l = *(const short8v*)(Alg + ko);
      a1h = *(const short8v*)(Ahg + (size_t)64*K + ko);
      a1l = *(const short8v*)(Alg + (size_t)64*K + ko);
      b0h = *(const short8v*)(Bhg + ko);
      b0l = *(const short8v*)(Blg + ko);
      b1h = *(const short8v*)(Bhg + (size_t)64*K + ko);
      b1l = *(const short8v*)(Blg + (size_t)64*K + ko);
    }
    int fr = lane & 15, fc = (lane >> 4) << 3;
    short8v ahf[4], alf[4], bhf[4], blf[4];
    #pragma unroll
    for (int mt=0; mt<4; ++mt){
      int r = (wr<<6) + (mt<<4) + fr;
      ahf[mt] = *(const short8v*)&AhS[r][fc];
      alf[mt] = *(const short8v*)&AlS[r][fc];
    }
    #pragma unroll
    for (int nt=0; nt<4; ++nt){
      int r = (wc<<6) + (nt<<4) + fr;
      bhf[nt] = *(const short8v*)&BhS[r][fc];
      blf[nt] = *(const short8v*)&BlS[r][fc];
    }
    #pragma unroll
    for (int mt=0; mt<4; ++mt)
      #pragma unroll
      for (int nt=0; nt<4; ++nt){
        f32x4 c = acc[mt][nt];
        c = __builtin_amdgcn_mfma_f32_16x16x32_bf16(ahf[mt], bhf[nt], c, 0,0,0);
        c = __builtin_amdgcn_mfma_f32_16x16x32_bf16(ahf[mt], blf[nt], c, 0,0,0);
        c = __builtin_amdgcn_mfma_f32_16x16x32_bf16(alf[mt], bhf[nt], c, 0,0,0);
        acc[mt][nt] = c;
      }
  }

  int rb = row0 + (wr<<6) + ((lane>>4)<<2);
  int cb = col0 + (wc<<6) + (lane & 15);
  float bs[4];
  int which = 0;
  if constexpr (EPI==EPI_QKV) which = blockIdx.x >> 2;
  #pragma unroll
  for (int nt=0; nt<4; ++nt){
    int col = cb + (nt<<4);
    if constexpr (EPI==EPI_QKV){
      const float* bp = (which==0) ? bias : (which==1) ? res : gamma;
      bs[nt] = bp[col & 511];
    } else {
      bs[nt] = bias[col];
    }
  }
  float qscale = 1.f;
  if constexpr (EPI==EPI_QKV) qscale = (which==0) ? scale : 1.f;

  if constexpr (OUT==2){
    if (which == 2){
      #pragma unroll
      for (int mt=0; mt<4; ++mt){
        int row = rb + (mt<<4);
        int b = row >> 9, tok = row & 511;
        #pragma unroll
        for (int nt=0; nt<4; ++nt){
          int dglob = cb + (nt<<4) - 1024;
          size_t vt = ((size_t)b*512 + dglob)*512 + tok;
          unsigned short h4[4], l4[4];
          #pragma unroll
          for (int j=0; j<4; ++j)
            splitc(acc[mt][nt][j] + bs[nt], h4[j], l4[j]);
          *(ushort4*)&VTh[vt] = make_ushort4(h4[0],h4[1],h4[2],h4[3]);
          *(ushort4*)&VTl[vt] = make_ushort4(l4[0],l4[1],l4[2],l4[3]);
        }
      }
      return;
    }
    #pragma unroll
    for (int mt=0; mt<4; ++mt)
      #pragma unroll
      for (int j=0; j<4; ++j){
        int row = rb + (mt<<4) + j;
        #pragma unroll
        for (int nt=0; nt<4; ++nt){
          float v = (acc[mt][nt][j] + bs[nt]) * qscale;
          size_t oidx = (size_t)row*O + cb + (nt<<4);
          unsigned short h,l; splitc(v,h,l); Yh[oidx]=h; Yl[oidx]=l;
        }
      }
    return;
  }

  #pragma unroll
  for (int mt=0; mt<4; ++mt)
    #pragma unroll
    for (int j=0; j<4; ++j){
      int row = rb + (mt<<4) + j;
      float rm = 1.f;
      if constexpr (EPI==EPI_RELU_MASK) rm = rowmask[row];
      #pragma unroll
      for (int nt=0; nt<4; ++nt){
        float v = acc[mt][nt][j] + bs[nt];
        if constexpr (EPI==EPI_GELU) v = 0.5f*v*(1.f+erff(v*0.7071067811865475f));
        else if constexpr (EPI==EPI_RELU_MASK) v = fmaxf(v,0.f)*rm;
        size_t oidx = (size_t)row*O + cb + (nt<<4);
        if constexpr (OUT==0) Y[oidx] = v;
        else { unsigned short h,l; splitc(v,h,l); Yh[oidx]=h; Yl[oidx]=l; }
      }
    }
}

// ---------------- MFMA windowed-rel attention v4: 2 Q-tiles per block --------
__global__ __launch_bounds__(256) void attn_mf(
    const unsigned short* __restrict__ Ph_g, const unsigned short* __restrict__ Pl_g,
    const unsigned short* __restrict__ VTh_g, const unsigned short* __restrict__ VTl_g,
    const float* __restrict__ relk, const float* __restrict__ relv,
    const float* __restrict__ mask, unsigned short* __restrict__ Oh,
    unsigned short* __restrict__ Ol)
{
  __shared__ float ms_[512];
  __shared__ float rv[9][64];
  __shared__ float qrel[32][16];
  __shared__ float red1[4][32];
  __shared__ float red2[4][32];
  __shared__ __align__(16) unsigned short Spool[32*520];
  unsigned short (*Qh)[72]  = (unsigned short(*)[72])(Spool);          // [32][72]
  unsigned short (*Ql)[72]  = (unsigned short(*)[72])(Spool + 2304);   // [32][72]
  unsigned short (*Rkh)[72] = (unsigned short(*)[72])(Spool + 4608);   // [16][72]
  unsigned short (*Rkl)[72] = (unsigned short(*)[72])(Spool + 5760);   // [16][72]
  unsigned short (*Sp)[520] = (unsigned short(*)[520])(Spool);         // [32][520]

  int id = blockIdx.x;
  int xcd = id & 7, kk = id >> 3;
  int bh_ = xcd*8 + (kk >> 4);
  int qt = kk & 15;
  int h = bh_ & 7, b_ = bh_ >> 3;
  int t = threadIdx.x;
  int l0 = qt * 32;
  const size_t rowoff = (size_t)b_ * 512;
  int lane = t & 63, w = t >> 6;

  ms_[t] = mask[rowoff + t]; ms_[t+256] = mask[rowoff + t + 256];
  for (int i = t; i < 576; i += 256) ((float*)rv)[i] = relv[i];
  {
    int r = t >> 4, c = (t & 15) << 2;
    float4 v;
    if (r < 9) v = *(const float4*)&relk[r*64 + c];
    else { v.x=0.f; v.y=0.f; v.z=0.f; v.w=0.f; }
    split4(v, &Rkh[r][c], &Rkl[r][c]);
  }
  for (int i = t; i < 512; i += 256){
    int r = (i & 255) >> 3, c = (i & 7) << 3;
    size_t g = (rowoff + l0 + r)*QKVS + h*64 + c;
    if (i < 256) *(short8v*)&Qh[r][c] = *(const short8v*)&Ph_g[g];
    else         *(short8v*)&Ql[r][c] = *(const short8v*)&Pl_g[g];
  }
  __syncthreads();

  int fr = lane & 15, fc = (lane >> 4) << 3;
  int qbase = (lane>>4) << 2;
  short8v a0h0 = *(const short8v*)&Qh[fr][fc];
  short8v a0h1 = *(const short8v*)&Qh[fr][32+fc];
  short8v a0l0 = *(const short8v*)&Ql[fr][fc];
  short8v a0l1 = *(const short8v*)&Ql[fr][32+fc];
  short8v a1h0 = *(const short8v*)&Qh[16+fr][fc];
  short8v a1h1 = *(const short8v*)&Qh[16+fr][32+fc];
  short8v a1l0 = *(const short8v*)&Ql[16+fr][fc];
  short8v a1l1 = *(const short8v*)&Ql[16+fr][32+fc];

  if (w < 2){
    short8v rh0 = *(const short8v*)&Rkh[fr][fc];
    short8v rh1 = *(const short8v*)&Rkh[fr][32+fc];
    short8v rl0 = *(const short8v*)&Rkl[fr][fc];
    short8v rl1 = *(const short8v*)&Rkl[fr][32+fc];
    short8v qa0 = (w==0) ? a0h0 : a1h0;
    short8v qa1 = (w==0) ? a0h1 : a1h1;
    short8v qb0 = (w==0) ? a0l0 : a1l0;
    short8v qb1 = (w==0) ? a0l1 : a1l1;
    f32x4 c4 = {};
    c4 = __builtin_amdgcn_mfma_f32_16x16x32_bf16(qa0,rh0,c4,0,0,0);
    c4 = __builtin_amdgcn_mfma_f32_16x16x32_bf16(qa1,rh1,c4,0,0,0);
    c4 = __builtin_amdgcn_mfma_f32_16x16x32_bf16(qa0,rl0,c4,0,0,0);
    c4 = __builtin_amdgcn_mfma_f32_16x16x32_bf16(qa1,rl1,c4,0,0,0);
    c4 = __builtin_amdgcn_mfma_f32_16x16x32_bf16(qb0,rh0,c4,0,0,0);
    c4 = __builtin_amdgcn_mfma_f32_16x16x32_bf16(qb1,rh1,c4,0,0,0);
    #pragma unroll
    for (int j = 0; j < 4; ++j) qrel[w*16 + qbase + j][fr] = c4[j];
  }
  __syncthreads();   // after this: Q/Rk LDS dead, P region live

  f32x4 sreg0[8], sreg1[8];
  #pragma unroll
  for (int tt = 0; tt < 8; ++tt){
    int br = tt*64 + w*16 + fr;
    const unsigned short* krh = Ph_g + (rowoff + br)*QKVS + 512 + h*64;
    const unsigned short* krl = Pl_g + (rowoff + br)*QKVS + 512 + h*64;
    short8v bh0 = *(const short8v*)(krh + fc);
    short8v bh1 = *(const short8v*)(krh + 32 + fc);
    short8v bl0 = *(const short8v*)(krl + fc);
    short8v bl1 = *(const short8v*)(krl + 32 + fc);
    f32x4 c0 = {}, c1 = {};
    c0 = __builtin_amdgcn_mfma_f32_16x16x32_bf16(a0h0,bh0,c0,0,0,0);
    c1 = __builtin_amdgcn_mfma_f32_16x16x32_bf16(a1h0,bh0,c1,0,0,0);
    c0 = __builtin_amdgcn_mfma_f32_16x16x32_bf16(a0h1,bh1,c0,0,0,0);
    c1 = __builtin_amdgcn_mfma_f32_16x16x32_bf16(a1h1,bh1,c1,0,0,0);
    c0 = __builtin_amdgcn_mfma_f32_16x16x32_bf16(a0h0,bl0,c0,0,0,0);
    c1 = __builtin_amdgcn_mfma_f32_16x16x32_bf16(a1h0,bl0,c1,0,0,0);
    c0 = __builtin_amdgcn_mfma_f32_16x16x32_bf16(a0h1,bl1,c0,0,0,0);
    c1 = __builtin_amdgcn_mfma_f32_16x16x32_bf16(a1h1,bl1,c1,0,0,0);
    c0 = __builtin_amdgcn_mfma_f32_16x16x32_bf16(a0l0,bh0,c0,0,0,0);
    c1 = __builtin_amdgcn_mfma_f32_16x16x32_bf16(a1l0,bh0,c1,0,0,0);
    c0 = __builtin_amdgcn_mfma_f32_16x16x32_bf16(a0l1,bh1,c0,0,0,0);
    c1 = __builtin_amdgcn_mfma_f32_16x16x32_bf16(a1l1,bh1,c1,0,0,0);
    int m = tt*64 + w*16 + fr;
    float mm_ = ms_[m];
    #pragma unroll
    for (int j = 0; j < 4; ++j){
      int q = qbase + j;
      {
        int l = l0 + q;
        float s = c0[j];
        int dlt = m - l + 4;
        if (dlt >= 0 && dlt <= 8) s += qrel[q][dlt];
        if (ms_[l] * mm_ == 0.f) s = -10000.f;
        c0[j] = s;
      }
      {
        int l = l0 + 16 + q;
        float s = c1[j];
        int dlt = m - l + 4;
        if (dlt >= 0 && dlt <= 8) s += qrel[16 + q][dlt];
        if (ms_[l] * mm_ == 0.f) s = -10000.f;
        c1[j] = s;
      }
    }
    sreg0[tt] = c0; sreg1[tt] = c1;
  }

  float mx0[4], mx1[4], sm0[4], sm1[4], inv0[4], inv1[4];
  #pragma unroll
  for (int j = 0; j < 4; ++j){
    float v0 = sreg0[0][j], v1 = sreg1[0][j];
    #pragma unroll
    for (int tt = 1; tt < 8; ++tt){
      v0 = fmaxf(v0, sreg0[tt][j]);
      v1 = fmaxf(v1, sreg1[tt][j]);
    }
    #pragma unroll
    for (int o = 8; o >= 1; o >>= 1){
      v0 = fmaxf(v0, __shfl_xor(v0, o));
      v1 = fmaxf(v1, __shfl_xor(v1, o));
    }
    mx0[j] = v0; mx1[j] = v1;
  }
  if (fr == 0){
    #pragma unroll
    for (int j = 0; j < 4; ++j){
      red1[w][qbase + j] = mx0[j];
      red1[w][16 + qbase + j] = mx1[j];
    }
  }
  __syncthreads();
  #pragma unroll
  for (int j = 0; j < 4; ++j){
    int q = qbase + j;
    mx0[j] = fmaxf(fmaxf(red1[0][q], red1[1][q]), fmaxf(red1[2][q], red1[3][q]));
    mx1[j] = fmaxf(fmaxf(red1[0][16+q], red1[1][16+q]), fmaxf(red1[2][16+q], red1[3][16+q]));
  }
  #pragma unroll
  for (int j = 0; j < 4; ++j){ sm0[j] = 0.f; sm1[j] = 0.f; }
  #pragma unroll
  for (int tt = 0; tt < 8; ++tt){
    f32x4 c0 = sreg0[tt], c1 = sreg1[tt];
    #pragma unroll
    for (int j = 0; j < 4; ++j){
      float e0 = expf(c0[j] - mx0[j]);
      float e1 = expf(c1[j] - mx1[j]);
      c0[j] = e0; c1[j] = e1;
      sm0[j] += e0; sm1[j] += e1;
    }
    sreg0[tt] = c0; sreg1[tt] = c1;
  }
  #pragma unroll
  for (int j = 0; j < 4; ++j){
    float v0 = sm0[j], v1 = sm1[j];
    #pragma unroll
    for (int o = 8; o >= 1; o >>= 1){
      v0 += __shfl_xor(v0, o);
      v1 += __shfl_xor(v1, o);
    }
    sm0[j] = v0; sm1[j] = v1;
  }
  if (fr == 0){
    #pragma unroll
    for (int j = 0; j < 4; ++j){
      red2[w][qbase + j] = sm0[j];
      red2[w][16 + qbase + j] = sm1[j];
    }
  }
  #pragma unroll
  for (int tt = 0; tt < 8; ++tt){
    int m = tt*64 + w*16 + fr;
    #pragma unroll
    for (int j = 0; j < 4; ++j){
      Sp[qbase + j][m]      = f2bf_rne(sreg0[tt][j]);
      Sp[16 + qbase + j][m] = f2bf_rne(sreg1[tt][j]);
    }
  }
  __syncthreads();
  #pragma unroll
  for (int j = 0; j < 4; ++j){
    int q = qbase + j;
    inv0[j] = 1.f / (red2[0][q] + red2[1][q] + red2[2][q] + red2[3][q]);
    inv1[j] = 1.f / (red2[0][16+q] + red2[1][16+q] + red2[2][16+q] + red2[3][16+q]);
  }

  f32x4 oacc0 = {}, oacc1 = {};
  const unsigned short* vrh = VTh_g + ((size_t)b_*512 + h*64 + w*16 + fr)*512;
  const unsigned short* vrl = VTl_g + ((size_t)b_*512 + h*64 + w*16 + fr)*512;
  #pragma unroll
  for (int tt = 0; tt < 8; ++tt){
    #pragma unroll
    for (int ks = 0; ks < 2; ++ks){
      int moff = tt*64 + ks*32 + fc;
      short8v ap0 = *(const short8v*)&Sp[fr][moff];
      short8v ap1 = *(const short8v*)&Sp[16+fr][moff];
      short8v bh = *(const short8v*)(vrh + moff);
      short8v bl = *(const short8v*)(vrl + moff);
      oacc0 = __builtin_amdgcn_mfma_f32_16x16x32_bf16(ap0,bh,oacc0,0,0,0);
      oacc1 = __builtin_amdgcn_mfma_f32_16x16x32_bf16(ap1,bh,oacc1,0,0,0);
      oacc0 = __builtin_amdgcn_mfma_f32_16x16x32_bf16(ap0,bl,oacc0,0,0,0);
      oacc1 = __builtin_amdgcn_mfma_f32_16x16x32_bf16(ap1,bl,oacc1,0,0,0);
    }
  }
  {
    int d = w*16 + fr;
    #pragma unroll
    for (int j = 0; j < 4; ++j){
      {
        int q = qbase + j;
        int l = l0 + q;
        float val = oacc0[j];
        #pragma unroll
        for (int dlt = 0; dlt < 9; ++dlt){
          int m = l + dlt - 4;
          if (m >= 0 && m < 512){
            float e = bf2f(Sp[q][m]);
            val += e * rv[dlt][d];
          }
        }
        val *= inv0[j];
        unsigned short hh, ll_; splitc(val, hh, ll_);
        size_t oidx = ((rowoff + l) << 9) + h*64 + d;
        Oh[oidx] = hh; Ol[oidx] = ll_;
      }
      {
        int q = 16 + qbase + j;
        int l = l0 + q;
        float val = oacc1[j];
        #pragma unroll
        for (int dlt = 0; dlt < 9; ++dlt){
          int m = l + dlt - 4;
          if (m >= 0 && m < 512){
            float e = bf2f(Sp[q][m]);
            val += e * rv[dlt][d];
          }
        }
        val *= inv1[j];
        unsigned short hh, ll_; splitc(val, hh, ll_);
        size_t oidx = ((rowoff + l) << 9) + h*64 + d;
        Oh[oidx] = hh; Ol[oidx] = ll_;
      }
    }
  }
}

// ---------------- final transpose ----------------
__global__ __launch_bounds__(256) void transpose_out_k(const float* __restrict__ xn,
    const float* __restrict__ mask, float* __restrict__ out){
  __shared__ float tile[32][33];
  int b_ = blockIdx.z; int c0 = blockIdx.x*32; int l0 = blockIdx.y*32;
  int tx = threadIdx.x & 31, ty = threadIdx.x >> 5;
  #pragma unroll
  for (int r=0;r<4;r++){
    int l = l0 + ty + r*8;
    tile[ty + r*8][tx] = xn[(((size_t)(b_*512 + l))<<9) + c0 + tx];
  }
  __syncthreads();
  float mm = mask[b_*512 + l0 + tx];
  #pragma unroll
  for (int r=0;r<4;r++){
    int c = c0 + ty + r*8;
    out[(((size_t)(b_*512 + c))<<9) + l0 + tx] = tile[tx][ty + r*8] * mm;
  }
}

extern "C" void kernel_launch(void* const* d_in, const int* in_sizes, int n_in,
                              void* d_out, int out_size, void* d_ws, size_t ws_size,
                              hipStream_t stream) {
  const int*   tokens   = (const int*)  d_in[0];
  const float* style_v  = (const float*)d_in[1];
  const float* mask     = (const float*)d_in[2];
  const float* embed_w  = (const float*)d_in[3];
  const float* cw_dw_w  = (const float*)d_in[4];
  const float* cw_dw_b  = (const float*)d_in[5];
  const float* cw_ln_g  = (const float*)d_in[6];
  const float* cw_ln_b  = (const float*)d_in[7];
  const float* cw_pw1_w = (const float*)d_in[8];
  const float* cw_pw1_b = (const float*)d_in[9];
  const float* cw_pw2_w = (const float*)d_in[10];
  const float* cw_pw2_b = (const float*)d_in[11];
  const float* cw_gamma = (const float*)d_in[12];
  const float* aq_w = (const float*)d_in[13];
  const float* aq_b = (const float*)d_in[14];
  const float* ak_w = (const float*)d_in[15];
  const float* ak_b = (const float*)d_in[16];
  const float* av_w = (const float*)d_in[17];
  const float* av_b = (const float*)d_in[18];
  const float* ao_w = (const float*)d_in[19];
  const float* ao_b = (const float*)d_in[20];
  const float* rel_k = (const float*)d_in[21];
  const float* rel_v = (const float*)d_in[22];
  const float* ln1_g = (const float*)d_in[23];
  const float* ln1_b = (const float*)d_in[24];
  const float* ln2_g = (const float*)d_in[25];
  const float* ln2_b = (const float*)d_in[26];
  const float* ffn_w1 = (const float*)d_in[27];
  const float* ffn_b1 = (const float*)d_in[28];
  const float* ffn_w2 = (const float*)d_in[29];
  const float* ffn_b2 = (const float*)d_in[30];
  const float* style_key = (const float*)d_in[31];
  const float* sq_w = (const float*)d_in[32];
  const float* sq_b = (const float*)d_in[33];
  const float* sk_w = (const float*)d_in[34];
  const float* sk_b = (const float*)d_in[35];
  const float* sv_w = (const float*)d_in[36];
  const float* sv_b = (const float*)d_in[37];
  const float* so_w = (const float*)d_in[38];
  const float* so_b = (const float*)d_in[39];
  const float* sn_g = (const float*)d_in[40];
  const float* sn_b = (const float*)d_in[41];

  const int N = NROWS;
  char* cur = (char*)d_ws;
  auto nextF = [&](size_t n)->float*{ float* p=(float*)cur; cur += n*sizeof(float); return p; };
  auto nextU = [&](size_t n)->unsigned short*{ unsigned short* p=(unsigned short*)cur; cur += n*2; return p; };

  float* X   = nextF((size_t)N*512);
  float* T   = nextF((size_t)N*512);
  float* Qb  = nextF((size_t)N*512);
  float* Vb  = nextF((size_t)N*512);
  unsigned short* Xh = nextU((size_t)N*512);
  unsigned short* Xl = nextU((size_t)N*512);
  unsigned short* Th = nextU((size_t)N*512);
  unsigned short* Tl = nextU((size_t)N*512);
  unsigned short* Hbh = nextU((size_t)N*2048);
  unsigned short* Hbl = nextU((size_t)N*2048);
  unsigned short* QKVh = nextU((size_t)N*QKVS);
  unsigned short* QKVl = nextU((size_t)N*QKVS);
  unsigned short* VTh = nextU((size_t)8*512*512);
  unsigned short* VTl = nextU((size_t)8*512*512);
  // weight planes
  unsigned short* pw1h = nextU(4194304); unsigned short* pw1l = nextU(4194304);
  unsigned short* pw2h = nextU(4194304); unsigned short* pw2l = nextU(4194304);
  unsigned short* qkvh = nextU((size_t)6*QKVS*512); unsigned short* qkvl = nextU((size_t)6*QKVS*512);
  unsigned short* aoh  = nextU(1572864); unsigned short* aol  = nextU(1572864);
  unsigned short* f1h  = nextU(6291456); unsigned short* f1l  = nextU(6291456);
  unsigned short* f2h  = nextU(6291456); unsigned short* f2l  = nextU(6291456);
  unsigned short* sqh  = nextU(524288);  unsigned short* sql  = nextU(524288);
  unsigned short* soh  = nextU(524288);  unsigned short* sol  = nextU(524288);
  // style planes: KKp [2 layers][2 heads][64][256]; VTp [2][2][256][64]
  unsigned short* KKsh = nextU(65536); unsigned short* KKsl = nextU(65536);
  unsigned short* VTsh = nextU(65536); unsigned short* VTsl = nextU(65536);

  // ---- weight prep (single merged launch) ----
  split_all<<<dim3(512,8),256,0,stream>>>(cw_pw1_w, cw_pw2_w, ao_w, ffn_w1,
      ffn_w2, sq_w, so_w, aq_w, ak_w, av_w,
      pw1h, pw1l, pw2h, pw2l, aoh, aol, f1h, f1l, f2h, f2l,
      sqh, sql, soh, sol, qkvh, qkvl);

  dim3 gbigqkv(12,32);

  embed_k<<<4096,128,0,stream>>>(tokens, embed_w, mask, X);

  // ---- ConvNeXt blocks (dwconv+LN fused; all GEMMs XCD-swizzled) ----
  for (int i=0;i<4;i++){
    dwln_k<<<4096,128,0,stream>>>(X, cw_dw_w + (size_t)i*512*5, cw_dw_b + i*512,
        mask, cw_ln_g+i*512, cw_ln_b+i*512, Th, Tl);
    gemm_big<EPI_GELU,false,1,1><<<512,256,0,stream>>>(Th, Tl,
        pw1h + (size_t)i*1048576, pw1l + (size_t)i*1048576,
        cw_pw1_b+i*2048, nullptr, nullptr, nullptr, nullptr, Hbh, Hbl,
        nullptr, nullptr, 512, 2048, 0.f);
    if (i < 3)
      gemm_ps<EPI_RES_GAMMA_MASK,false,0,2,1><<<512,256,0,stream>>>(Hbh, Hbl,
          pw2h + (size_t)i*1048576, pw2l + (size_t)i*1048576,
          cw_pw2_b+i*512, X, cw_gamma+i*512, mask, X, nullptr, nullptr,
          nullptr, nullptr, 2048, 512, 0.f);
    else
      gemm_ps<EPI_RES_GAMMA_MASK,false,3,2,1><<<512,256,0,stream>>>(Hbh, Hbl,
          pw2h + (size_t)i*1048576, pw2l + (size_t)i*1048576,
          cw_pw2_b+i*512, X, cw_gamma+i*512, mask, X, Xh, Xl,
          nullptr, nullptr, 2048, 512, 0.f);
  }

  // ---- Attention layers ----
  for (int i=0;i<6;i++){
    gemm_big<EPI_QKV,false,2,0><<<gbigqkv,256,0,stream>>>(Xh, Xl,
        qkvh + (size_t)i*QKVS*512, qkvl + (size_t)i*QKVS*512,
        aq_b+i*512, ak_b+i*512, av_b+i*512, nullptr, nullptr, QKVh, QKVl,
        VTh, VTl, 512, QKVS, 0.125f);
    attn_mf<<<1024,256,0,stream>>>(QKVh, QKVl, VTh, VTl,
        rel_k + (size_t)i*9*64, rel_v + (size_t)i*9*64, mask, Th, Tl);
    gemm_ps<EPI_RES,false,0,2,1><<<512,256,0,stream>>>(Th, Tl,
        aoh + (size_t)i*262144, aol + (size_t)i*262144,
        ao_b+i*512, X, nullptr, nullptr, Qb, nullptr, nullptr,
        nullptr, nullptr, 512, 512, 0.f);
    ln_rows<true,false><<<1024,256,0,stream>>>(Qb, ln1_g+i*512, ln1_b+i*512,
        nullptr, X, Xh, Xl, N);
    gemm_big<EPI_RELU_MASK,true,1,1><<<512,256,0,stream>>>(Xh, Xl,
        f1h + (size_t)i*1048576, f1l + (size_t)i*1048576,
        ffn_b1+i*2048, nullptr, nullptr, mask, nullptr, Hbh, Hbl,
        nullptr, nullptr, 512, 2048, 0.f);
    gemm_ps<EPI_RES_MASK,false,0,2,1><<<512,256,0,stream>>>(Hbh, Hbl,
        f2h + (size_t)i*1048576, f2l + (size_t)i*1048576,
        ffn_b2+i*512, X, nullptr, mask, Qb, nullptr, nullptr,
        nullptr, nullptr, 2048, 512, 0.f);
    if (i < 5)
      ln_rows<true,false><<<1024,256,0,stream>>>(Qb, ln2_g+i*512, ln2_b+i*512,
          nullptr, X, Xh, Xl, N);
    else
      ln_rows<true,true><<<1024,256,0,stream>>>(Qb, ln2_g+i*512, ln2_b+i*512,
          mask, X, Xh, Xl, N);
  }

  // ---- Style attention (MFMA path) ----
  style_prep<<<dim3(8,4),256,0,stream>>>(style_key, style_v, sk_w, sk_b,
      sv_w, sv_b, KKsh, KKsl, VTsh, VTsl);

  // layer 0: xin = masked X -> Q planes -> style_mf -> so gemm (x1 planes)
  gemm_ps<EPI_BIAS,false,1,2,1><<<512,256,0,stream>>>(Xh, Xl, sqh, sql,
      sq_b, nullptr, nullptr, nullptr, nullptr, QKVh, QKVl,
      nullptr, nullptr, 512, 512, 0.f);
  style_mf<<<256,256,0,stream>>>(QKVh, QKVl, KKsh, KKsl, VTsh, VTsl,
      mask, Th, Tl);
  gemm_ps<EPI_RES_MASK,false,1,2,1><<<512,256,0,stream>>>(Th, Tl, soh, sol,
      so_b, X, nullptr, mask, nullptr, Hbh, Hbl,
      nullptr, nullptr, 512, 512, 0.f);   // x1 planes
  // layer 1: xin = x1 (planes); residual xt = X
  gemm_ps<EPI_BIAS,false,1,2,1><<<512,256,0,stream>>>(Hbh, Hbl, sqh+262144, sql+262144,
      sq_b+512, nullptr, nullptr, nullptr, nullptr, QKVh, QKVl,
      nullptr, nullptr, 512, 512, 0.f);
  style_mf<<<256,256,0,stream>>>(QKVh, QKVl, KKsh+32768, KKsl+32768,
      VTsh+32768, VTsl+32768, mask, Th, Tl);
  gemm_ps<EPI_RES_MASK,false,0,2,1><<<512,256,0,stream>>>(Th, Tl, soh+262144, sol+262144,
      so_b+512, X, nullptr, mask, Vb, nullptr, nullptr,
      nullptr, nullptr, 512, 512, 0.f);  // x2

  ln_rows<false,false><<<1024,256,0,stream>>>(Vb, sn_g, sn_b, nullptr,
      Qb, nullptr, nullptr, N);
  transpose_out_k<<<dim3(16,16,8),256,0,stream>>>(Qb, mask, (float*)d_out);
}

// Round 30
// 1617.267 us; speedup vs baseline: 1.1700x; 1.0114x over previous
//
#include <hip/hip_runtime.h>
#include <cstdint>

#define Bb 8
#define Ll 512
#define Cc 512
#define Hh 8
#define HD 64
#define Ff 2048
#define Ss 50
#define NROWS 4096   // B*L
#define QKVS 1536

typedef __attribute__((ext_vector_type(8))) short short8v;  // 8 bf16 (4 VGPR)
typedef __attribute__((ext_vector_type(4))) float f32x4;

__device__ __forceinline__ float wave_sum(float v){
  #pragma unroll
  for (int o=32;o>=1;o>>=1) v += __shfl_xor(v,o);
  return v;
}
__device__ __forceinline__ float bf2f(unsigned short u){
  return __uint_as_float(((unsigned)u) << 16);
}

// cheap split: hi = trunc-bf16(a); lo = trunc-bf16(a - hi). err ~ 2^-16 |a|
__device__ __forceinline__ void splitc(float a, unsigned short& hi, unsigned short& lo){
  unsigned u = __float_as_uint(a);
  hi = (unsigned short)(u >> 16);
  float l = a - __uint_as_float(u & 0xFFFF0000u);
  lo = (unsigned short)(__float_as_uint(l) >> 16);
}
__device__ __forceinline__ unsigned short f2bf_rne(float a){
  unsigned u = __float_as_uint(a);
  unsigned r = u + 0x7FFFu + ((u >> 16) & 1u);
  return (unsigned short)(r >> 16);
}
__device__ __forceinline__ void split4(float4 v, unsigned short* hi, unsigned short* lo){
  unsigned short h0,h1,h2,h3,l0,l1,l2,l3;
  splitc(v.x,h0,l0); splitc(v.y,h1,l1); splitc(v.z,h2,l2); splitc(v.w,h3,l3);
  *(ushort4*)hi = make_ushort4(h0,h1,h2,h3);
  *(ushort4*)lo = make_ushort4(l0,l1,l2,l3);
}

// ---------------- merged weight split: 8 segments in one launch --------------
__global__ __launch_bounds__(256) void split_all(
    const float* __restrict__ pw1w, const float* __restrict__ pw2w,
    const float* __restrict__ aow,  const float* __restrict__ f1w,
    const float* __restrict__ f2w,  const float* __restrict__ sqw,
    const float* __restrict__ sow,
    const float* __restrict__ aqw, const float* __restrict__ akw,
    const float* __restrict__ avw,
    unsigned short* __restrict__ pw1h, unsigned short* __restrict__ pw1l,
    unsigned short* __restrict__ pw2h, unsigned short* __restrict__ pw2l,
    unsigned short* __restrict__ aoh,  unsigned short* __restrict__ aol,
    unsigned short* __restrict__ f1h,  unsigned short* __restrict__ f1l,
    unsigned short* __restrict__ f2h,  unsigned short* __restrict__ f2l,
    unsigned short* __restrict__ sqh,  unsigned short* __restrict__ sql,
    unsigned short* __restrict__ soh,  unsigned short* __restrict__ sol,
    unsigned short* __restrict__ qkvh, unsigned short* __restrict__ qkvl)
{
  int seg = blockIdx.y;
  if (seg == 7){
    const int n4 = 6*QKVS*512/4;
    for (int i = blockIdx.x*256 + threadIdx.x; i < n4; i += gridDim.x*256){
      int e = i << 2;
      int layer = e / 786432;
      int r = e - layer*786432;
      int which = r >> 18;
      int off = r & 262143;
      const float* s = (which==0) ? aqw : (which==1) ? akw : avw;
      float4 vv = *(const float4*)(s + (size_t)layer*262144 + off);
      split4(vv, (unsigned short*)((ushort4*)qkvh + i),
                 (unsigned short*)((ushort4*)qkvl + i));
    }
    return;
  }
  const float* src; unsigned short* hi; unsigned short* lo; int n4;
  switch(seg){
    case 0: src=pw1w; hi=pw1h; lo=pw1l; n4=1048576; break;
    case 1: src=pw2w; hi=pw2h; lo=pw2l; n4=1048576; break;
    case 2: src=aow;  hi=aoh;  lo=aol;  n4=393216;  break;
    case 3: src=f1w;  hi=f1h;  lo=f1l;  n4=1572864; break;
    case 4: src=f2w;  hi=f2h;  lo=f2l;  n4=1572864; break;
    case 5: src=sqw;  hi=sqh;  lo=sql;  n4=131072;  break;
    default: src=sow; hi=soh;  lo=sol;  n4=131072;  break;
  }
  for (int i = blockIdx.x*256 + threadIdx.x; i < n4; i += gridDim.x*256){
    float4 v = ((const float4*)src)[i];
    split4(v, (unsigned short*)((ushort4*)hi + i), (unsigned short*)((ushort4*)lo + i));
  }
}

// ---------------- embed gather (mask fused) ----------------
__global__ __launch_bounds__(128) void embed_k(const int* __restrict__ tok,
    const float* __restrict__ emb, const float* __restrict__ mask,
    float* __restrict__ x){
  int n = blockIdx.x;
  int t = tok[n];
  float m = mask[n];
  float4 v = ((const float4*)(emb + ((size_t)t<<9)))[threadIdx.x];
  v.x*=m; v.y*=m; v.z*=m; v.w*=m;
  ((float4*)(x + ((size_t)n<<9)))[threadIdx.x] = v;
}

// ---------------- FUSED depthwise conv K=5 + bias + mask + LayerNorm + split --
__global__ __launch_bounds__(128) void dwln_k(const float* __restrict__ x,
    const float* __restrict__ w, const float* __restrict__ bias,
    const float* __restrict__ mask, const float* __restrict__ g,
    const float* __restrict__ bt, unsigned short* __restrict__ yh,
    unsigned short* __restrict__ yl){
  __shared__ float ws1[2], ws2[2];
  int n = blockIdx.x; int b_ = n >> 9, l = n & 511;
  int c0 = threadIdx.x * 4;
  float a0=bias[c0], a1=bias[c0+1], a2=bias[c0+2], a3=bias[c0+3];
  #pragma unroll
  for (int k=0;k<5;k++){
    int ls = l + k - 2; ls = ls < 0 ? 0 : (ls > 511 ? 511 : ls);
    const float4 xv = *(const float4*)&x[((size_t)(b_*512 + ls) << 9) + c0];
    a0 += w[(c0+0)*5+k]*xv.x;
    a1 += w[(c0+1)*5+k]*xv.y;
    a2 += w[(c0+2)*5+k]*xv.z;
    a3 += w[(c0+3)*5+k]*xv.w;
  }
  float mm = mask[n];
  a0*=mm; a1*=mm; a2*=mm; a3*=mm;
  int wv = threadIdx.x >> 6, ln_ = threadIdx.x & 63;
  float s = wave_sum(a0+a1+a2+a3);
  if (ln_ == 0) ws1[wv] = s;
  __syncthreads();
  float mean = (ws1[0] + ws1[1]) * (1.f/512.f);
  float d0=a0-mean, d1=a1-mean, d2=a2-mean, d3=a3-mean;
  float sq = wave_sum(d0*d0+d1*d1+d2*d2+d3*d3);
  if (ln_ == 0) ws2[wv] = sq;
  __syncthreads();
  float var = (ws2[0] + ws2[1]) * (1.f/512.f);
  float inv = 1.f/sqrtf(var + 1e-6f);
  float4 gv = *(const float4*)&g[c0];
  float4 bv = *(const float4*)&bt[c0];
  float4 o;
  o.x = d0*inv*gv.x + bv.x;
  o.y = d1*inv*gv.y + bv.y;
  o.z = d2*inv*gv.z + bv.z;
  o.w = d3*inv*gv.w + bv.w;
  size_t base = ((size_t)n << 9) + c0;
  split4(o, yh+base, yl+base);
}

// ---------------- rowwise LayerNorm over C=512 (optional split / mask) -------
template<bool SPLIT, bool MASK>
__global__ __launch_bounds__(256) void ln_rows(const float* __restrict__ x,
    const float* __restrict__ g, const float* __restrict__ bt,
    const float* __restrict__ rowmask,
    float* __restrict__ y, unsigned short* __restrict__ yh,
    unsigned short* __restrict__ yl, int nrows){
  int wid = threadIdx.x >> 6, lane = threadIdx.x & 63;
  int row = blockIdx.x*4 + wid;
  if (row >= nrows) return;
  const float4* xr = (const float4*)(x + ((size_t)row<<9));
  float4 a = xr[lane*2], b = xr[lane*2+1];
  float s = a.x+a.y+a.z+a.w+b.x+b.y+b.z+b.w;
  s = wave_sum(s);
  float m = s * (1.f/512.f);
  float d0=a.x-m,d1=a.y-m,d2=a.z-m,d3=a.w-m,d4=b.x-m,d5=b.y-m,d6=b.z-m,d7=b.w-m;
  float sq = d0*d0+d1*d1+d2*d2+d3*d3+d4*d4+d5*d5+d6*d6+d7*d7;
  sq = wave_sum(sq);
  float var = sq * (1.f/512.f);
  float inv = 1.f/sqrtf(var + 1e-6f);
  const float4* gr = (const float4*)g; const float4* br = (const float4*)bt;
  float4 g0=gr[lane*2], g1=gr[lane*2+1], b0=br[lane*2], b1=br[lane*2+1];
  float4 o0, o1;
  o0.x=d0*inv*g0.x+b0.x; o0.y=d1*inv*g0.y+b0.y; o0.z=d2*inv*g0.z+b0.z; o0.w=d3*inv*g0.w+b0.w;
  o1.x=d4*inv*g1.x+b1.x; o1.y=d5*inv*g1.y+b1.y; o1.z=d6*inv*g1.z+b1.z; o1.w=d7*inv*g1.w+b1.w;
  if constexpr (MASK){
    float mf = rowmask[row];
    o0.x*=mf; o0.y*=mf; o0.z*=mf; o0.w*=mf;
    o1.x*=mf; o1.y*=mf; o1.z*=mf; o1.w*=mf;
  }
  float4* yr = (float4*)(y + ((size_t)row<<9));
  yr[lane*2]=o0; yr[lane*2+1]=o1;
  if constexpr (SPLIT){
    size_t base = ((size_t)row<<9) + lane*8;
    split4(o0, yh+base,   yl+base);
    split4(o1, yh+base+4, yl+base+4);
  }
}

#define EPI_BIAS 0
#define EPI_SCALE 1
#define EPI_GELU 2
#define EPI_RES 3
#define EPI_RELU_MASK 4
#define EPI_RES_MASK 5
#define EPI_RES_GAMMA_MASK 6
#define EPI_TANH 7
#define EPI_QKV 8

// ---------------- style K/V prep -> bf16 planes (zero-padded to 64 keys) -----
__global__ __launch_bounds__(256) void style_prep(
    const float* __restrict__ style_key, const float* __restrict__ style_v,
    const float* __restrict__ sk_w, const float* __restrict__ sk_b,
    const float* __restrict__ sv_w, const float* __restrict__ sv_b,
    unsigned short* __restrict__ KKh, unsigned short* __restrict__ KKl,
    unsigned short* __restrict__ VTh_s, unsigned short* __restrict__ VTl_s)
{
  __shared__ float As[16][68];
  __shared__ float Bs[16][68];
  int sel = blockIdx.y;
  bool is_k = (sel < 2);
  int layer = sel & 1;
  const float* A = is_k ? style_key : style_v;
  const float* W = (sel==0) ? sk_w : (sel==1) ? sk_w+262144 :
                   (sel==2) ? sv_w : sv_w+262144;
  const float* bias = (sel==0) ? sk_b : (sel==1) ? sk_b+512 :
                      (sel==2) ? sv_b : sv_b+512;
  const int N = 50, K = 512;
  int t = threadIdx.x;
  int tx = t & 15, ty = t >> 4;
  int col0 = blockIdx.x << 6;
  int lr = t >> 2, lk = (t & 3) << 2;
  float acc[4][4] = {};
  bool arok = lr < N;
  const float* Ap = A + (size_t)(arok ? lr : 0) * K + lk;
  const float* Wp = W + (size_t)(col0 + lr) * K + lk;
  for (int k0 = 0; k0 < K; k0 += 16) {
    float4 av;
    if (arok) av = *(const float4*)(Ap + k0);
    else { av.x=0;av.y=0;av.z=0;av.w=0; }
    float4 bv = *(const float4*)(Wp + k0);
    As[lk+0][lr]=av.x; As[lk+1][lr]=av.y; As[lk+2][lr]=av.z; As[lk+3][lr]=av.w;
    Bs[lk+0][lr]=bv.x; Bs[lk+1][lr]=bv.y; Bs[lk+2][lr]=bv.z; Bs[lk+3][lr]=bv.w;
    __syncthreads();
    #pragma unroll
    for (int k=0;k<16;k++){
      float4 af = *(const float4*)&As[k][ty<<2];
      float4 bf = *(const float4*)&Bs[k][tx<<2];
      float a4[4]={af.x,af.y,af.z,af.w};
      float b4[4]={bf.x,bf.y,bf.z,bf.w};
      #pragma unroll
      for (int i=0;i<4;i++)
        #pragma unroll
        for (int j=0;j<4;j++)
          acc[i][j] += a4[i]*b4[j];
    }
    __syncthreads();
  }
  #pragma unroll
  for (int i=0;i<4;i++){
    int row = (ty<<2) + i;                 // 0..63 (padded keys zeroed)
    #pragma unroll
    for (int j=0;j<4;j++){
      int col = col0 + (tx<<2) + j;
      int head = col >> 8, d = col & 255;
      float v = 0.f;
      if (row < N){
        v = acc[i][j] + bias[col];
        if (is_k) v = tanhf(v);
      }
      unsigned short hh, ll_;
      splitc(v, hh, ll_);
      if (is_k){
        size_t o = (((size_t)layer*2 + head)<<14) + row*256 + d;
        KKh[o]=hh; KKl[o]=ll_;
      } else {
        size_t o = (((size_t)layer*2 + head)<<14) + d*64 + row;
        VTh_s[o]=hh; VTl_s[o]=ll_;
      }
    }
  }
}

// ---------------- MFMA style attention: block = 16 rows x 2 heads ------------
__global__ __launch_bounds__(256) void style_mf(
    const unsigned short* __restrict__ Qh_g, const unsigned short* __restrict__ Ql_g,
    const unsigned short* __restrict__ KKh, const unsigned short* __restrict__ KKl,
    const unsigned short* __restrict__ VTh_s, const unsigned short* __restrict__ VTl_s,
    const float* __restrict__ mask,
    unsigned short* __restrict__ Oh, unsigned short* __restrict__ Ol)
{
  __shared__ float Sc[2][16][68];
  __shared__ unsigned short Pph[2][16][72], Ppl[2][16][72];
  int t = threadIdx.x, lane = t & 63, w = t >> 6;
  int head = w >> 1, nh = w & 1;
  int rowbase = blockIdx.x * 16;
  int fr = lane & 15, fc = (lane >> 4) << 3, qbase = (lane >> 4) << 2;

  // ---- QK: S = Q_h . KK_h^T ----
  f32x4 s2[2] = {};
  #pragma unroll
  for (int ks = 0; ks < 8; ++ks){
    size_t qoff = (size_t)(rowbase + fr)*512 + head*256 + ks*32 + fc;
    short8v ah = *(const short8v*)(Qh_g + qoff);
    short8v al = *(const short8v*)(Ql_g + qoff);
    #pragma unroll
    for (int nt = 0; nt < 2; ++nt){
      int key = nh*32 + nt*16 + fr;
      size_t ko = (((size_t)head)<<14) + key*256 + ks*32 + fc;
      short8v bh = *(const short8v*)(KKh + ko);
      short8v bl = *(const short8v*)(KKl + ko);
      f32x4 c = s2[nt];
      c = __builtin_amdgcn_mfma_f32_16x16x32_bf16(ah,bh,c,0,0,0);
      c = __builtin_amdgcn_mfma_f32_16x16x32_bf16(ah,bl,c,0,0,0);
      c = __builtin_amdgcn_mfma_f32_16x16x32_bf16(al,bh,c,0,0,0);
      s2[nt] = c;
    }
  }
  #pragma unroll
  for (int nt = 0; nt < 2; ++nt)
    #pragma unroll
    for (int j = 0; j < 4; ++j)
      Sc[head][qbase+j][nh*32 + nt*16 + fr] = s2[nt][j] * 0.044194173824159216f;
  __syncthreads();

  // ---- softmax over 50 keys (32 threads: head x row); keep/sum folded in ----
  if (t < 32){
    int h2 = t >> 4, r = t & 15;
    float mx = -3.4e38f;
    for (int ss = 0; ss < 50; ++ss) mx = fmaxf(mx, Sc[h2][r][ss]);
    float sum = 0.f;
    for (int ss = 0; ss < 50; ++ss) sum += expf(Sc[h2][r][ss] - mx);
    float keep = (mask[rowbase + r] == 0.f) ? 0.f : 1.f;
    float inv = keep / sum;
    for (int ss = 0; ss < 64; ++ss){
      float p = (ss < 50) ? expf(Sc[h2][r][ss] - mx) * inv : 0.f;
      unsigned short hh, ll_;
      splitc(p, hh, ll_);
      Pph[h2][r][ss] = hh; Ppl[h2][r][ss] = ll_;
    }
  }
  __syncthreads();

  // ---- AV: O = P . V ----
  f32x4 av[8] = {};
  #pragma unroll
  for (int ks = 0; ks < 2; ++ks){
    short8v ah = *(const short8v*)&Pph[head][fr][ks*32 + fc];
    short8v al = *(const short8v*)&Ppl[head][fr][ks*32 + fc];
    #pragma unroll
    for (int nt = 0; nt < 8; ++nt){
      int d = nh*128 + nt*16 + fr;
      size_t vo = (((size_t)head)<<14) + d*64 + ks*32 + fc;
      short8v bh = *(const short8v*)(VTh_s + vo);
      short8v bl = *(const short8v*)(VTl_s + vo);
      f32x4 c = av[nt];
      c = __builtin_amdgcn_mfma_f32_16x16x32_bf16(ah,bh,c,0,0,0);
      c = __builtin_amdgcn_mfma_f32_16x16x32_bf16(ah,bl,c,0,0,0);
      c = __builtin_amdgcn_mfma_f32_16x16x32_bf16(al,bh,c,0,0,0);
      av[nt] = c;
    }
  }
  #pragma unroll
  for (int nt = 0; nt < 8; ++nt)
    #pragma unroll
    for (int j = 0; j < 4; ++j){
      int row = rowbase + qbase + j;
      int d = nh*128 + nt*16 + fr;
      unsigned short hh, ll_;
      splitc(av[nt][j], hh, ll_);
      size_t o = (size_t)row*512 + head*256 + d;
      Oh[o] = hh; Ol[o] = ll_;
    }
}

// ---------------- pre-split MFMA GEMM, double-buffered LDS (64-row tiles) ----
// OUT: 0 = fp32 Y, 1 = planes, 2 = QKV mode, 3 = fp32 Y + planes.
// SWZ=1: 1D grid 512; col-blocks sharing an A-row co-locate on one XCD.
template<int EPI, bool AMASK, int OUT, int NF, int SWZ>
__global__ __launch_bounds__(256) void gemm_ps(
    const unsigned short* __restrict__ Ah, const unsigned short* __restrict__ Al,
    const unsigned short* __restrict__ Wh, const unsigned short* __restrict__ Wl,
    const float* __restrict__ bias, const float* __restrict__ res,
    const float* __restrict__ gamma, const float* __restrict__ rowmask,
    float* __restrict__ Y, unsigned short* __restrict__ Yh,
    unsigned short* __restrict__ Yl, unsigned short* __restrict__ VTh,
    unsigned short* __restrict__ VTl, int K, int O, float scale)
{
  __shared__ unsigned short AhS[2][64][40], AlS[2][64][40];
  __shared__ unsigned short BhS[2][NF*32][40], BlS[2][NF*32][40];
  int t = threadIdx.x;
  int row0, col0;
  if constexpr (SWZ){
    int id = blockIdx.x;          // 512 blocks; XCD = id & 7
    int slot = id >> 3;           // 0..63
    row0 = ((id & 7) + ((slot >> 3) << 3)) << 6;   // rows == xcd (mod 8)
    col0 = (slot & 7) << 6;                        // 8 col-blocks per row
  } else {
    row0 = blockIdx.y << 6;
    col0 = blockIdx.x << (NF==4 ? 7 : 6);
  }
  int lane = t & 63, wid = t >> 6;
  int wr = wid >> 1, wc = wid & 1;

  int sr = t >> 2, sc = (t & 3) << 3;
  const unsigned short* Ahg = Ah + (size_t)(row0 + sr)*K + sc;
  const unsigned short* Alg = Al + (size_t)(row0 + sr)*K + sc;
  const unsigned short* Bhg = Wh + (size_t)(col0 + sr)*K + sc;
  const unsigned short* Blg = Wl + (size_t)(col0 + sr)*K + sc;
  float am = 1.f;
  if (AMASK) am = rowmask[row0 + sr];

  f32x4 acc[2][NF] = {};
  int nsteps = K >> 5;
  short8v ah_, al_, bh0_, bl0_, bh1_, bl1_;
  ah_ = *(const short8v*)(Ahg);
  al_ = *(const short8v*)(Alg);
  bh0_ = *(const short8v*)(Bhg);
  bl0_ = *(const short8v*)(Blg);
  if constexpr (NF==4){
    bh1_ = *(const short8v*)(Bhg + (size_t)64*K);
    bl1_ = *(const short8v*)(Blg + (size_t)64*K);
  }
  if (AMASK && am == 0.f){ ah_ ^= ah_; al_ ^= al_; }
  *(short8v*)&AhS[0][sr][sc] = ah_;
  *(short8v*)&AlS[0][sr][sc] = al_;
  *(short8v*)&BhS[0][sr][sc] = bh0_;
  *(short8v*)&BlS[0][sr][sc] = bl0_;
  if constexpr (NF==4){
    *(short8v*)&BhS[0][sr+64][sc] = bh1_;
    *(short8v*)&BlS[0][sr+64][sc] = bl1_;
  }

  int st = 0;
  for (int s = 0; s < nsteps; ++s){
    if (s+1 < nsteps){
      int ko = (s+1) << 5;
      ah_ = *(const short8v*)(Ahg + ko);
      al_ = *(const short8v*)(Alg + ko);
      bh0_ = *(const short8v*)(Bhg + ko);
      bl0_ = *(const short8v*)(Blg + ko);
      if constexpr (NF==4){
        bh1_ = *(const short8v*)(Bhg + (size_t)64*K + ko);
        bl1_ = *(const short8v*)(Blg + (size_t)64*K + ko);
      }
      if (AMASK && am == 0.f){ ah_ ^= ah_; al_ ^= al_; }
    }
    __syncthreads();
    int fr = lane & 15, fc = (lane >> 4) << 3;
    short8v ahf[2], alf[2], bhf[NF], blf[NF];
    #pragma unroll
    for (int mt=0; mt<2; ++mt){
      int r = (wr<<5) + (mt<<4) + fr;
      ahf[mt] = *(const short8v*)&AhS[st][r][fc];
      alf[mt] = *(const short8v*)&AlS[st][r][fc];
    }
    #pragma unroll
    for (int nt=0; nt<NF; ++nt){
      int r = (NF==4 ? (wc<<6) : (wc<<5)) + (nt<<4) + fr;
      bhf[nt] = *(const short8v*)&BhS[st][r][fc];
      blf[nt] = *(const short8v*)&BlS[st][r][fc];
    }
    #pragma unroll
    for (int mt=0; mt<2; ++mt)
      #pragma unroll
      for (int nt=0; nt<NF; ++nt){
        f32x4 c = acc[mt][nt];
        c = __builtin_amdgcn_mfma_f32_16x16x32_bf16(ahf[mt], bhf[nt], c, 0,0,0);
        c = __builtin_amdgcn_mfma_f32_16x16x32_bf16(ahf[mt], blf[nt], c, 0,0,0);
        c = __builtin_amdgcn_mfma_f32_16x16x32_bf16(alf[mt], bhf[nt], c, 0,0,0);
        acc[mt][nt] = c;
      }
    if (s+1 < nsteps){
      int nb = st ^ 1;
      *(short8v*)&AhS[nb][sr][sc] = ah_;
      *(short8v*)&AlS[nb][sr][sc] = al_;
      *(short8v*)&BhS[nb][sr][sc] = bh0_;
      *(short8v*)&BlS[nb][sr][sc] = bl0_;
      if constexpr (NF==4){
        *(short8v*)&BhS[nb][sr+64][sc] = bh1_;
        *(short8v*)&BlS[nb][sr+64][sc] = bl1_;
      }
    }
    st ^= 1;
  }

  int rb = row0 + (wr<<5) + ((lane>>4)<<2);
  int cb = col0 + (NF==4 ? (wc<<6) : (wc<<5)) + (lane & 15);
  float bs[NF], gm[NF];
  int which = 0;
  if constexpr (EPI==EPI_QKV) which = blockIdx.x >> 2;
  #pragma unroll
  for (int nt=0; nt<NF; ++nt){
    int col = cb + (nt<<4);
    if constexpr (EPI==EPI_QKV){
      const float* bp = (which==0) ? bias : (which==1) ? res : gamma;
      bs[nt] = bp[col & 511];
    } else {
      bs[nt] = bias[col];
      if constexpr (EPI==EPI_RES_GAMMA_MASK) gm[nt] = gamma[col];
    }
  }
  float qscale = 1.f;
  if constexpr (EPI==EPI_QKV) qscale = (which==0) ? scale : 1.f;

  if constexpr (OUT==2){
    if (which == 2){
      #pragma unroll
      for (int mt=0; mt<2; ++mt){
        int row = rb + (mt<<4);
        int b = row >> 9, tok = row & 511;
        #pragma unroll
        for (int nt=0; nt<NF; ++nt){
          int dglob = cb + (nt<<4) - 1024;
          size_t vt = ((size_t)b*512 + dglob)*512 + tok;
          unsigned short h4[4], l4[4];
          #pragma unroll
          for (int j=0; j<4; ++j)
            splitc(acc[mt][nt][j] + bs[nt], h4[j], l4[j]);
          *(ushort4*)&VTh[vt] = make_ushort4(h4[0],h4[1],h4[2],h4[3]);
          *(ushort4*)&VTl[vt] = make_ushort4(l4[0],l4[1],l4[2],l4[3]);
        }
      }
      return;
    }
    #pragma unroll
    for (int mt=0; mt<2; ++mt)
      #pragma unroll
      for (int j=0; j<4; ++j){
        int row = rb + (mt<<4) + j;
        #pragma unroll
        for (int nt=0; nt<NF; ++nt){
          float v = (acc[mt][nt][j] + bs[nt]) * qscale;
          size_t oidx = (size_t)row*O + cb + (nt<<4);
          unsigned short h,l; splitc(v,h,l); Yh[oidx]=h; Yl[oidx]=l;
        }
      }
    return;
  }

  #pragma unroll
  for (int mt=0; mt<2; ++mt)
    #pragma unroll
    for (int j=0; j<4; ++j){
      int row = rb + (mt<<4) + j;
      float rm = 1.f;
      if constexpr (EPI==EPI_RELU_MASK || EPI==EPI_RES_MASK || EPI==EPI_RES_GAMMA_MASK)
        rm = rowmask[row];
      const float* rr = nullptr;
      if constexpr (EPI==EPI_RES || EPI==EPI_RES_MASK || EPI==EPI_RES_GAMMA_MASK)
        rr = res + (size_t)row*O + cb;
      #pragma unroll
      for (int nt=0; nt<NF; ++nt){
        float v = acc[mt][nt][j] + bs[nt];
        if constexpr (EPI==EPI_SCALE) v *= scale;
        else if constexpr (EPI==EPI_QKV) v *= qscale;
        else if constexpr (EPI==EPI_GELU) v = 0.5f*v*(1.f+erff(v*0.7071067811865475f));
        else if constexpr (EPI==EPI_RES) v = rr[nt<<4] + v;
        else if constexpr (EPI==EPI_RELU_MASK) v = fmaxf(v,0.f)*rm;
        else if constexpr (EPI==EPI_RES_MASK) v = rr[nt<<4] + v*rm;
        else if constexpr (EPI==EPI_RES_GAMMA_MASK) v = (rr[nt<<4] + gm[nt]*v)*rm;
        size_t oidx = (size_t)row*O + cb + (nt<<4);
        if constexpr (OUT==0) Y[oidx] = v;
        else if constexpr (OUT==3){
          Y[oidx] = v;
          unsigned short h,l; splitc(v,h,l); Yh[oidx]=h; Yl[oidx]=l;
        }
        else { unsigned short h,l; splitc(v,h,l); Yh[oidx]=h; Yl[oidx]=l; }
      }
    }
}

// ---------------- 128x128x32 MFMA GEMM (big-O GEMMs: pw1/ffn1/QKV) -----------
// SWZ=1: 1D grid 512 (32r x 16c); SWZ=2: 1D grid 384 (32r x 12c, QKV).
template<int EPI, bool AMASK, int OUT, int SWZ>
__global__ __launch_bounds__(256) void gemm_big(
    const unsigned short* __restrict__ Ah, const unsigned short* __restrict__ Al,
    const unsigned short* __restrict__ Wh, const unsigned short* __restrict__ Wl,
    const float* __restrict__ bias, const float* __restrict__ res,
    const float* __restrict__ gamma, const float* __restrict__ rowmask,
    float* __restrict__ Y, unsigned short* __restrict__ Yh,
    unsigned short* __restrict__ Yl, unsigned short* __restrict__ VTh,
    unsigned short* __restrict__ VTl, int K, int O, float scale)
{
  __shared__ unsigned short AhS[128][40], AlS[128][40];
  __shared__ unsigned short BhS[128][40], BlS[128][40];
  int t = threadIdx.x;
  int row0, col0;
  if constexpr (SWZ == 1){
    int id = blockIdx.x;          // 512 blocks; XCD = id & 7
    int slot = id >> 3;           // 0..63
    row0 = ((id & 7) + ((slot >> 4) << 3)) << 7;   // 32 rows: xcd + 8*(slot>>4)
    col0 = (slot & 15) << 7;                       // 16 col-blocks per row
  } else if constexpr (SWZ == 2){
    int id = blockIdx.x;          // 384 blocks; XCD = id & 7
    int slot = id >> 3;           // 0..47
    int rq = slot / 12;           // 0..3
    int cbk = slot - rq*12;       // 0..11
    row0 = ((id & 7) + (rq << 3)) << 7;            // 32 rows
    col0 = cbk << 7;                               // 12 col-blocks per row
  } else {
    row0 = blockIdx.y << 7;
    col0 = blockIdx.x << 7;
  }
  int lane = t & 63, wid = t >> 6;
  int wr = wid >> 1, wc = wid & 1;

  int sr = t >> 2, sc = (t & 3) << 3;
  const unsigned short* Ahg = Ah + (size_t)(row0 + sr)*K + sc;
  const unsigned short* Alg = Al + (size_t)(row0 + sr)*K + sc;
  const unsigned short* Bhg = Wh + (size_t)(col0 + sr)*K + sc;
  const unsigned short* Blg = Wl + (size_t)(col0 + sr)*K + sc;
  bool az0 = false, az1 = false;
  if (AMASK){ az0 = (rowmask[row0+sr] == 0.f); az1 = (rowmask[row0+sr+64] == 0.f); }

  f32x4 acc[4][4] = {};
  int nsteps = K >> 5;
  short8v a0h,a0l,a1h,a1l,b0h,b0l,b1h,b1l;
  a0h = *(const short8v*)(Ahg);
  a0l = *(const short8v*)(Alg);
  a1h = *(const short8v*)(Ahg + (size_t)64*K);
  a1l = *(const short8v*)(Alg + (size_t)64*K);
  b0h = *(const short8v*)(Bhg);
  b0l = *(const short8v*)(Blg);
  b1h = *(const short8v*)(Bhg + (size_t)64*K);
  b1l = *(const short8v*)(Blg + (size_t)64*K);

  for (int s = 0; s < nsteps; ++s){
    if (AMASK){
      if (az0){ a0h ^= a0h; a0l ^= a0l; }
      if (az1){ a1h ^= a1h; a1l ^= a1l; }
    }
    __syncthreads();
    *(short8v*)&AhS[sr][sc] = a0h;    *(short8v*)&AlS[sr][sc] = a0l;
    *(short8v*)&AhS[sr+64][sc] = a1h; *(short8v*)&AlS[sr+64][sc] = a1l;
    *(short8v*)&BhS[sr][sc] = b0h;    *(short8v*)&BlS[sr][sc] = b0l;
    *(short8v*)&BhS[sr+64][sc] = b1h; *(short8v*)&BlS[sr+64][sc] = b1l;
    __syncthreads();
    if (s+1 < nsteps){
      int ko = (s+1) << 5;
      a0h = *(const short8v*)(Ahg + ko);
      a0l = *(const short8v*)(Alg + ko);
      a1h = *(const short8v*)(Ahg + (size_t)64*K + ko);
      a1l = *(const short8v*)(Alg + (size_t)64*K + ko);
      b0h = *(const short8v*)(Bhg + ko);
      b0l = *(const short8v*)(Blg + ko);
      b1h = *(const short8v*)(Bhg + (size_t)64*K + ko);
      b1l = *(const short8v*)(Blg + (size_t)64*K + ko);
    }
    int fr = lane & 15, fc = (lane >> 4) << 3;
    short8v ahf[4], alf[4], bhf[4], blf[4];
    #pragma unroll
    for (int mt=0; mt<4; ++mt){
      int r = (wr<<6) + (mt<<4) + fr;
      ahf[mt] = *(const short8v*)&AhS[r][fc];
      alf[mt] = *(const short8v*)&AlS[r][fc];
    }
    #pragma unroll
    for (int nt=0; nt<4; ++nt){
      int r = (wc<<6) + (nt<<4) + fr;
      bhf[nt] = *(const short8v*)&BhS[r][fc];
      blf[nt] = *(const short8v*)&BlS[r][fc];
    }
    #pragma unroll
    for (int mt=0; mt<4; ++mt)
      #pragma unroll
      for (int nt=0; nt<4; ++nt){
        f32x4 c = acc[mt][nt];
        c = __builtin_amdgcn_mfma_f32_16x16x32_bf16(ahf[mt], bhf[nt], c, 0,0,0);
        c = __builtin_amdgcn_mfma_f32_16x16x32_bf16(ahf[mt], blf[nt], c, 0,0,0);
        c = __builtin_amdgcn_mfma_f32_16x16x32_bf16(alf[mt], bhf[nt], c, 0,0,0);
        acc[mt][nt] = c;
      }
  }

  int rb = row0 + (wr<<6) + ((lane>>4)<<2);
  int cb = col0 + (wc<<6) + (lane & 15);
  float bs[4];
  int which = 0;
  if constexpr (EPI==EPI_QKV) which = col0 >> 9;
  #pragma unroll
  for (int nt=0; nt<4; ++nt){
    int col = cb + (nt<<4);
    if constexpr (EPI==EPI_QKV){
      const float* bp = (which==0) ? bias : (which==1) ? res : gamma;
      bs[nt] = bp[col & 511];
    } else {
      bs[nt] = bias[col];
    }
  }
  float qscale = 1.f;
  if constexpr (EPI==EPI_QKV) qscale = (which==0) ? scale : 1.f;

  if constexpr (OUT==2){
    if (which == 2){
      #pragma unroll
      for (int mt=0; mt<4; ++mt){
        int row = rb + (mt<<4);
        int b = row >> 9, tok = row & 511;
        #pragma unroll
        for (int nt=0; nt<4; ++nt){
          int dglob = cb + (nt<<4) - 1024;
          size_t vt = ((size_t)b*512 + dglob)*512 + tok;
          unsigned short h4[4], l4[4];
          #pragma unroll
          for (int j=0; j<4; ++j)
            splitc(acc[mt][nt][j] + bs[nt], h4[j], l4[j]);
          *(ushort4*)&VTh[vt] = make_ushort4(h4[0],h4[1],h4[2],h4[3]);
          *(ushort4*)&VTl[vt] = make_ushort4(l4[0],l4[1],l4[2],l4[3]);
        }
      }
      return;
    }
    #pragma unroll
    for (int mt=0; mt<4; ++mt)
      #pragma unroll
      for (int j=0; j<4; ++j){
        int row = rb + (mt<<4) + j;
        #pragma unroll
        for (int nt=0; nt<4; ++nt){
          float v = (acc[mt][nt][j] + bs[nt]) * qscale;
          size_t oidx = (size_t)row*O + cb + (nt<<4);
          unsigned short h,l; splitc(v,h,l); Yh[oidx]=h; Yl[oidx]=l;
        }
      }
    return;
  }

  #pragma unroll
  for (int mt=0; mt<4; ++mt)
    #pragma unroll
    for (int j=0; j<4; ++j){
      int row = rb + (mt<<4) + j;
      float rm = 1.f;
      if constexpr (EPI==EPI_RELU_MASK) rm = rowmask[row];
      #pragma unroll
      for (int nt=0; nt<4; ++nt){
        float v = acc[mt][nt][j] + bs[nt];
        if constexpr (EPI==EPI_GELU) v = 0.5f*v*(1.f+erff(v*0.7071067811865475f));
        else if constexpr (EPI==EPI_RELU_MASK) v = fmaxf(v,0.f)*rm;
        size_t oidx = (size_t)row*O + cb + (nt<<4);
        if constexpr (OUT==0) Y[oidx] = v;
        else { unsigned short h,l; splitc(v,h,l); Yh[oidx]=h; Yl[oidx]=l; }
      }
    }
}

// ---------------- MFMA windowed-rel attention v4: 2 Q-tiles per block --------
__global__ __launch_bounds__(256) void attn_mf(
    const unsigned short* __restrict__ Ph_g, const unsigned short* __restrict__ Pl_g,
    const unsigned short* __restrict__ VTh_g, const unsigned short* __restrict__ VTl_g,
    const float* __restrict__ relk, const float* __restrict__ relv,
    const float* __restrict__ mask, unsigned short* __restrict__ Oh,
    unsigned short* __restrict__ Ol)
{
  __shared__ float ms_[512];
  __shared__ float rv[9][64];
  __shared__ float qrel[32][16];
  __shared__ float red1[4][32];
  __shared__ float red2[4][32];
  __shared__ __align__(16) unsigned short Spool[32*520];
  unsigned short (*Qh)[72]  = (unsigned short(*)[72])(Spool);          // [32][72]
  unsigned short (*Ql)[72]  = (unsigned short(*)[72])(Spool + 2304);   // [32][72]
  unsigned short (*Rkh)[72] = (unsigned short(*)[72])(Spool + 4608);   // [16][72]
  unsigned short (*Rkl)[72] = (unsigned short(*)[72])(Spool + 5760);   // [16][72]
  unsigned short (*Sp)[520] = (unsigned short(*)[520])(Spool);         // [32][520]

  int id = blockIdx.x;
  int xcd = id & 7, kk = id >> 3;
  int bh_ = xcd*8 + (kk >> 4);
  int qt = kk & 15;
  int h = bh_ & 7, b_ = bh_ >> 3;
  int t = threadIdx.x;
  int l0 = qt * 32;
  const size_t rowoff = (size_t)b_ * 512;
  int lane = t & 63, w = t >> 6;

  ms_[t] = mask[rowoff + t]; ms_[t+256] = mask[rowoff + t + 256];
  for (int i = t; i < 576; i += 256) ((float*)rv)[i] = relv[i];
  {
    int r = t >> 4, c = (t & 15) << 2;
    float4 v;
    if (r < 9) v = *(const float4*)&relk[r*64 + c];
    else { v.x=0.f; v.y=0.f; v.z=0.f; v.w=0.f; }
    split4(v, &Rkh[r][c], &Rkl[r][c]);
  }
  for (int i = t; i < 512; i += 256){
    int r = (i & 255) >> 3, c = (i & 7) << 3;
    size_t g = (rowoff + l0 + r)*QKVS + h*64 + c;
    if (i < 256) *(short8v*)&Qh[r][c] = *(const short8v*)&Ph_g[g];
    else         *(short8v*)&Ql[r][c] = *(const short8v*)&Pl_g[g];
  }
  __syncthreads();

  int fr = lane & 15, fc = (lane >> 4) << 3;
  int qbase = (lane>>4) << 2;
  short8v a0h0 = *(const short8v*)&Qh[fr][fc];
  short8v a0h1 = *(const short8v*)&Qh[fr][32+fc];
  short8v a0l0 = *(const short8v*)&Ql[fr][fc];
  short8v a0l1 = *(const short8v*)&Ql[fr][32+fc];
  short8v a1h0 = *(const short8v*)&Qh[16+fr][fc];
  short8v a1h1 = *(const short8v*)&Qh[16+fr][32+fc];
  short8v a1l0 = *(const short8v*)&Ql[16+fr][fc];
  short8v a1l1 = *(const short8v*)&Ql[16+fr][32+fc];

  if (w < 2){
    short8v rh0 = *(const short8v*)&Rkh[fr][fc];
    short8v rh1 = *(const short8v*)&Rkh[fr][32+fc];
    short8v rl0 = *(const short8v*)&Rkl[fr][fc];
    short8v rl1 = *(const short8v*)&Rkl[fr][32+fc];
    short8v qa0 = (w==0) ? a0h0 : a1h0;
    short8v qa1 = (w==0) ? a0h1 : a1h1;
    short8v qb0 = (w==0) ? a0l0 : a1l0;
    short8v qb1 = (w==0) ? a0l1 : a1l1;
    f32x4 c4 = {};
    c4 = __builtin_amdgcn_mfma_f32_16x16x32_bf16(qa0,rh0,c4,0,0,0);
    c4 = __builtin_amdgcn_mfma_f32_16x16x32_bf16(qa1,rh1,c4,0,0,0);
    c4 = __builtin_amdgcn_mfma_f32_16x16x32_bf16(qa0,rl0,c4,0,0,0);
    c4 = __builtin_amdgcn_mfma_f32_16x16x32_bf16(qa1,rl1,c4,0,0,0);
    c4 = __builtin_amdgcn_mfma_f32_16x16x32_bf16(qb0,rh0,c4,0,0,0);
    c4 = __builtin_amdgcn_mfma_f32_16x16x32_bf16(qb1,rh1,c4,0,0,0);
    #pragma unroll
    for (int j = 0; j < 4; ++j) qrel[w*16 + qbase + j][fr] = c4[j];
  }
  __syncthreads();   // after this: Q/Rk LDS dead, P region live

  f32x4 sreg0[8], sreg1[8];
  #pragma unroll
  for (int tt = 0; tt < 8; ++tt){
    int br = tt*64 + w*16 + fr;
    const unsigned short* krh = Ph_g + (rowoff + br)*QKVS + 512 + h*64;
    const unsigned short* krl = Pl_g + (rowoff + br)*QKVS + 512 + h*64;
    short8v bh0 = *(const short8v*)(krh + fc);
    short8v bh1 = *(const short8v*)(krh + 32 + fc);
    short8v bl0 = *(const short8v*)(krl + fc);
    short8v bl1 = *(const short8v*)(krl + 32 + fc);
    f32x4 c0 = {}, c1 = {};
    c0 = __builtin_amdgcn_mfma_f32_16x16x32_bf16(a0h0,bh0,c0,0,0,0);
    c1 = __builtin_amdgcn_mfma_f32_16x16x32_bf16(a1h0,bh0,c1,0,0,0);
    c0 = __builtin_amdgcn_mfma_f32_16x16x32_bf16(a0h1,bh1,c0,0,0,0);
    c1 = __builtin_amdgcn_mfma_f32_16x16x32_bf16(a1h1,bh1,c1,0,0,0);
    c0 = __builtin_amdgcn_mfma_f32_16x16x32_bf16(a0h0,bl0,c0,0,0,0);
    c1 = __builtin_amdgcn_mfma_f32_16x16x32_bf16(a1h0,bl0,c1,0,0,0);
    c0 = __builtin_amdgcn_mfma_f32_16x16x32_bf16(a0h1,bl1,c0,0,0,0);
    c1 = __builtin_amdgcn_mfma_f32_16x16x32_bf16(a1h1,bl1,c1,0,0,0);
    c0 = __builtin_amdgcn_mfma_f32_16x16x32_bf16(a0l0,bh0,c0,0,0,0);
    c1 = __builtin_amdgcn_mfma_f32_16x16x32_bf16(a1l0,bh0,c1,0,0,0);
    c0 = __builtin_amdgcn_mfma_f32_16x16x32_bf16(a0l1,bh1,c0,0,0,0);
    c1 = __builtin_amdgcn_mfma_f32_16x16x32_bf16(a1l1,bh1,c1,0,0,0);
    int m = tt*64 + w*16 + fr;
    float mm_ = ms_[m];
    #pragma unroll
    for (int j = 0; j < 4; ++j){
      int q = qbase + j;
      {
        int l = l0 + q;
        float s = c0[j];
        int dlt = m - l + 4;
        if (dlt >= 0 && dlt <= 8) s += qrel[q][dlt];
        if (ms_[l] * mm_ == 0.f) s = -10000.f;
        c0[j] = s;
      }
      {
        int l = l0 + 16 + q;
        float s = c1[j];
        int dlt = m - l + 4;
        if (dlt >= 0 && dlt <= 8) s += qrel[16 + q][dlt];
        if (ms_[l] * mm_ == 0.f) s = -10000.f;
        c1[j] = s;
      }
    }
    sreg0[tt] = c0; sreg1[tt] = c1;
  }

  float mx0[4], mx1[4], sm0[4], sm1[4], inv0[4], inv1[4];
  #pragma unroll
  for (int j = 0; j < 4; ++j){
    float v0 = sreg0[0][j], v1 = sreg1[0][j];
    #pragma unroll
    for (int tt = 1; tt < 8; ++tt){
      v0 = fmaxf(v0, sreg0[tt][j]);
      v1 = fmaxf(v1, sreg1[tt][j]);
    }
    #pragma unroll
    for (int o = 8; o >= 1; o >>= 1){
      v0 = fmaxf(v0, __shfl_xor(v0, o));
      v1 = fmaxf(v1, __shfl_xor(v1, o));
    }
    mx0[j] = v0; mx1[j] = v1;
  }
  if (fr == 0){
    #pragma unroll
    for (int j = 0; j < 4; ++j){
      red1[w][qbase + j] = mx0[j];
      red1[w][16 + qbase + j] = mx1[j];
    }
  }
  __syncthreads();
  #pragma unroll
  for (int j = 0; j < 4; ++j){
    int q = qbase + j;
    mx0[j] = fmaxf(fmaxf(red1[0][q], red1[1][q]), fmaxf(red1[2][q], red1[3][q]));
    mx1[j] = fmaxf(fmaxf(red1[0][16+q], red1[1][16+q]), fmaxf(red1[2][16+q], red1[3][16+q]));
  }
  #pragma unroll
  for (int j = 0; j < 4; ++j){ sm0[j] = 0.f; sm1[j] = 0.f; }
  #pragma unroll
  for (int tt = 0; tt < 8; ++tt){
    f32x4 c0 = sreg0[tt], c1 = sreg1[tt];
    #pragma unroll
    for (int j = 0; j < 4; ++j){
      float e0 = expf(c0[j] - mx0[j]);
      float e1 = expf(c1[j] - mx1[j]);
      c0[j] = e0; c1[j] = e1;
      sm0[j] += e0; sm1[j] += e1;
    }
    sreg0[tt] = c0; sreg1[tt] = c1;
  }
  #pragma unroll
  for (int j = 0; j < 4; ++j){
    float v0 = sm0[j], v1 = sm1[j];
    #pragma unroll
    for (int o = 8; o >= 1; o >>= 1){
      v0 += __shfl_xor(v0, o);
      v1 += __shfl_xor(v1, o);
    }
    sm0[j] = v0; sm1[j] = v1;
  }
  if (fr == 0){
    #pragma unroll
    for (int j = 0; j < 4; ++j){
      red2[w][qbase + j] = sm0[j];
      red2[w][16 + qbase + j] = sm1[j];
    }
  }
  #pragma unroll
  for (int tt = 0; tt < 8; ++tt){
    int m = tt*64 + w*16 + fr;
    #pragma unroll
    for (int j = 0; j < 4; ++j){
      Sp[qbase + j][m]      = f2bf_rne(sreg0[tt][j]);
      Sp[16 + qbase + j][m] = f2bf_rne(sreg1[tt][j]);
    }
  }
  __syncthreads();
  #pragma unroll
  for (int j = 0; j < 4; ++j){
    int q = qbase + j;
    inv0[j] = 1.f / (red2[0][q] + red2[1][q] + red2[2][q] + red2[3][q]);
    inv1[j] = 1.f / (red2[0][16+q] + red2[1][16+q] + red2[2][16+q] + red2[3][16+q]);
  }

  f32x4 oacc0 = {}, oacc1 = {};
  const unsigned short* vrh = VTh_g + ((size_t)b_*512 + h*64 + w*16 + fr)*512;
  const unsigned short* vrl = VTl_g + ((size_t)b_*512 + h*64 + w*16 + fr)*512;
  #pragma unroll
  for (int tt = 0; tt < 8; ++tt){
    #pragma unroll
    for (int ks = 0; ks < 2; ++ks){
      int moff = tt*64 + ks*32 + fc;
      short8v ap0 = *(const short8v*)&Sp[fr][moff];
      short8v ap1 = *(const short8v*)&Sp[16+fr][moff];
      short8v bh = *(const short8v*)(vrh + moff);
      short8v bl = *(const short8v*)(vrl + moff);
      oacc0 = __builtin_amdgcn_mfma_f32_16x16x32_bf16(ap0,bh,oacc0,0,0,0);
      oacc1 = __builtin_amdgcn_mfma_f32_16x16x32_bf16(ap1,bh,oacc1,0,0,0);
      oacc0 = __builtin_amdgcn_mfma_f32_16x16x32_bf16(ap0,bl,oacc0,0,0,0);
      oacc1 = __builtin_amdgcn_mfma_f32_16x16x32_bf16(ap1,bl,oacc1,0,0,0);
    }
  }
  {
    int d = w*16 + fr;
    #pragma unroll
    for (int j = 0; j < 4; ++j){
      {
        int q = qbase + j;
        int l = l0 + q;
        float val = oacc0[j];
        #pragma unroll
        for (int dlt = 0; dlt < 9; ++dlt){
          int m = l + dlt - 4;
          if (m >= 0 && m < 512){
            float e = bf2f(Sp[q][m]);
            val += e * rv[dlt][d];
          }
        }
        val *= inv0[j];
        unsigned short hh, ll_; splitc(val, hh, ll_);
        size_t oidx = ((rowoff + l) << 9) + h*64 + d;
        Oh[oidx] = hh; Ol[oidx] = ll_;
      }
      {
        int q = 16 + qbase + j;
        int l = l0 + q;
        float val = oacc1[j];
        #pragma unroll
        for (int dlt = 0; dlt < 9; ++dlt){
          int m = l + dlt - 4;
          if (m >= 0 && m < 512){
            float e = bf2f(Sp[q][m]);
            val += e * rv[dlt][d];
          }
        }
        val *= inv1[j];
        unsigned short hh, ll_; splitc(val, hh, ll_);
        size_t oidx = ((rowoff + l) << 9) + h*64 + d;
        Oh[oidx] = hh; Ol[oidx] = ll_;
      }
    }
  }
}

// ---------------- final transpose ----------------
__global__ __launch_bounds__(256) void transpose_out_k(const float* __restrict__ xn,
    const float* __restrict__ mask, float* __restrict__ out){
  __shared__ float tile[32][33];
  int b_ = blockIdx.z; int c0 = blockIdx.x*32; int l0 = blockIdx.y*32;
  int tx = threadIdx.x & 31, ty = threadIdx.x >> 5;
  #pragma unroll
  for (int r=0;r<4;r++){
    int l = l0 + ty + r*8;
    tile[ty + r*8][tx] = xn[(((size_t)(b_*512 + l))<<9) + c0 + tx];
  }
  __syncthreads();
  float mm = mask[b_*512 + l0 + tx];
  #pragma unroll
  for (int r=0;r<4;r++){
    int c = c0 + ty + r*8;
    out[(((size_t)(b_*512 + c))<<9) + l0 + tx] = tile[tx][ty + r*8] * mm;
  }
}

extern "C" void kernel_launch(void* const* d_in, const int* in_sizes, int n_in,
                              void* d_out, int out_size, void* d_ws, size_t ws_size,
                              hipStream_t stream) {
  const int*   tokens   = (const int*)  d_in[0];
  const float* style_v  = (const float*)d_in[1];
  const float* mask     = (const float*)d_in[2];
  const float* embed_w  = (const float*)d_in[3];
  const float* cw_dw_w  = (const float*)d_in[4];
  const float* cw_dw_b  = (const float*)d_in[5];
  const float* cw_ln_g  = (const float*)d_in[6];
  const float* cw_ln_b  = (const float*)d_in[7];
  const float* cw_pw1_w = (const float*)d_in[8];
  const float* cw_pw1_b = (const float*)d_in[9];
  const float* cw_pw2_w = (const float*)d_in[10];
  const float* cw_pw2_b = (const float*)d_in[11];
  const float* cw_gamma = (const float*)d_in[12];
  const float* aq_w = (const float*)d_in[13];
  const float* aq_b = (const float*)d_in[14];
  const float* ak_w = (const float*)d_in[15];
  const float* ak_b = (const float*)d_in[16];
  const float* av_w = (const float*)d_in[17];
  const float* av_b = (const float*)d_in[18];
  const float* ao_w = (const float*)d_in[19];
  const float* ao_b = (const float*)d_in[20];
  const float* rel_k = (const float*)d_in[21];
  const float* rel_v = (const float*)d_in[22];
  const float* ln1_g = (const float*)d_in[23];
  const float* ln1_b = (const float*)d_in[24];
  const float* ln2_g = (const float*)d_in[25];
  const float* ln2_b = (const float*)d_in[26];
  const float* ffn_w1 = (const float*)d_in[27];
  const float* ffn_b1 = (const float*)d_in[28];
  const float* ffn_w2 = (const float*)d_in[29];
  const float* ffn_b2 = (const float*)d_in[30];
  const float* style_key = (const float*)d_in[31];
  const float* sq_w = (const float*)d_in[32];
  const float* sq_b = (const float*)d_in[33];
  const float* sk_w = (const float*)d_in[34];
  const float* sk_b = (const float*)d_in[35];
  const float* sv_w = (const float*)d_in[36];
  const float* sv_b = (const float*)d_in[37];
  const float* so_w = (const float*)d_in[38];
  const float* so_b = (const float*)d_in[39];
  const float* sn_g = (const float*)d_in[40];
  const float* sn_b = (const float*)d_in[41];

  const int N = NROWS;
  char* cur = (char*)d_ws;
  auto nextF = [&](size_t n)->float*{ float* p=(float*)cur; cur += n*sizeof(float); return p; };
  auto nextU = [&](size_t n)->unsigned short*{ unsigned short* p=(unsigned short*)cur; cur += n*2; return p; };

  float* X   = nextF((size_t)N*512);
  float* T   = nextF((size_t)N*512);
  float* Qb  = nextF((size_t)N*512);
  float* Vb  = nextF((size_t)N*512);
  unsigned short* Xh = nextU((size_t)N*512);
  unsigned short* Xl = nextU((size_t)N*512);
  unsigned short* Th = nextU((size_t)N*512);
  unsigned short* Tl = nextU((size_t)N*512);
  unsigned short* Hbh = nextU((size_t)N*2048);
  unsigned short* Hbl = nextU((size_t)N*2048);
  unsigned short* QKVh = nextU((size_t)N*QKVS);
  unsigned short* QKVl = nextU((size_t)N*QKVS);
  unsigned short* VTh = nextU((size_t)8*512*512);
  unsigned short* VTl = nextU((size_t)8*512*512);
  // weight planes
  unsigned short* pw1h = nextU(4194304); unsigned short* pw1l = nextU(4194304);
  unsigned short* pw2h = nextU(4194304); unsigned short* pw2l = nextU(4194304);
  unsigned short* qkvh = nextU((size_t)6*QKVS*512); unsigned short* qkvl = nextU((size_t)6*QKVS*512);
  unsigned short* aoh  = nextU(1572864); unsigned short* aol  = nextU(1572864);
  unsigned short* f1h  = nextU(6291456); unsigned short* f1l  = nextU(6291456);
  unsigned short* f2h  = nextU(6291456); unsigned short* f2l  = nextU(6291456);
  unsigned short* sqh  = nextU(524288);  unsigned short* sql  = nextU(524288);
  unsigned short* soh  = nextU(524288);  unsigned short* sol  = nextU(524288);
  // style planes: KKp [2 layers][2 heads][64][256]; VTp [2][2][256][64]
  unsigned short* KKsh = nextU(65536); unsigned short* KKsl = nextU(65536);
  unsigned short* VTsh = nextU(65536); unsigned short* VTsl = nextU(65536);

  // ---- weight prep (single merged launch) ----
  split_all<<<dim3(512,8),256,0,stream>>>(cw_pw1_w, cw_pw2_w, ao_w, ffn_w1,
      ffn_w2, sq_w, so_w, aq_w, ak_w, av_w,
      pw1h, pw1l, pw2h, pw2l, aoh, aol, f1h, f1l, f2h, f2l,
      sqh, sql, soh, sol, qkvh, qkvl);

  embed_k<<<4096,128,0,stream>>>(tokens, embed_w, mask, X);

  // ---- ConvNeXt blocks (dwconv+LN fused; all GEMMs XCD-swizzled) ----
  for (int i=0;i<4;i++){
    dwln_k<<<4096,128,0,stream>>>(X, cw_dw_w + (size_t)i*512*5, cw_dw_b + i*512,
        mask, cw_ln_g+i*512, cw_ln_b+i*512, Th, Tl);
    gemm_big<EPI_GELU,false,1,1><<<512,256,0,stream>>>(Th, Tl,
        pw1h + (size_t)i*1048576, pw1l + (size_t)i*1048576,
        cw_pw1_b+i*2048, nullptr, nullptr, nullptr, nullptr, Hbh, Hbl,
        nullptr, nullptr, 512, 2048, 0.f);
    if (i < 3)
      gemm_ps<EPI_RES_GAMMA_MASK,false,0,2,1><<<512,256,0,stream>>>(Hbh, Hbl,
          pw2h + (size_t)i*1048576, pw2l + (size_t)i*1048576,
          cw_pw2_b+i*512, X, cw_gamma+i*512, mask, X, nullptr, nullptr,
          nullptr, nullptr, 2048, 512, 0.f);
    else
      gemm_ps<EPI_RES_GAMMA_MASK,false,3,2,1><<<512,256,0,stream>>>(Hbh, Hbl,
          pw2h + (size_t)i*1048576, pw2l + (size_t)i*1048576,
          cw_pw2_b+i*512, X, cw_gamma+i*512, mask, X, Xh, Xl,
          nullptr, nullptr, 2048, 512, 0.f);
  }

  // ---- Attention layers ----
  for (int i=0;i<6;i++){
    gemm_big<EPI_QKV,false,2,2><<<384,256,0,stream>>>(Xh, Xl,
        qkvh + (size_t)i*QKVS*512, qkvl + (size_t)i*QKVS*512,
        aq_b+i*512, ak_b+i*512, av_b+i*512, nullptr, nullptr, QKVh, QKVl,
        VTh, VTl, 512, QKVS, 0.125f);
    attn_mf<<<1024,256,0,stream>>>(QKVh, QKVl, VTh, VTl,
        rel_k + (size_t)i*9*64, rel_v + (size_t)i*9*64, mask, Th, Tl);
    gemm_ps<EPI_RES,false,0,2,1><<<512,256,0,stream>>>(Th, Tl,
        aoh + (size_t)i*262144, aol + (size_t)i*262144,
        ao_b+i*512, X, nullptr, nullptr, Qb, nullptr, nullptr,
        nullptr, nullptr, 512, 512, 0.f);
    ln_rows<true,false><<<1024,256,0,stream>>>(Qb, ln1_g+i*512, ln1_b+i*512,
        nullptr, X, Xh, Xl, N);
    gemm_big<EPI_RELU_MASK,true,1,1><<<512,256,0,stream>>>(Xh, Xl,
        f1h + (size_t)i*1048576, f1l + (size_t)i*1048576,
        ffn_b1+i*2048, nullptr, nullptr, mask, nullptr, Hbh, Hbl,
        nullptr, nullptr, 512, 2048, 0.f);
    gemm_ps<EPI_RES_MASK,false,0,2,1><<<512,256,0,stream>>>(Hbh, Hbl,
        f2h + (size_t)i*1048576, f2l + (size_t)i*1048576,
        ffn_b2+i*512, X, nullptr, mask, Qb, nullptr, nullptr,
        nullptr, nullptr, 2048, 512, 0.f);
    if (i < 5)
      ln_rows<true,false><<<1024,256,0,stream>>>(Qb, ln2_g+i*512, ln2_b+i*512,
          nullptr, X, Xh, Xl, N);
    else
      ln_rows<true,true><<<1024,256,0,stream>>>(Qb, ln2_g+i*512, ln2_b+i*512,
          mask, X, Xh, Xl, N);
  }

  // ---- Style attention (MFMA path) ----
  style_prep<<<dim3(8,4),256,0,stream>>>(style_key, style_v, sk_w, sk_b,
      sv_w, sv_b, KKsh, KKsl, VTsh, VTsl);

  // layer 0: xin = masked X -> Q planes -> style_mf -> so gemm (x1 planes)
  gemm_ps<EPI_BIAS,false,1,2,1><<<512,256,0,stream>>>(Xh, Xl, sqh, sql,
      sq_b, nullptr, nullptr, nullptr, nullptr, QKVh, QKVl,
      nullptr, nullptr, 512, 512, 0.f);
  style_mf<<<256,256,0,stream>>>(QKVh, QKVl, KKsh, KKsl, VTsh, VTsl,
      mask, Th, Tl);
  gemm_ps<EPI_RES_MASK,false,1,2,1><<<512,256,0,stream>>>(Th, Tl, soh, sol,
      so_b, X, nullptr, mask, nullptr, Hbh, Hbl,
      nullptr, nullptr, 512, 512, 0.f);   // x1 planes
  // layer 1: xin = x1 (planes); residual xt = X
  gemm_ps<EPI_BIAS,false,1,2,1><<<512,256,0,stream>>>(Hbh, Hbl, sqh+262144, sql+262144,
      sq_b+512, nullptr, nullptr, nullptr, nullptr, QKVh, QKVl,
      nullptr, nullptr, 512, 512, 0.f);
  style_mf<<<256,256,0,stream>>>(QKVh, QKVl, KKsh+32768, KKsl+32768,
      VTsh+32768, VTsl+32768, mask, Th, Tl);
  gemm_ps<EPI_RES_MASK,false,0,2,1><<<512,256,0,stream>>>(Th, Tl, soh+262144, sol+262144,
      so_b+512, X, nullptr, mask, Vb, nullptr, nullptr,
      nullptr, nullptr, 512, 512, 0.f);  // x2

  ln_rows<false,false><<<1024,256,0,stream>>>(Vb, sn_g, sn_b, nullptr,
      Qb, nullptr, nullptr, N);
  transpose_out_k<<<dim3(16,16,8),256,0,stream>>>(Qb, mask, (float*)d_out);
}